// Round 2
// baseline (1232.863 us; speedup 1.0000x reference)
//
#include <hip/hip_runtime.h>

typedef unsigned short u16;
typedef __bf16 bf16x8 __attribute__((ext_vector_type(8)));
typedef float f32x4 __attribute__((ext_vector_type(4)));

#define NB 32          // batch
#define NS 512         // seq
#define NH 768         // hidden
#define NK 4           // heads
#define NBS 16384      // B*S
#define H3 2304        // 3H
#define HH 589824      // 768*768

__device__ inline float bf2f(u16 u) {
    unsigned x = ((unsigned)u) << 16;
    return __builtin_bit_cast(float, x);
}
__device__ inline u16 f2bf(float f) {
    unsigned u = __builtin_bit_cast(unsigned, f);
    u += 0x7fffu + ((u >> 16) & 1u);
    return (u16)(u >> 16);
}
// async global->LDS, 16B/lane; LDS dst = wave-uniform base + lane*16 (m97 recipe).
__device__ inline void gld16(const u16* g, u16* l) {
    __builtin_amdgcn_global_load_lds(
        (const __attribute__((address_space(1))) unsigned int*)g,
        (__attribute__((address_space(3))) unsigned int*)l, 16, 0, 0);
}

// ---------------------------------------------------------------------------
// Workspace layout (bytes):
//  comb    @ 0           9,437,184  f32 [4][768(h)][768(j)]  (tier 0/1 only)
//  combB   @ 9,437,184      12,288  f32 [4][768]
//  W_ht    @ 9,449,472     393,216  f32 [4][32][768]
//  scores  @ 9,842,688     262,144  f32 [4][32][512]
//  q_f32   @ 10,104,832     98,304  f32 [32][768]
//  hT      @ 10,203,136     98,304  f32 [768][32]
//  xT      @ 10,301,440    196,608  f32 [1536][32]
//  sx      @ 10,498,048    294,912  f32 [32][2304]  (73,728 floats)
//  sh      @ 10,792,960    294,912  f32 [32][2304]  (73,728 floats) -> 11,087,872
//  combTH  @ 11,087,872   4,718,592 bf16 [4][j][h] hi
//  combTL  @ 15,806,464   4,718,592 bf16 [4][j][h] lo   -> 20,525,056  TIER1
//  textH   @ 20,525,056  25,165,824 bf16 [bs][h] hi
//  textL   @ 45,690,880  25,165,824 bf16 [bs][h] lo     -> 70,856,704  TIER2
//  TP      @ 70,856,704 201,326,592 f32 [4][bs][j]      -> 272,183,296 TIER3
//  TIER2 prep scratch overlaid on textH region (consumed before split_text):
//   WsTH @ 20,525,056  WsTL @ 25,243,648  pwH @ 29,962,240  pwL @ 34,680,832
//
// TIER3: the scores GEMM operand text@comb is hop-INVARIANT (only the W_ht
// bias inside tanh changes per hop). Compute TP = text@comb once, then per
// hop a memory-bound tanh-reduce pass over TP (201 MB/hop).
// ---------------------------------------------------------------------------

// P: one-time prep (all tiers; tier2 sections gated).
__global__ void prep_kernel(const float* __restrict__ WsW, const float* __restrict__ pwb,
                            const float* __restrict__ Wsb, float* __restrict__ combB,
                            const float* __restrict__ question,
                            float* __restrict__ q_f32, float* __restrict__ hT,
                            const float* __restrict__ pwW,
                            u16* __restrict__ WsTH, u16* __restrict__ WsTL,
                            u16* __restrict__ pwH, u16* __restrict__ pwL, int tier)
{
    int bid = blockIdx.x, t = threadIdx.x;
    if (bid < 48) {
        int idx = bid * 64 + (t >> 2);      // 0..3071
        int ph = t & 3;
        int k = idx / NH, j = idx % NH;
        const float* W = WsW + (long)k * HH + j;
        const float* pb = pwb + k * NH;
        float acc = 0.f;
        #pragma unroll 8
        for (int m = ph * 192; m < ph * 192 + 192; ++m)
            acc += pb[m] * W[(long)m * NH];
        acc += __shfl_xor(acc, 1);
        acc += __shfl_xor(acc, 2);
        if (ph == 0) combB[idx] = acc + Wsb[idx];
    } else if (bid < 144) {
        int idx = (bid - 48) * 256 + t;
        q_f32[idx] = question[idx];
    } else if (bid < 240) {
        int idx = (bid - 144) * 256 + t;
        hT[idx] = 0.f;
    } else if (bid < 2544) {
        if (tier < 2) return;
        __shared__ float tile[32][33];
        int bid2 = bid - 240;
        int k = bid2 / 576, rem = bid2 % 576, tr = rem / 24, tc = rem % 24;
        const float* src = WsW + (long)k * HH;
        long dbase = (long)k * HH;
        int tx = t & 31, ty = t >> 5;
        #pragma unroll
        for (int i = 0; i < 4; ++i)
            tile[tx][ty + i*8] = src[(long)(tr*32 + ty + i*8) * NH + tc*32 + tx];
        __syncthreads();
        #pragma unroll
        for (int i = 0; i < 4; ++i) {
            float v = tile[ty + i*8][tx];
            u16 hv = f2bf(v);
            u16 lv = f2bf(v - bf2f(hv));
            long o = dbase + (long)(tc*32 + ty + i*8) * NH + tr*32 + tx;
            WsTH[o] = hv; WsTL[o] = lv;
        }
    } else {
        if (tier < 2) return;
        long base = (long)(bid - 2544) * 1024 + t * 4;
        float4 v = *(const float4*)(pwW + base);
        ushort4 hv, lv;
        hv.x = f2bf(v.x); lv.x = f2bf(v.x - bf2f(hv.x));
        hv.y = f2bf(v.y); lv.y = f2bf(v.y - bf2f(hv.y));
        hv.z = f2bf(v.z); lv.z = f2bf(v.z - bf2f(hv.z));
        hv.w = f2bf(v.w); lv.w = f2bf(v.w - bf2f(hv.w));
        *(ushort4*)(pwH + base) = hv;
        *(ushort4*)(pwL + base) = lv;
    }
}

// TIER2: combT[k][j][h] = sum_m WsT[k][j][m] * pw[k][h][m], split-bf16 3-MFMA.
__global__ __launch_bounds__(256) void comb_mfma_kernel(
    const u16* __restrict__ WsTH, const u16* __restrict__ WsTL,
    const u16* __restrict__ pwH, const u16* __restrict__ pwL,
    u16* __restrict__ combTH, u16* __restrict__ combTL)
{
    __shared__ __align__(16) u16 AsH[128 * 32];
    __shared__ __align__(16) u16 AsL[128 * 32];
    __shared__ __align__(16) u16 BsH[128 * 32];
    __shared__ __align__(16) u16 BsL[128 * 32];
    const int t = threadIdx.x;
    const int wave = t >> 6, lane = t & 63;
    const int k = blockIdx.z;
    const long m0 = (long)blockIdx.x * 128;   // j-rows
    const int n0 = blockIdx.y * 128;          // h-cols
    const u16* AH = WsTH + (long)k * HH;
    const u16* AL = WsTL + (long)k * HH;
    const u16* BH = pwH + (long)k * HH;
    const u16* BL = pwL + (long)k * HH;

    const int r = t >> 2, ch = t & 3;
    const int wm = (wave & 1) * 64, wn = (wave >> 1) * 64;
    const int fr = lane & 15, fq = lane >> 4;

    f32x4 acc[4][4];
    #pragma unroll
    for (int i = 0; i < 4; ++i)
        #pragma unroll
        for (int j = 0; j < 4; ++j) acc[i][j] = (f32x4){0.f, 0.f, 0.f, 0.f};

    for (int k0 = 0; k0 < NH; k0 += 32) {
        gld16(AH + (m0 + r)      * NH + k0 + ch*8, AsH + t*8);
        gld16(AH + (m0 + 64 + r) * NH + k0 + ch*8, AsH + 2048 + t*8);
        gld16(AL + (m0 + r)      * NH + k0 + ch*8, AsL + t*8);
        gld16(AL + (m0 + 64 + r) * NH + k0 + ch*8, AsL + 2048 + t*8);
        gld16(BH + (long)(n0 + r)      * NH + k0 + ch*8, BsH + t*8);
        gld16(BH + (long)(n0 + 64 + r) * NH + k0 + ch*8, BsH + 2048 + t*8);
        gld16(BL + (long)(n0 + r)      * NH + k0 + ch*8, BsL + t*8);
        gld16(BL + (long)(n0 + 64 + r) * NH + k0 + ch*8, BsL + 2048 + t*8);
        __syncthreads();
        bf16x8 afH[4], afL[4], bfH[4], bfL[4];
        #pragma unroll
        for (int i = 0; i < 4; ++i) {
            afH[i] = *(const bf16x8*)(AsH + (wm + i*16 + fr)*32 + fq*8);
            afL[i] = *(const bf16x8*)(AsL + (wm + i*16 + fr)*32 + fq*8);
            bfH[i] = *(const bf16x8*)(BsH + (wn + i*16 + fr)*32 + fq*8);
            bfL[i] = *(const bf16x8*)(BsL + (wn + i*16 + fr)*32 + fq*8);
        }
        #pragma unroll
        for (int i = 0; i < 4; ++i)
            #pragma unroll
            for (int j = 0; j < 4; ++j) {
                acc[i][j] = __builtin_amdgcn_mfma_f32_16x16x32_bf16(afH[i], bfH[j], acc[i][j], 0, 0, 0);
                acc[i][j] = __builtin_amdgcn_mfma_f32_16x16x32_bf16(afH[i], bfL[j], acc[i][j], 0, 0, 0);
                acc[i][j] = __builtin_amdgcn_mfma_f32_16x16x32_bf16(afL[i], bfH[j], acc[i][j], 0, 0, 0);
            }
        __syncthreads();
    }
    long kb = (long)k * HH;
    #pragma unroll
    for (int i = 0; i < 4; ++i) {
        long m = m0 + wm + i*16 + fq*4;       // j-row
        #pragma unroll
        for (int j = 0; j < 4; ++j) {
            long n = n0 + wn + j*16 + fr;     // h-col
            #pragma unroll
            for (int rr = 0; rr < 4; ++rr) {
                float v = acc[i][j][rr];
                u16 hv = f2bf(v);
                u16 lv = f2bf(v - bf2f(hv));
                combTH[kb + (m + rr) * NH + n] = hv;
                combTL[kb + (m + rr) * NH + n] = lv;
            }
        }
    }
}

// tier 0/1: comb[k][h][j] f32 VALU GEMM (proven R8 kernel).
__global__ __launch_bounds__(256) void comb_valu_kernel(
    const float* __restrict__ pwW, const float* __restrict__ WsW,
    float* __restrict__ comb)
{
    __shared__ float AtT[32][68];
    __shared__ float Bt[32][132];
    const int t = threadIdx.x;
    const int m0 = blockIdx.x * 64, j0 = blockIdx.y * 128, k = blockIdx.z;
    const float* A = pwW + (long)k * HH;
    const float* B = WsW + (long)k * HH;
    const int r4 = (t >> 4) * 4, c8 = (t & 15) * 8;
    float acc[4][8];
    #pragma unroll
    for (int rr = 0; rr < 4; ++rr)
        #pragma unroll
        for (int cc = 0; cc < 8; ++cc) acc[rr][cc] = 0.f;
    for (int h0 = 0; h0 < NH; h0 += 32) {
        #pragma unroll
        for (int p = 0; p < 8; ++p) {
            int idx = p * 256 + t;
            int r = idx >> 5, hh = idx & 31;
            AtT[hh][r] = A[(long)(m0 + r) * NH + h0 + hh];
        }
        #pragma unroll
        for (int p = 0; p < 16; ++p) {
            int idx = p * 256 + t;
            int hh = idx >> 7, c = idx & 127;
            Bt[hh][c] = B[(long)(h0 + hh) * NH + j0 + c];
        }
        __syncthreads();
        for (int hh = 0; hh < 32; ++hh) {
            float4 av  = *(const float4*)&AtT[hh][r4];
            float4 bv0 = *(const float4*)&Bt[hh][c8];
            float4 bv1 = *(const float4*)&Bt[hh][c8 + 4];
            float a[4] = {av.x, av.y, av.z, av.w};
            float bb[8] = {bv0.x, bv0.y, bv0.z, bv0.w, bv1.x, bv1.y, bv1.z, bv1.w};
            #pragma unroll
            for (int rr = 0; rr < 4; ++rr)
                #pragma unroll
                for (int cc = 0; cc < 8; ++cc) acc[rr][cc] += a[rr] * bb[cc];
        }
        __syncthreads();
    }
    float* C = comb + (long)k * HH;
    #pragma unroll
    for (int rr = 0; rr < 4; ++rr)
        #pragma unroll
        for (int cc = 0; cc < 8; ++cc)
            C[(long)(m0 + r4 + rr) * NH + j0 + c8 + cc] = acc[rr][cc];
}

// tier1: transpose+split comb f32 -> combTH/combTL. grid 2304.
__global__ void split_combT_kernel(const float* __restrict__ comb,
                                   u16* __restrict__ combTH, u16* __restrict__ combTL)
{
    __shared__ float tile[32][33];
    int bid = blockIdx.x, t = threadIdx.x;
    int k = bid / 576, rem = bid % 576, tr = rem / 24, tc = rem % 24;
    const float* src = comb + (long)k * HH;
    long dbase = (long)k * HH;
    int tx = t & 31, ty = t >> 5;
    #pragma unroll
    for (int i = 0; i < 4; ++i)
        tile[tx][ty + i*8] = src[(long)(tr*32 + ty + i*8) * NH + tc*32 + tx];
    __syncthreads();
    #pragma unroll
    for (int i = 0; i < 4; ++i) {
        float v = tile[ty + i*8][tx];
        u16 hv = f2bf(v);
        u16 lv = f2bf(v - bf2f(hv));
        long o = dbase + (long)(tc*32 + ty + i*8) * NH + tr*32 + tx;
        combTH[o] = hv; combTL[o] = lv;
    }
}

// TIER2: split text f32 -> textH/textL. grid 12288 (after comb_mfma!).
__global__ void split_text_kernel(const float* __restrict__ text,
                                  u16* __restrict__ textH, u16* __restrict__ textL)
{
    long base = (long)blockIdx.x * 1024 + threadIdx.x * 4;
    float4 v = *(const float4*)(text + base);
    ushort4 hv, lv;
    hv.x = f2bf(v.x); lv.x = f2bf(v.x - bf2f(hv.x));
    hv.y = f2bf(v.y); lv.y = f2bf(v.y - bf2f(hv.y));
    hv.z = f2bf(v.z); lv.z = f2bf(v.z - bf2f(hv.z));
    hv.w = f2bf(v.w); lv.w = f2bf(v.w - bf2f(hv.w));
    *(ushort4*)(textH + base) = hv;
    *(ushort4*)(textL + base) = lv;
}

// TIER3: TP[k][bs][j] = (text @ comb[k])[bs][j] f32, computed ONCE (hop-invariant).
// Same GEMM body as fused_scores_mfma<1>; raw f32 accumulator store.
__global__ __launch_bounds__(256) void tp_gemm_kernel(
    const u16* __restrict__ textH, const u16* __restrict__ textL,
    const u16* __restrict__ combTH, const u16* __restrict__ combTL,
    float* __restrict__ TP)
{
    __shared__ __align__(16) u16 AsH[128 * 32];
    __shared__ __align__(16) u16 AsL[128 * 32];
    __shared__ __align__(16) u16 BsH[128 * 32];
    __shared__ __align__(16) u16 BsL[128 * 32];
    const int t = threadIdx.x;
    const int wave = t >> 6, lane = t & 63;
    const int k = blockIdx.z;
    const long m0 = (long)blockIdx.x * 128;   // bs-rows
    const int n0 = blockIdx.y * 128;          // j-cols
    const u16* BH = combTH + (long)k * HH;
    const u16* BL = combTL + (long)k * HH;

    const int r = t >> 2, ch = t & 3;
    const int wm = (wave & 1) * 64, wn = (wave >> 1) * 64;
    const int fr = lane & 15, fq = lane >> 4;

    f32x4 acc[4][4];
    #pragma unroll
    for (int i = 0; i < 4; ++i)
        #pragma unroll
        for (int j = 0; j < 4; ++j) acc[i][j] = (f32x4){0.f, 0.f, 0.f, 0.f};

    for (int h0 = 0; h0 < NH; h0 += 32) {
        gld16(textH + (m0 + r)      * NH + h0 + ch*8, AsH + t*8);
        gld16(textH + (m0 + 64 + r) * NH + h0 + ch*8, AsH + 2048 + t*8);
        gld16(textL + (m0 + r)      * NH + h0 + ch*8, AsL + t*8);
        gld16(textL + (m0 + 64 + r) * NH + h0 + ch*8, AsL + 2048 + t*8);
        gld16(BH + (long)(n0 + r)      * NH + h0 + ch*8, BsH + t*8);
        gld16(BH + (long)(n0 + 64 + r) * NH + h0 + ch*8, BsH + 2048 + t*8);
        gld16(BL + (long)(n0 + r)      * NH + h0 + ch*8, BsL + t*8);
        gld16(BL + (long)(n0 + 64 + r) * NH + h0 + ch*8, BsL + 2048 + t*8);
        __syncthreads();
        bf16x8 afH[4], afL[4], bfH[4], bfL[4];
        #pragma unroll
        for (int i = 0; i < 4; ++i) {
            afH[i] = *(const bf16x8*)(AsH + (wm + i*16 + fr)*32 + fq*8);
            afL[i] = *(const bf16x8*)(AsL + (wm + i*16 + fr)*32 + fq*8);
            bfH[i] = *(const bf16x8*)(BsH + (wn + i*16 + fr)*32 + fq*8);
            bfL[i] = *(const bf16x8*)(BsL + (wn + i*16 + fr)*32 + fq*8);
        }
        #pragma unroll
        for (int i = 0; i < 4; ++i)
            #pragma unroll
            for (int j = 0; j < 4; ++j) {
                acc[i][j] = __builtin_amdgcn_mfma_f32_16x16x32_bf16(afH[i], bfH[j], acc[i][j], 0, 0, 0);
                acc[i][j] = __builtin_amdgcn_mfma_f32_16x16x32_bf16(afH[i], bfL[j], acc[i][j], 0, 0, 0);
                acc[i][j] = __builtin_amdgcn_mfma_f32_16x16x32_bf16(afL[i], bfH[j], acc[i][j], 0, 0, 0);
            }
        __syncthreads();
    }
    float* out = TP + ((long)k * NBS + m0) * NH + n0;
    #pragma unroll
    for (int i = 0; i < 4; ++i) {
        #pragma unroll
        for (int rr = 0; rr < 4; ++rr) {
            int m = wm + i*16 + fq*4 + rr;
            #pragma unroll
            for (int j = 0; j < 4; ++j) {
                int n = wn + j*16 + fr;
                out[(long)m * NH + n] = acc[i][j][rr];
            }
        }
    }
}

// TIER3 per-hop: scores[k][b][s] = We_b[k] + sum_j tanh(TP + combB + W_ht)*We.
// Memory-bound pass over TP (201 MB). grid (16, 32, 4), 256 thr (4 waves).
__global__ __launch_bounds__(256) void score_pass_kernel(
    const float* __restrict__ TP, const float* __restrict__ combB,
    const float* __restrict__ W_ht, const float* __restrict__ WeW,
    const float* __restrict__ Web, float* __restrict__ scores)
{
    __shared__ __align__(16) float bias_s[NH];
    __shared__ __align__(16) float we_s[NH];
    const int t = threadIdx.x;
    const int k = blockIdx.z, b = blockIdx.y;
    const int s0 = blockIdx.x * 32;
    for (int i = t; i < NH; i += 256) {
        bias_s[i] = combB[k * NH + i] + W_ht[((k << 5) + b) * NH + i];
        we_s[i]   = WeW[k * NH + i];
    }
    __syncthreads();
    const int wave = t >> 6, lane = t & 63;
    const float* tpb = TP + ((long)k * NBS + (b << 9) + s0) * NH;
    const float web = Web[k];
    for (int sr = wave; sr < 32; sr += 4) {
        const float* row = tpb + (long)sr * NH;
        float part = 0.f;
        #pragma unroll
        for (int p = 0; p < 3; ++p) {
            const int j = p * 256 + lane * 4;   // lane*16B, conflict-free b128 LDS reads
            float4 v  = *(const float4*)(row + j);
            float4 bb = *(const float4*)(bias_s + j);
            float4 ww = *(const float4*)(we_s + j);
            part += tanhf(v.x + bb.x) * ww.x;
            part += tanhf(v.y + bb.y) * ww.y;
            part += tanhf(v.z + bb.z) * ww.z;
            part += tanhf(v.w + bb.w) * ww.w;
        }
        part += __shfl_xor(part, 1);
        part += __shfl_xor(part, 2);
        part += __shfl_xor(part, 4);
        part += __shfl_xor(part, 8);
        part += __shfl_xor(part, 16);
        part += __shfl_xor(part, 32);
        if (lane == 0) scores[(((k << 5) + b) << 9) + s0 + sr] = part + web;
    }
}

// Per-hop init: scores=We_b (65,536 f), W_ht=Wt_b (98,304 f), sx/sh=0 (147,456 f).
// grid 1216 = 256 + 384 + 576.
__global__ void init_hop_kernel(const float* __restrict__ Web, float* __restrict__ scores,
                                const float* __restrict__ Wtb, float* __restrict__ W_ht,
                                float* __restrict__ sx, float* __restrict__ sh)
{
    int bid = blockIdx.x, t = threadIdx.x;
    if (bid < 256) {
        int idx = bid * 256 + t;              // 65,536
        scores[idx] = Web[idx >> 14];
    } else if (bid < 640) {
        int idx = (bid - 256) * 256 + t;      // 98,304
        int k = idx / 24576, j = idx % NH;
        W_ht[idx] = Wtb[k * NH + j];
    } else {
        int idx = (bid - 640) * 256 + t;      // 147,456 floats total (NOT bytes!)
        if (idx < 73728) sx[idx] = 0.f;
        else sh[idx - 73728] = 0.f;
    }
}

// W_ht partials: grid 1536 = 4k x 32b x 3jt x 4hg; atomicAdd into W_ht.
__global__ void wht2_kernel(const float* __restrict__ q, const float* __restrict__ WtW,
                            float* __restrict__ W_ht)
{
    int bid = blockIdx.x;
    int k = bid / 384, rem = bid % 384, b = rem / 12, rem2 = rem % 12;
    int jt = rem2 / 4, hg = rem2 % 4;
    int j = jt * 256 + threadIdx.x;
    const float* W = WtW + (long)k * HH + j;
    const float* qb = q + b * NH;
    float acc = 0.f;
    #pragma unroll 8
    for (int h = hg * 192; h < hg * 192 + 192; ++h) acc += qb[h] * W[(long)h * NH];
    atomicAdd(&W_ht[(k*NB + b) * NH + j], acc);
}

// ---------------------------------------------------------------------------
// MFMA split-bf16 fused scores (proven R9). grid (128, 6, 4).
// ---------------------------------------------------------------------------
template <int AM>
__global__ __launch_bounds__(256) void fused_scores_mfma(
    const float* __restrict__ textf,
    const u16* __restrict__ textH, const u16* __restrict__ textL,
    const u16* __restrict__ combTH, const u16* __restrict__ combTL,
    const float* __restrict__ combB, const float* __restrict__ W_ht,
    const float* __restrict__ WeW, float* __restrict__ scores)
{
    __shared__ __align__(16) u16 AsH[128 * 32];
    __shared__ __align__(16) u16 AsL[128 * 32];
    __shared__ __align__(16) u16 BsH[128 * 32];
    __shared__ __align__(16) u16 BsL[128 * 32];
    __shared__ float wht_s[128];
    __shared__ float we_s[128];
    __shared__ float sred[128];
    const int t = threadIdx.x;
    const int wave = t >> 6, lane = t & 63;
    const int k = blockIdx.z;
    const long m0 = (long)blockIdx.x * 128;
    const int n0 = blockIdx.y * 128;
    const int b = (int)(m0 >> 9), srow = (int)(m0 & 511);
    const u16* BH = combTH + (long)k * HH;
    const u16* BL = combTL + (long)k * HH;

    if (t < 128) {
        wht_s[t] = W_ht[((k << 5) + b) * NH + n0 + t] + combB[k * NH + n0 + t];
        we_s[t]  = WeW[k * NH + n0 + t];
        sred[t]  = 0.f;
    }

    const int r = t >> 2, ch = t & 3;
    const int wm = (wave & 1) * 64, wn = (wave >> 1) * 64;
    const int fr = lane & 15, fq = lane >> 4;

    f32x4 acc[4][4];
    #pragma unroll
    for (int i = 0; i < 4; ++i)
        #pragma unroll
        for (int j = 0; j < 4; ++j) acc[i][j] = (f32x4){0.f, 0.f, 0.f, 0.f};

    for (int h0 = 0; h0 < NH; h0 += 32) {
        if (AM) {
            gld16(textH + (m0 + r)      * NH + h0 + ch*8, AsH + t*8);
            gld16(textH + (m0 + 64 + r) * NH + h0 + ch*8, AsH + 2048 + t*8);
            gld16(textL + (m0 + r)      * NH + h0 + ch*8, AsL + t*8);
            gld16(textL + (m0 + 64 + r) * NH + h0 + ch*8, AsL + 2048 + t*8);
        } else {
            #pragma unroll
            for (int p = 0; p < 4; ++p) {
                int task = p * 256 + t;
                int row = task >> 3, g = task & 7;
                float4 v = *(const float4*)(textf + (m0 + row) * NH + h0 + g*4);
                ushort4 hv, lv;
                hv.x = f2bf(v.x); lv.x = f2bf(v.x - bf2f(hv.x));
                hv.y = f2bf(v.y); lv.y = f2bf(v.y - bf2f(hv.y));
                hv.z = f2bf(v.z); lv.z = f2bf(v.z - bf2f(hv.z));
                hv.w = f2bf(v.w); lv.w = f2bf(v.w - bf2f(hv.w));
                *(ushort4*)(AsH + row * 32 + g*4) = hv;
                *(ushort4*)(AsL + row * 32 + g*4) = lv;
            }
        }
        gld16(BH + (long)(n0 + r)      * NH + h0 + ch*8, BsH + t*8);
        gld16(BH + (long)(n0 + 64 + r) * NH + h0 + ch*8, BsH + 2048 + t*8);
        gld16(BL + (long)(n0 + r)      * NH + h0 + ch*8, BsL + t*8);
        gld16(BL + (long)(n0 + 64 + r) * NH + h0 + ch*8, BsL + 2048 + t*8);
        __syncthreads();
        bf16x8 afH[4], afL[4], bfH[4], bfL[4];
        #pragma unroll
        for (int i = 0; i < 4; ++i) {
            afH[i] = *(const bf16x8*)(AsH + (wm + i*16 + fr)*32 + fq*8);
            afL[i] = *(const bf16x8*)(AsL + (wm + i*16 + fr)*32 + fq*8);
            bfH[i] = *(const bf16x8*)(BsH + (wn + i*16 + fr)*32 + fq*8);
            bfL[i] = *(const bf16x8*)(BsL + (wn + i*16 + fr)*32 + fq*8);
        }
        #pragma unroll
        for (int i = 0; i < 4; ++i)
            #pragma unroll
            for (int j = 0; j < 4; ++j) {
                acc[i][j] = __builtin_amdgcn_mfma_f32_16x16x32_bf16(afH[i], bfH[j], acc[i][j], 0, 0, 0);
                acc[i][j] = __builtin_amdgcn_mfma_f32_16x16x32_bf16(afH[i], bfL[j], acc[i][j], 0, 0, 0);
                acc[i][j] = __builtin_amdgcn_mfma_f32_16x16x32_bf16(afL[i], bfH[j], acc[i][j], 0, 0, 0);
            }
        __syncthreads();
    }
    #pragma unroll
    for (int i = 0; i < 4; ++i) {
        #pragma unroll
        for (int rr = 0; rr < 4; ++rr) {
            int m = wm + i*16 + fq*4 + rr;
            float part = 0.f;
            #pragma unroll
            for (int j = 0; j < 4; ++j) {
                int n = wn + j*16 + fr;
                part += tanhf(acc[i][j][rr] + wht_s[n]) * we_s[n];
            }
            part += __shfl_xor(part, 1);
            part += __shfl_xor(part, 2);
            part += __shfl_xor(part, 4);
            part += __shfl_xor(part, 8);
            if (fr == 0) atomicAdd(&sred[m], part);
        }
    }
    __syncthreads();
    if (t < 128)
        atomicAdd(&scores[(((k << 5) + b) << 9) + srow + t], sred[t]);
}

// tier0 fallback (proven R8). grid (256, 6, 4).
__global__ __launch_bounds__(256) void fused_scores_valu(
    const float* __restrict__ text, const float* __restrict__ comb,
    const float* __restrict__ combB, const float* __restrict__ W_ht,
    const float* __restrict__ WeW, float* __restrict__ scores)
{
    __shared__ float AtT[32][68];
    __shared__ float Bt[32][132];
    __shared__ float wht_s[128];
    __shared__ float we_s[128];
    __shared__ float sred[64];
    const int t = threadIdx.x;
    const int row0 = blockIdx.x * 64;
    const int j0 = blockIdx.y * 128, k = blockIdx.z;
    const int b = row0 >> 9, s0 = row0 & 511;
    const float* B = comb + (long)k * HH;
    const int r4 = (t >> 4) * 4, c8 = (t & 15) * 8;
    if (t < 128) {
        wht_s[t] = W_ht[((k << 5) + b) * NH + j0 + t] + combB[k * NH + j0 + t];
        we_s[t]  = WeW[k * NH + j0 + t];
    }
    if (t < 64) sred[t] = 0.f;
    float acc[4][8];
    #pragma unroll
    for (int rr = 0; rr < 4; ++rr)
        #pragma unroll
        for (int cc = 0; cc < 8; ++cc) acc[rr][cc] = 0.f;
    for (int h0 = 0; h0 < NH; h0 += 32) {
        #pragma unroll
        for (int p = 0; p < 8; ++p) {
            int idx = p * 256 + t;
            int r = idx >> 5, hh = idx & 31;
            AtT[hh][r] = text[(long)(row0 + r) * NH + h0 + hh];
        }
        #pragma unroll
        for (int p = 0; p < 16; ++p) {
            int idx = p * 256 + t;
            int hh = idx >> 7, c = idx & 127;
            Bt[hh][c] = B[(long)(h0 + hh) * NH + j0 + c];
        }
        __syncthreads();
        for (int hh = 0; hh < 32; ++hh) {
            float4 av  = *(const float4*)&AtT[hh][r4];
            float4 bv0 = *(const float4*)&Bt[hh][c8];
            float4 bv1 = *(const float4*)&Bt[hh][c8 + 4];
            float a[4] = {av.x, av.y, av.z, av.w};
            float bb[8] = {bv0.x, bv0.y, bv0.z, bv0.w, bv1.x, bv1.y, bv1.z, bv1.w};
            #pragma unroll
            for (int rr = 0; rr < 4; ++rr)
                #pragma unroll
                for (int cc = 0; cc < 8; ++cc) acc[rr][cc] += a[rr] * bb[cc];
        }
        __syncthreads();
    }
    float part[4] = {0.f, 0.f, 0.f, 0.f};
    #pragma unroll
    for (int rr = 0; rr < 4; ++rr)
        #pragma unroll
        for (int cc = 0; cc < 8; ++cc)
            part[rr] += tanhf(acc[rr][cc] + wht_s[c8 + cc]) * we_s[c8 + cc];
    #pragma unroll
    for (int rr = 0; rr < 4; ++rr)
        atomicAdd(&sred[r4 + rr], part[rr]);
    __syncthreads();
    if (t < 64)
        atomicAdd(&scores[(((k << 5) + b) << 9) + s0 + t], sred[t]);
}

__global__ void softmax_kernel(const float* __restrict__ scores,
                               const float* __restrict__ headw_W, const float* __restrict__ headw_b,
                               const float* __restrict__ text,
                               const float* __restrict__ q_f32,
                               float* __restrict__ xT, float* __restrict__ out_prob, int hop)
{
    __shared__ float sc[NK][NS];
    __shared__ float red[256];
    __shared__ float rv[256];
    __shared__ int   ri[256];
    int b = blockIdx.x, t = threadIdx.x;
    for (int i = t; i < NK * NS; i += 256) {
        int k = i >> 9, s = i & 511;
        sc[k][s] = scores[((k*NB + b) << 9) + s];
    }
    __syncthreads();
    float fac[NK];
    for (int k = 0; k < NK; ++k) {
        float v0 = sc[k][t], v1 = sc[k][t + 256];
        red[t] = fmaxf(v0, v1);
        __syncthreads();
        for (int o = 128; o > 0; o >>= 1) { if (t < o) red[t] = fmaxf(red[t], red[t + o]); __syncthreads(); }
        float mx = red[0];
        __syncthreads();
        float e0 = expf(v0 - mx), e1 = expf(v1 - mx);
        sc[k][t] = e0; sc[k][t + 256] = e1;
        red[t] = e0 + e1;
        __syncthreads();
        for (int o = 128; o > 0; o >>= 1) { if (t < o) red[t] += red[t + o]; __syncthreads(); }
        fac[k] = headw_W[k] / red[0];
        __syncthreads();
    }
    float hwb = headw_b[0];
    float a0 = hwb, a1 = hwb;
    for (int k = 0; k < NK; ++k) { a0 += sc[k][t] * fac[k]; a1 += sc[k][t + 256] * fac[k]; }
    red[t] = a0*a0 + a1*a1;
    float bv; int bi;
    if (a0 >= a1) { bv = a0; bi = t; } else { bv = a1; bi = t + 256; }
    rv[t] = bv; ri[t] = bi;
    __syncthreads();
    for (int o = 128; o > 0; o >>= 1) {
        if (t < o) {
            red[t] += red[t + o];
            if (rv[t + o] > rv[t] || (rv[t + o] == rv[t] && ri[t + o] < ri[t])) { rv[t] = rv[t + o]; ri[t] = ri[t + o]; }
        }
        __syncthreads();
    }
    float scale = sqrtf(red[0]);
    int idx = ri[0];
    if (hop == 0) {
        out_prob[(b << 9) + t]       = a0 / scale;
        out_prob[(b << 9) + t + 256] = a1 / scale;
    }
    const float* trow = text + (long)(b * NS + idx) * NH;
    for (int i = t; i < NH; i += 256) {
        xT[i * NB + b]        = q_f32[b*NH + i];
        xT[(NH + i) * NB + b] = trow[i];
    }
}

// GRU matvec partials: grid (36 j-tiles, 3 c-groups); atomicAdd into sx/sh.
__global__ __launch_bounds__(256) void gru_mm3_kernel(
    const float* __restrict__ Wih, const float* __restrict__ Whh,
    const float* __restrict__ xT, const float* __restrict__ hT,
    float* __restrict__ sx, float* __restrict__ sh)
{
    __shared__ float xs[8192];
    int t = threadIdx.x;
    int tj = t & 63, tq = t >> 6;
    int j = blockIdx.x * 64 + tj;
    int cg = blockIdx.y;
    float acc[8];
    #pragma unroll
    for (int bq = 0; bq < 8; ++bq) acc[bq] = 0.f;
    for (int c = cg * 2; c < cg * 2 + 2; ++c) {
        for (int idx = t; idx < 8192; idx += 256) xs[idx] = xT[c * 8192 + idx];
        __syncthreads();
        #pragma unroll 8
        for (int ii = 0; ii < 256; ++ii) {
            float w = Wih[(long)(c * 256 + ii) * H3 + j];
            #pragma unroll
            for (int bq = 0; bq < 8; ++bq) acc[bq] += xs[ii * 32 + tq * 8 + bq] * w;
        }
        __syncthreads();
    }
    #pragma unroll
    for (int bq = 0; bq < 8; ++bq)
        atomicAdd(&sx[(long)(tq * 8 + bq) * H3 + j], acc[bq]);
    #pragma unroll
    for (int bq = 0; bq < 8; ++bq) acc[bq] = 0.f;
    {
        int c = cg;
        for (int idx = t; idx < 8192; idx += 256) xs[idx] = hT[c * 8192 + idx];
        __syncthreads();
        #pragma unroll 8
        for (int ii = 0; ii < 256; ++ii) {
            float w = Whh[(long)(c * 256 + ii) * H3 + j];
            #pragma unroll
            for (int bq = 0; bq < 8; ++bq) acc[bq] += xs[ii * 32 + tq * 8 + bq] * w;
        }
    }
    #pragma unroll
    for (int bq = 0; bq < 8; ++bq)
        atomicAdd(&sh[(long)(tq * 8 + bq) * H3 + j], acc[bq]);
}

__global__ void gate_kernel(const float* __restrict__ sx, const float* __restrict__ sh,
                            const float* __restrict__ bih, const float* __restrict__ bhh,
                            float* __restrict__ hT, float* __restrict__ q_f32,
                            float* __restrict__ out_h, int hop)
{
    int gid = blockIdx.x * 256 + threadIdx.x;
    int b = gid / NH, j = gid % NH;
    float xr = bih[j]        + sx[b*H3 + j];
    float xz = bih[NH + j]   + sx[b*H3 + NH + j];
    float xn = bih[1536 + j] + sx[b*H3 + 1536 + j];
    float hr = bhh[j]        + sh[b*H3 + j];
    float hz = bhh[NH + j]   + sh[b*H3 + NH + j];
    float hn = bhh[1536 + j] + sh[b*H3 + 1536 + j];
    float r = 1.f / (1.f + expf(-(xr + hr)));
    float z = 1.f / (1.f + expf(-(xz + hz)));
    float n = tanhf(xn + r * hn);
    float hp = hT[j * NB + b];
    float hnew = (1.f - z) * n + z * hp;
    hT[j * NB + b] = hnew;
    q_f32[gid] = hnew;
    out_h[(long)(b * 3 + hop) * NH + j] = hnew;
}

// ---------------------------------------------------------------------------
extern "C" void kernel_launch(void* const* d_in, const int* in_sizes, int n_in,
                              void* d_out, int out_size, void* d_ws, size_t ws_size,
                              hipStream_t stream)
{
    const float* question = (const float*)d_in[0];
    const float* text     = (const float*)d_in[1];
    const float* pw_W     = (const float*)d_in[2];
    const float* pw_b     = (const float*)d_in[3];
    const float* Ws_W     = (const float*)d_in[4];
    const float* Ws_b     = (const float*)d_in[5];
    const float* Wt_W     = (const float*)d_in[6];
    const float* Wt_b     = (const float*)d_in[7];
    const float* We_W     = (const float*)d_in[8];
    const float* We_b     = (const float*)d_in[9];
    const float* headw_W  = (const float*)d_in[10];
    const float* headw_b  = (const float*)d_in[11];
    const float* Wih      = (const float*)d_in[12];
    const float* Whh      = (const float*)d_in[13];
    const float* bih      = (const float*)d_in[14];
    const float* bhh      = (const float*)d_in[15];

    char* ws = (char*)d_ws;
    float* comb   = (float*)(ws + 0);
    float* combB  = (float*)(ws + 9437184);
    float* W_ht   = (float*)(ws + 9449472);
    float* scores = (float*)(ws + 9842688);
    float* q_f32  = (float*)(ws + 10104832);
    float* hT     = (float*)(ws + 10203136);
    float* xT     = (float*)(ws + 10301440);
    float* sx     = (float*)(ws + 10498048);
    float* sh     = (float*)(ws + 10792960);
    u16*   combTH = (u16*)  (ws + 11087872);
    u16*   combTL = (u16*)  (ws + 15806464);
    u16*   textH  = (u16*)  (ws + 20525056);
    u16*   textL  = (u16*)  (ws + 45690880);
    float* TP     = (float*)(ws + 70856704);
    // tier2 prep scratch overlaid on textH region (dead before split_text):
    u16*   WsTH   = (u16*)  (ws + 20525056);
    u16*   WsTL   = (u16*)  (ws + 25243648);
    u16*   pwH    = (u16*)  (ws + 29962240);
    u16*   pwL    = (u16*)  (ws + 34680832);
    const int tier = (ws_size >= (size_t)272183296) ? 3
                   : (ws_size >= (size_t)70856704) ? 2
                   : (ws_size >= (size_t)20525056) ? 1 : 0;

    float* out_prob = (float*)d_out;
    float* out_h    = (float*)d_out + NB * NS;

    prep_kernel<<<4848, 256, 0, stream>>>(Ws_W, pw_b, Ws_b, combB, question, q_f32, hT,
                                          pw_W, WsTH, WsTL, pwH, pwL, tier);
    if (tier >= 2) {
        comb_mfma_kernel<<<dim3(6, 6, 4), 256, 0, stream>>>(WsTH, WsTL, pwH, pwL,
                                                            combTH, combTL);
        split_text_kernel<<<12288, 256, 0, stream>>>(text, textH, textL);
        if (tier == 3)
            tp_gemm_kernel<<<dim3(128, 6, 4), 256, 0, stream>>>(textH, textL,
                                                                combTH, combTL, TP);
    } else {
        comb_valu_kernel<<<dim3(12, 6, 4), 256, 0, stream>>>(pw_W, Ws_W, comb);
        if (tier == 1)
            split_combT_kernel<<<2304, 256, 0, stream>>>(comb, combTH, combTL);
    }

    for (int hop = 0; hop < 3; ++hop) {
        init_hop_kernel<<<1216, 256, 0, stream>>>(We_b, scores, Wt_b, W_ht, sx, sh);
        wht2_kernel<<<1536, 256, 0, stream>>>(q_f32, Wt_W, W_ht);
        if (tier == 3) {
            score_pass_kernel<<<dim3(16, 32, 4), 256, 0, stream>>>(
                TP, combB, W_ht, We_W, We_b, scores);
        } else if (tier == 2) {
            fused_scores_mfma<1><<<dim3(128, 6, 4), 256, 0, stream>>>(
                text, textH, textL, combTH, combTL, combB, W_ht, We_W, scores);
        } else if (tier == 1) {
            fused_scores_mfma<0><<<dim3(128, 6, 4), 256, 0, stream>>>(
                text, nullptr, nullptr, combTH, combTL, combB, W_ht, We_W, scores);
        } else {
            fused_scores_valu<<<dim3(256, 6, 4), 256, 0, stream>>>(
                text, comb, combB, W_ht, We_W, scores);
        }
        softmax_kernel<<<32, 256, 0, stream>>>(scores, headw_W, headw_b, text,
                                               q_f32, xT, out_prob, hop);
        gru_mm3_kernel<<<dim3(36, 3), 256, 0, stream>>>(Wih, Whh, xT, hT, sx, sh);
        gate_kernel<<<96, 256, 0, stream>>>(sx, sh, bih, bhh, hT, q_f32, out_h, hop);
    }
}

// Round 3
// 825.990 us; speedup vs baseline: 1.4926x; 1.4926x over previous
//
#include <hip/hip_runtime.h>

typedef unsigned short u16;
typedef __bf16 bf16x8 __attribute__((ext_vector_type(8)));
typedef float f32x4 __attribute__((ext_vector_type(4)));

#define NB 32          // batch
#define NS 512         // seq
#define NH 768         // hidden
#define NK 4           // heads
#define NBS 16384      // B*S
#define H3 2304        // 3H
#define HH 589824      // 768*768

__device__ inline float bf2f(u16 u) {
    unsigned x = ((unsigned)u) << 16;
    return __builtin_bit_cast(float, x);
}
__device__ inline u16 f2bf(float f) {
    unsigned u = __builtin_bit_cast(unsigned, f);
    u += 0x7fffu + ((u >> 16) & 1u);
    return (u16)(u >> 16);
}
// async global->LDS, 16B/lane; LDS dst = wave-uniform base + lane*16 (m97 recipe).
__device__ inline void gld16(const u16* g, u16* l) {
    __builtin_amdgcn_global_load_lds(
        (const __attribute__((address_space(1))) unsigned int*)g,
        (__attribute__((address_space(3))) unsigned int*)l, 16, 0, 0);
}

// ---------------------------------------------------------------------------
// Workspace layout (bytes):
//  comb    @ 0           9,437,184  f32 [4][768(h)][768(j)]  (tier 0/1 only)
//  combB   @ 9,437,184      12,288  f32 [4][768]
//  W_ht    @ 9,449,472     393,216  f32 [4][32][768]
//  scores  @ 9,842,688     262,144  f32 [4][32][512]
//  q_f32   @ 10,104,832     98,304  f32 [32][768]
//  hT      @ 10,203,136     98,304  f32 [768][32]
//  xT      @ 10,301,440    196,608  f32 [1536][32]
//  sx      @ 10,498,048    294,912  f32 [32][2304]
//  sh      @ 10,792,960    294,912  f32 [32][2304]  -> 11,087,872
//  combTH  @ 11,087,872   4,718,592 bf16 [4][j][h] hi
//  combTL  @ 15,806,464   4,718,592 bf16 [4][j][h] lo   -> 20,525,056  TIER1
//  TP      @ 20,525,056   NSTORE x 50,331,648 f32 [k][bs][j]  (TIER3)
//  TIER3 prep scratch overlaid on TP region (consumed by comb_mfma BEFORE
//  tp_gemm writes TP):
//   WsTH @ 20,525,056  WsTL @ 25,243,648  pwH @ 29,962,240  pwL @ 34,680,832
//
// TIER3 (adaptive): scores GEMM operand text@comb is hop-INVARIANT (only the
// W_ht bias inside tanh changes per hop). Cache TP = text@comb for
// NSTORE = (ws_size - 20,525,056)/50,331,648 heads (>=1 whenever
// ws >= 70,856,704, which both prior successful runs satisfied). Stored
// heads become a memory-bound tanh-reduce pass per hop; the remaining
// 4-NSTORE heads keep the per-hop MFMA GEMM (on-the-fly f32->split-bf16
// staging, so textH/textL are no longer materialized at all).
// ---------------------------------------------------------------------------

// P: one-time prep (all tiers; scratch sections gated by tier>=2).
__global__ void prep_kernel(const float* __restrict__ WsW, const float* __restrict__ pwb,
                            const float* __restrict__ Wsb, float* __restrict__ combB,
                            const float* __restrict__ question,
                            float* __restrict__ q_f32, float* __restrict__ hT,
                            const float* __restrict__ pwW,
                            u16* __restrict__ WsTH, u16* __restrict__ WsTL,
                            u16* __restrict__ pwH, u16* __restrict__ pwL, int tier)
{
    int bid = blockIdx.x, t = threadIdx.x;
    if (bid < 48) {
        int idx = bid * 64 + (t >> 2);      // 0..3071
        int ph = t & 3;
        int k = idx / NH, j = idx % NH;
        const float* W = WsW + (long)k * HH + j;
        const float* pb = pwb + k * NH;
        float acc = 0.f;
        #pragma unroll 8
        for (int m = ph * 192; m < ph * 192 + 192; ++m)
            acc += pb[m] * W[(long)m * NH];
        acc += __shfl_xor(acc, 1);
        acc += __shfl_xor(acc, 2);
        if (ph == 0) combB[idx] = acc + Wsb[idx];
    } else if (bid < 144) {
        int idx = (bid - 48) * 256 + t;
        q_f32[idx] = question[idx];
    } else if (bid < 240) {
        int idx = (bid - 144) * 256 + t;
        hT[idx] = 0.f;
    } else if (bid < 2544) {
        if (tier < 2) return;
        __shared__ float tile[32][33];
        int bid2 = bid - 240;
        int k = bid2 / 576, rem = bid2 % 576, tr = rem / 24, tc = rem % 24;
        const float* src = WsW + (long)k * HH;
        long dbase = (long)k * HH;
        int tx = t & 31, ty = t >> 5;
        #pragma unroll
        for (int i = 0; i < 4; ++i)
            tile[tx][ty + i*8] = src[(long)(tr*32 + ty + i*8) * NH + tc*32 + tx];
        __syncthreads();
        #pragma unroll
        for (int i = 0; i < 4; ++i) {
            float v = tile[ty + i*8][tx];
            u16 hv = f2bf(v);
            u16 lv = f2bf(v - bf2f(hv));
            long o = dbase + (long)(tc*32 + ty + i*8) * NH + tr*32 + tx;
            WsTH[o] = hv; WsTL[o] = lv;
        }
    } else {
        if (tier < 2) return;
        long base = (long)(bid - 2544) * 1024 + t * 4;
        float4 v = *(const float4*)(pwW + base);
        ushort4 hv, lv;
        hv.x = f2bf(v.x); lv.x = f2bf(v.x - bf2f(hv.x));
        hv.y = f2bf(v.y); lv.y = f2bf(v.y - bf2f(hv.y));
        hv.z = f2bf(v.z); lv.z = f2bf(v.z - bf2f(hv.z));
        hv.w = f2bf(v.w); lv.w = f2bf(v.w - bf2f(hv.w));
        *(ushort4*)(pwH + base) = hv;
        *(ushort4*)(pwL + base) = lv;
    }
}

// combT[k][j][h] = sum_m WsT[k][j][m] * pw[k][h][m], split-bf16 3-MFMA.
__global__ __launch_bounds__(256) void comb_mfma_kernel(
    const u16* __restrict__ WsTH, const u16* __restrict__ WsTL,
    const u16* __restrict__ pwH, const u16* __restrict__ pwL,
    u16* __restrict__ combTH, u16* __restrict__ combTL)
{
    __shared__ __align__(16) u16 AsH[128 * 32];
    __shared__ __align__(16) u16 AsL[128 * 32];
    __shared__ __align__(16) u16 BsH[128 * 32];
    __shared__ __align__(16) u16 BsL[128 * 32];
    const int t = threadIdx.x;
    const int wave = t >> 6, lane = t & 63;
    const int k = blockIdx.z;
    const long m0 = (long)blockIdx.x * 128;   // j-rows
    const int n0 = blockIdx.y * 128;          // h-cols
    const u16* AH = WsTH + (long)k * HH;
    const u16* AL = WsTL + (long)k * HH;
    const u16* BH = pwH + (long)k * HH;
    const u16* BL = pwL + (long)k * HH;

    const int r = t >> 2, ch = t & 3;
    const int wm = (wave & 1) * 64, wn = (wave >> 1) * 64;
    const int fr = lane & 15, fq = lane >> 4;

    f32x4 acc[4][4];
    #pragma unroll
    for (int i = 0; i < 4; ++i)
        #pragma unroll
        for (int j = 0; j < 4; ++j) acc[i][j] = (f32x4){0.f, 0.f, 0.f, 0.f};

    for (int k0 = 0; k0 < NH; k0 += 32) {
        gld16(AH + (m0 + r)      * NH + k0 + ch*8, AsH + t*8);
        gld16(AH + (m0 + 64 + r) * NH + k0 + ch*8, AsH + 2048 + t*8);
        gld16(AL + (m0 + r)      * NH + k0 + ch*8, AsL + t*8);
        gld16(AL + (m0 + 64 + r) * NH + k0 + ch*8, AsL + 2048 + t*8);
        gld16(BH + (long)(n0 + r)      * NH + k0 + ch*8, BsH + t*8);
        gld16(BH + (long)(n0 + 64 + r) * NH + k0 + ch*8, BsH + 2048 + t*8);
        gld16(BL + (long)(n0 + r)      * NH + k0 + ch*8, BsL + t*8);
        gld16(BL + (long)(n0 + 64 + r) * NH + k0 + ch*8, BsL + 2048 + t*8);
        __syncthreads();
        bf16x8 afH[4], afL[4], bfH[4], bfL[4];
        #pragma unroll
        for (int i = 0; i < 4; ++i) {
            afH[i] = *(const bf16x8*)(AsH + (wm + i*16 + fr)*32 + fq*8);
            afL[i] = *(const bf16x8*)(AsL + (wm + i*16 + fr)*32 + fq*8);
            bfH[i] = *(const bf16x8*)(BsH + (wn + i*16 + fr)*32 + fq*8);
            bfL[i] = *(const bf16x8*)(BsL + (wn + i*16 + fr)*32 + fq*8);
        }
        #pragma unroll
        for (int i = 0; i < 4; ++i)
            #pragma unroll
            for (int j = 0; j < 4; ++j) {
                acc[i][j] = __builtin_amdgcn_mfma_f32_16x16x32_bf16(afH[i], bfH[j], acc[i][j], 0, 0, 0);
                acc[i][j] = __builtin_amdgcn_mfma_f32_16x16x32_bf16(afH[i], bfL[j], acc[i][j], 0, 0, 0);
                acc[i][j] = __builtin_amdgcn_mfma_f32_16x16x32_bf16(afL[i], bfH[j], acc[i][j], 0, 0, 0);
            }
        __syncthreads();
    }
    long kb = (long)k * HH;
    #pragma unroll
    for (int i = 0; i < 4; ++i) {
        long m = m0 + wm + i*16 + fq*4;       // j-row
        #pragma unroll
        for (int j = 0; j < 4; ++j) {
            long n = n0 + wn + j*16 + fr;     // h-col
            #pragma unroll
            for (int rr = 0; rr < 4; ++rr) {
                float v = acc[i][j][rr];
                u16 hv = f2bf(v);
                u16 lv = f2bf(v - bf2f(hv));
                combTH[kb + (m + rr) * NH + n] = hv;
                combTL[kb + (m + rr) * NH + n] = lv;
            }
        }
    }
}

// tier 0/1: comb[k][h][j] f32 VALU GEMM (proven R8 kernel).
__global__ __launch_bounds__(256) void comb_valu_kernel(
    const float* __restrict__ pwW, const float* __restrict__ WsW,
    float* __restrict__ comb)
{
    __shared__ float AtT[32][68];
    __shared__ float Bt[32][132];
    const int t = threadIdx.x;
    const int m0 = blockIdx.x * 64, j0 = blockIdx.y * 128, k = blockIdx.z;
    const float* A = pwW + (long)k * HH;
    const float* B = WsW + (long)k * HH;
    const int r4 = (t >> 4) * 4, c8 = (t & 15) * 8;
    float acc[4][8];
    #pragma unroll
    for (int rr = 0; rr < 4; ++rr)
        #pragma unroll
        for (int cc = 0; cc < 8; ++cc) acc[rr][cc] = 0.f;
    for (int h0 = 0; h0 < NH; h0 += 32) {
        #pragma unroll
        for (int p = 0; p < 8; ++p) {
            int idx = p * 256 + t;
            int r = idx >> 5, hh = idx & 31;
            AtT[hh][r] = A[(long)(m0 + r) * NH + h0 + hh];
        }
        #pragma unroll
        for (int p = 0; p < 16; ++p) {
            int idx = p * 256 + t;
            int hh = idx >> 7, c = idx & 127;
            Bt[hh][c] = B[(long)(h0 + hh) * NH + j0 + c];
        }
        __syncthreads();
        for (int hh = 0; hh < 32; ++hh) {
            float4 av  = *(const float4*)&AtT[hh][r4];
            float4 bv0 = *(const float4*)&Bt[hh][c8];
            float4 bv1 = *(const float4*)&Bt[hh][c8 + 4];
            float a[4] = {av.x, av.y, av.z, av.w};
            float bb[8] = {bv0.x, bv0.y, bv0.z, bv0.w, bv1.x, bv1.y, bv1.z, bv1.w};
            #pragma unroll
            for (int rr = 0; rr < 4; ++rr)
                #pragma unroll
                for (int cc = 0; cc < 8; ++cc) acc[rr][cc] += a[rr] * bb[cc];
        }
        __syncthreads();
    }
    float* C = comb + (long)k * HH;
    #pragma unroll
    for (int rr = 0; rr < 4; ++rr)
        #pragma unroll
        for (int cc = 0; cc < 8; ++cc)
            C[(long)(m0 + r4 + rr) * NH + j0 + c8 + cc] = acc[rr][cc];
}

// tier1: transpose+split comb f32 -> combTH/combTL. grid 2304.
__global__ void split_combT_kernel(const float* __restrict__ comb,
                                   u16* __restrict__ combTH, u16* __restrict__ combTL)
{
    __shared__ float tile[32][33];
    int bid = blockIdx.x, t = threadIdx.x;
    int k = bid / 576, rem = bid % 576, tr = rem / 24, tc = rem % 24;
    const float* src = comb + (long)k * HH;
    long dbase = (long)k * HH;
    int tx = t & 31, ty = t >> 5;
    #pragma unroll
    for (int i = 0; i < 4; ++i)
        tile[tx][ty + i*8] = src[(long)(tr*32 + ty + i*8) * NH + tc*32 + tx];
    __syncthreads();
    #pragma unroll
    for (int i = 0; i < 4; ++i) {
        float v = tile[ty + i*8][tx];
        u16 hv = f2bf(v);
        u16 lv = f2bf(v - bf2f(hv));
        long o = dbase + (long)(tc*32 + ty + i*8) * NH + tr*32 + tx;
        combTH[o] = hv; combTL[o] = lv;
    }
}

// TIER3: TP[k][bs][j] = (text @ comb[k])[bs][j] f32, computed ONCE for heads
// [0, NSTORE). A-operand split-bf16 staged on the fly from f32 text (proven
// AM=0 path). grid (128, 6, NSTORE).
__global__ __launch_bounds__(256) void tp_gemm_kernel(
    const float* __restrict__ textf,
    const u16* __restrict__ combTH, const u16* __restrict__ combTL,
    float* __restrict__ TP)
{
    __shared__ __align__(16) u16 AsH[128 * 32];
    __shared__ __align__(16) u16 AsL[128 * 32];
    __shared__ __align__(16) u16 BsH[128 * 32];
    __shared__ __align__(16) u16 BsL[128 * 32];
    const int t = threadIdx.x;
    const int wave = t >> 6, lane = t & 63;
    const int k = blockIdx.z;
    const long m0 = (long)blockIdx.x * 128;   // bs-rows
    const int n0 = blockIdx.y * 128;          // j-cols
    const u16* BH = combTH + (long)k * HH;
    const u16* BL = combTL + (long)k * HH;

    const int r = t >> 2, ch = t & 3;
    const int wm = (wave & 1) * 64, wn = (wave >> 1) * 64;
    const int fr = lane & 15, fq = lane >> 4;

    f32x4 acc[4][4];
    #pragma unroll
    for (int i = 0; i < 4; ++i)
        #pragma unroll
        for (int j = 0; j < 4; ++j) acc[i][j] = (f32x4){0.f, 0.f, 0.f, 0.f};

    for (int h0 = 0; h0 < NH; h0 += 32) {
        #pragma unroll
        for (int p = 0; p < 4; ++p) {
            int task = p * 256 + t;
            int row = task >> 3, g = task & 7;
            float4 v = *(const float4*)(textf + (m0 + row) * NH + h0 + g*4);
            ushort4 hv, lv;
            hv.x = f2bf(v.x); lv.x = f2bf(v.x - bf2f(hv.x));
            hv.y = f2bf(v.y); lv.y = f2bf(v.y - bf2f(hv.y));
            hv.z = f2bf(v.z); lv.z = f2bf(v.z - bf2f(hv.z));
            hv.w = f2bf(v.w); lv.w = f2bf(v.w - bf2f(hv.w));
            *(ushort4*)(AsH + row * 32 + g*4) = hv;
            *(ushort4*)(AsL + row * 32 + g*4) = lv;
        }
        gld16(BH + (long)(n0 + r)      * NH + h0 + ch*8, BsH + t*8);
        gld16(BH + (long)(n0 + 64 + r) * NH + h0 + ch*8, BsH + 2048 + t*8);
        gld16(BL + (long)(n0 + r)      * NH + h0 + ch*8, BsL + t*8);
        gld16(BL + (long)(n0 + 64 + r) * NH + h0 + ch*8, BsL + 2048 + t*8);
        __syncthreads();
        bf16x8 afH[4], afL[4], bfH[4], bfL[4];
        #pragma unroll
        for (int i = 0; i < 4; ++i) {
            afH[i] = *(const bf16x8*)(AsH + (wm + i*16 + fr)*32 + fq*8);
            afL[i] = *(const bf16x8*)(AsL + (wm + i*16 + fr)*32 + fq*8);
            bfH[i] = *(const bf16x8*)(BsH + (wn + i*16 + fr)*32 + fq*8);
            bfL[i] = *(const bf16x8*)(BsL + (wn + i*16 + fr)*32 + fq*8);
        }
        #pragma unroll
        for (int i = 0; i < 4; ++i)
            #pragma unroll
            for (int j = 0; j < 4; ++j) {
                acc[i][j] = __builtin_amdgcn_mfma_f32_16x16x32_bf16(afH[i], bfH[j], acc[i][j], 0, 0, 0);
                acc[i][j] = __builtin_amdgcn_mfma_f32_16x16x32_bf16(afH[i], bfL[j], acc[i][j], 0, 0, 0);
                acc[i][j] = __builtin_amdgcn_mfma_f32_16x16x32_bf16(afL[i], bfH[j], acc[i][j], 0, 0, 0);
            }
        __syncthreads();
    }
    float* out = TP + ((long)k * NBS + m0) * NH + n0;
    #pragma unroll
    for (int i = 0; i < 4; ++i) {
        #pragma unroll
        for (int rr = 0; rr < 4; ++rr) {
            int m = wm + i*16 + fq*4 + rr;
            #pragma unroll
            for (int j = 0; j < 4; ++j) {
                int n = wn + j*16 + fr;
                out[(long)m * NH + n] = acc[i][j][rr];
            }
        }
    }
}

// TIER3 per-hop: scores[k][b][s] = We_b[k] + sum_j tanh(TP + combB + W_ht)*We
// for stored heads k < NSTORE. Memory-bound pass. grid (16, 32, NSTORE).
__global__ __launch_bounds__(256) void score_pass_kernel(
    const float* __restrict__ TP, const float* __restrict__ combB,
    const float* __restrict__ W_ht, const float* __restrict__ WeW,
    const float* __restrict__ Web, float* __restrict__ scores)
{
    __shared__ __align__(16) float bias_s[NH];
    __shared__ __align__(16) float we_s[NH];
    const int t = threadIdx.x;
    const int k = blockIdx.z, b = blockIdx.y;
    const int s0 = blockIdx.x * 32;
    for (int i = t; i < NH; i += 256) {
        bias_s[i] = combB[k * NH + i] + W_ht[((k << 5) + b) * NH + i];
        we_s[i]   = WeW[k * NH + i];
    }
    __syncthreads();
    const int wave = t >> 6, lane = t & 63;
    const float* tpb = TP + ((long)k * NBS + (b << 9) + s0) * NH;
    const float web = Web[k];
    for (int sr = wave; sr < 32; sr += 4) {
        const float* row = tpb + (long)sr * NH;
        float part = 0.f;
        #pragma unroll
        for (int p = 0; p < 3; ++p) {
            const int j = p * 256 + lane * 4;   // lane*16B, conflict-free b128 LDS reads
            float4 v  = *(const float4*)(row + j);
            float4 bb = *(const float4*)(bias_s + j);
            float4 ww = *(const float4*)(we_s + j);
            part += tanhf(v.x + bb.x) * ww.x;
            part += tanhf(v.y + bb.y) * ww.y;
            part += tanhf(v.z + bb.z) * ww.z;
            part += tanhf(v.w + bb.w) * ww.w;
        }
        part += __shfl_xor(part, 1);
        part += __shfl_xor(part, 2);
        part += __shfl_xor(part, 4);
        part += __shfl_xor(part, 8);
        part += __shfl_xor(part, 16);
        part += __shfl_xor(part, 32);
        if (lane == 0) scores[(((k << 5) + b) << 9) + s0 + sr] = part + web;
    }
}

// Per-hop init: scores=We_b (65,536 f), W_ht=Wt_b (98,304 f), sx/sh=0 (147,456 f).
// grid 1216 = 256 + 384 + 576.
__global__ void init_hop_kernel(const float* __restrict__ Web, float* __restrict__ scores,
                                const float* __restrict__ Wtb, float* __restrict__ W_ht,
                                float* __restrict__ sx, float* __restrict__ sh)
{
    int bid = blockIdx.x, t = threadIdx.x;
    if (bid < 256) {
        int idx = bid * 256 + t;              // 65,536
        scores[idx] = Web[idx >> 14];
    } else if (bid < 640) {
        int idx = (bid - 256) * 256 + t;      // 98,304
        int k = idx / 24576, j = idx % NH;
        W_ht[idx] = Wtb[k * NH + j];
    } else {
        int idx = (bid - 640) * 256 + t;      // 147,456 floats total (NOT bytes!)
        if (idx < 73728) sx[idx] = 0.f;
        else sh[idx - 73728] = 0.f;
    }
}

// W_ht partials: grid 1536 = 4k x 32b x 3jt x 4hg; atomicAdd into W_ht.
__global__ void wht2_kernel(const float* __restrict__ q, const float* __restrict__ WtW,
                            float* __restrict__ W_ht)
{
    int bid = blockIdx.x;
    int k = bid / 384, rem = bid % 384, b = rem / 12, rem2 = rem % 12;
    int jt = rem2 / 4, hg = rem2 % 4;
    int j = jt * 256 + threadIdx.x;
    const float* W = WtW + (long)k * HH + j;
    const float* qb = q + b * NH;
    float acc = 0.f;
    #pragma unroll 8
    for (int h = hg * 192; h < hg * 192 + 192; ++h) acc += qb[h] * W[(long)h * NH];
    atomicAdd(&W_ht[(k*NB + b) * NH + j], acc);
}

// ---------------------------------------------------------------------------
// MFMA split-bf16 fused scores (proven R9), head-offset koff.
// grid (128, 6, nheads); processes heads [koff, koff+nheads).
// ---------------------------------------------------------------------------
template <int AM>
__global__ __launch_bounds__(256) void fused_scores_mfma(
    const float* __restrict__ textf,
    const u16* __restrict__ textH, const u16* __restrict__ textL,
    const u16* __restrict__ combTH, const u16* __restrict__ combTL,
    const float* __restrict__ combB, const float* __restrict__ W_ht,
    const float* __restrict__ WeW, float* __restrict__ scores, int koff)
{
    __shared__ __align__(16) u16 AsH[128 * 32];
    __shared__ __align__(16) u16 AsL[128 * 32];
    __shared__ __align__(16) u16 BsH[128 * 32];
    __shared__ __align__(16) u16 BsL[128 * 32];
    __shared__ float wht_s[128];
    __shared__ float we_s[128];
    __shared__ float sred[128];
    const int t = threadIdx.x;
    const int wave = t >> 6, lane = t & 63;
    const int k = koff + blockIdx.z;
    const long m0 = (long)blockIdx.x * 128;
    const int n0 = blockIdx.y * 128;
    const int b = (int)(m0 >> 9), srow = (int)(m0 & 511);
    const u16* BH = combTH + (long)k * HH;
    const u16* BL = combTL + (long)k * HH;

    if (t < 128) {
        wht_s[t] = W_ht[((k << 5) + b) * NH + n0 + t] + combB[k * NH + n0 + t];
        we_s[t]  = WeW[k * NH + n0 + t];
        sred[t]  = 0.f;
    }

    const int r = t >> 2, ch = t & 3;
    const int wm = (wave & 1) * 64, wn = (wave >> 1) * 64;
    const int fr = lane & 15, fq = lane >> 4;

    f32x4 acc[4][4];
    #pragma unroll
    for (int i = 0; i < 4; ++i)
        #pragma unroll
        for (int j = 0; j < 4; ++j) acc[i][j] = (f32x4){0.f, 0.f, 0.f, 0.f};

    for (int h0 = 0; h0 < NH; h0 += 32) {
        if (AM) {
            gld16(textH + (m0 + r)      * NH + h0 + ch*8, AsH + t*8);
            gld16(textH + (m0 + 64 + r) * NH + h0 + ch*8, AsH + 2048 + t*8);
            gld16(textL + (m0 + r)      * NH + h0 + ch*8, AsL + t*8);
            gld16(textL + (m0 + 64 + r) * NH + h0 + ch*8, AsL + 2048 + t*8);
        } else {
            #pragma unroll
            for (int p = 0; p < 4; ++p) {
                int task = p * 256 + t;
                int row = task >> 3, g = task & 7;
                float4 v = *(const float4*)(textf + (m0 + row) * NH + h0 + g*4);
                ushort4 hv, lv;
                hv.x = f2bf(v.x); lv.x = f2bf(v.x - bf2f(hv.x));
                hv.y = f2bf(v.y); lv.y = f2bf(v.y - bf2f(hv.y));
                hv.z = f2bf(v.z); lv.z = f2bf(v.z - bf2f(hv.z));
                hv.w = f2bf(v.w); lv.w = f2bf(v.w - bf2f(hv.w));
                *(ushort4*)(AsH + row * 32 + g*4) = hv;
                *(ushort4*)(AsL + row * 32 + g*4) = lv;
            }
        }
        gld16(BH + (long)(n0 + r)      * NH + h0 + ch*8, BsH + t*8);
        gld16(BH + (long)(n0 + 64 + r) * NH + h0 + ch*8, BsH + 2048 + t*8);
        gld16(BL + (long)(n0 + r)      * NH + h0 + ch*8, BsL + t*8);
        gld16(BL + (long)(n0 + 64 + r) * NH + h0 + ch*8, BsL + 2048 + t*8);
        __syncthreads();
        bf16x8 afH[4], afL[4], bfH[4], bfL[4];
        #pragma unroll
        for (int i = 0; i < 4; ++i) {
            afH[i] = *(const bf16x8*)(AsH + (wm + i*16 + fr)*32 + fq*8);
            afL[i] = *(const bf16x8*)(AsL + (wm + i*16 + fr)*32 + fq*8);
            bfH[i] = *(const bf16x8*)(BsH + (wn + i*16 + fr)*32 + fq*8);
            bfL[i] = *(const bf16x8*)(BsL + (wn + i*16 + fr)*32 + fq*8);
        }
        #pragma unroll
        for (int i = 0; i < 4; ++i)
            #pragma unroll
            for (int j = 0; j < 4; ++j) {
                acc[i][j] = __builtin_amdgcn_mfma_f32_16x16x32_bf16(afH[i], bfH[j], acc[i][j], 0, 0, 0);
                acc[i][j] = __builtin_amdgcn_mfma_f32_16x16x32_bf16(afH[i], bfL[j], acc[i][j], 0, 0, 0);
                acc[i][j] = __builtin_amdgcn_mfma_f32_16x16x32_bf16(afL[i], bfH[j], acc[i][j], 0, 0, 0);
            }
        __syncthreads();
    }
    #pragma unroll
    for (int i = 0; i < 4; ++i) {
        #pragma unroll
        for (int rr = 0; rr < 4; ++rr) {
            int m = wm + i*16 + fq*4 + rr;
            float part = 0.f;
            #pragma unroll
            for (int j = 0; j < 4; ++j) {
                int n = wn + j*16 + fr;
                part += tanhf(acc[i][j][rr] + wht_s[n]) * we_s[n];
            }
            part += __shfl_xor(part, 1);
            part += __shfl_xor(part, 2);
            part += __shfl_xor(part, 4);
            part += __shfl_xor(part, 8);
            if (fr == 0) atomicAdd(&sred[m], part);
        }
    }
    __syncthreads();
    if (t < 128)
        atomicAdd(&scores[(((k << 5) + b) << 9) + srow + t], sred[t]);
}

// tier0 fallback (proven R8). grid (256, 6, 4).
__global__ __launch_bounds__(256) void fused_scores_valu(
    const float* __restrict__ text, const float* __restrict__ comb,
    const float* __restrict__ combB, const float* __restrict__ W_ht,
    const float* __restrict__ WeW, float* __restrict__ scores)
{
    __shared__ float AtT[32][68];
    __shared__ float Bt[32][132];
    __shared__ float wht_s[128];
    __shared__ float we_s[128];
    __shared__ float sred[64];
    const int t = threadIdx.x;
    const int row0 = blockIdx.x * 64;
    const int j0 = blockIdx.y * 128, k = blockIdx.z;
    const int b = row0 >> 9, s0 = row0 & 511;
    const float* B = comb + (long)k * HH;
    const int r4 = (t >> 4) * 4, c8 = (t & 15) * 8;
    if (t < 128) {
        wht_s[t] = W_ht[((k << 5) + b) * NH + j0 + t] + combB[k * NH + j0 + t];
        we_s[t]  = WeW[k * NH + j0 + t];
    }
    if (t < 64) sred[t] = 0.f;
    float acc[4][8];
    #pragma unroll
    for (int rr = 0; rr < 4; ++rr)
        #pragma unroll
        for (int cc = 0; cc < 8; ++cc) acc[rr][cc] = 0.f;
    for (int h0 = 0; h0 < NH; h0 += 32) {
        #pragma unroll
        for (int p = 0; p < 8; ++p) {
            int idx = p * 256 + t;
            int r = idx >> 5, hh = idx & 31;
            AtT[hh][r] = text[(long)(row0 + r) * NH + h0 + hh];
        }
        #pragma unroll
        for (int p = 0; p < 16; ++p) {
            int idx = p * 256 + t;
            int hh = idx >> 7, c = idx & 127;
            Bt[hh][c] = B[(long)(h0 + hh) * NH + j0 + c];
        }
        __syncthreads();
        for (int hh = 0; hh < 32; ++hh) {
            float4 av  = *(const float4*)&AtT[hh][r4];
            float4 bv0 = *(const float4*)&Bt[hh][c8];
            float4 bv1 = *(const float4*)&Bt[hh][c8 + 4];
            float a[4] = {av.x, av.y, av.z, av.w};
            float bb[8] = {bv0.x, bv0.y, bv0.z, bv0.w, bv1.x, bv1.y, bv1.z, bv1.w};
            #pragma unroll
            for (int rr = 0; rr < 4; ++rr)
                #pragma unroll
                for (int cc = 0; cc < 8; ++cc) acc[rr][cc] += a[rr] * bb[cc];
        }
        __syncthreads();
    }
    float part[4] = {0.f, 0.f, 0.f, 0.f};
    #pragma unroll
    for (int rr = 0; rr < 4; ++rr)
        #pragma unroll
        for (int cc = 0; cc < 8; ++cc)
            part[rr] += tanhf(acc[rr][cc] + wht_s[c8 + cc]) * we_s[c8 + cc];
    #pragma unroll
    for (int rr = 0; rr < 4; ++rr)
        atomicAdd(&sred[r4 + rr], part[rr]);
    __syncthreads();
    if (t < 64)
        atomicAdd(&scores[(((k << 5) + b) << 9) + s0 + t], sred[t]);
}

__global__ void softmax_kernel(const float* __restrict__ scores,
                               const float* __restrict__ headw_W, const float* __restrict__ headw_b,
                               const float* __restrict__ text,
                               const float* __restrict__ q_f32,
                               float* __restrict__ xT, float* __restrict__ out_prob, int hop)
{
    __shared__ float sc[NK][NS];
    __shared__ float red[256];
    __shared__ float rv[256];
    __shared__ int   ri[256];
    int b = blockIdx.x, t = threadIdx.x;
    for (int i = t; i < NK * NS; i += 256) {
        int k = i >> 9, s = i & 511;
        sc[k][s] = scores[((k*NB + b) << 9) + s];
    }
    __syncthreads();
    float fac[NK];
    for (int k = 0; k < NK; ++k) {
        float v0 = sc[k][t], v1 = sc[k][t + 256];
        red[t] = fmaxf(v0, v1);
        __syncthreads();
        for (int o = 128; o > 0; o >>= 1) { if (t < o) red[t] = fmaxf(red[t], red[t + o]); __syncthreads(); }
        float mx = red[0];
        __syncthreads();
        float e0 = expf(v0 - mx), e1 = expf(v1 - mx);
        sc[k][t] = e0; sc[k][t + 256] = e1;
        red[t] = e0 + e1;
        __syncthreads();
        for (int o = 128; o > 0; o >>= 1) { if (t < o) red[t] += red[t + o]; __syncthreads(); }
        fac[k] = headw_W[k] / red[0];
        __syncthreads();
    }
    float hwb = headw_b[0];
    float a0 = hwb, a1 = hwb;
    for (int k = 0; k < NK; ++k) { a0 += sc[k][t] * fac[k]; a1 += sc[k][t + 256] * fac[k]; }
    red[t] = a0*a0 + a1*a1;
    float bv; int bi;
    if (a0 >= a1) { bv = a0; bi = t; } else { bv = a1; bi = t + 256; }
    rv[t] = bv; ri[t] = bi;
    __syncthreads();
    for (int o = 128; o > 0; o >>= 1) {
        if (t < o) {
            red[t] += red[t + o];
            if (rv[t + o] > rv[t] || (rv[t + o] == rv[t] && ri[t + o] < ri[t])) { rv[t] = rv[t + o]; ri[t] = ri[t + o]; }
        }
        __syncthreads();
    }
    float scale = sqrtf(red[0]);
    int idx = ri[0];
    if (hop == 0) {
        out_prob[(b << 9) + t]       = a0 / scale;
        out_prob[(b << 9) + t + 256] = a1 / scale;
    }
    const float* trow = text + (long)(b * NS + idx) * NH;
    for (int i = t; i < NH; i += 256) {
        xT[i * NB + b]        = q_f32[b*NH + i];
        xT[(NH + i) * NB + b] = trow[i];
    }
}

// GRU matvec partials: grid (36 j-tiles, 3 c-groups); atomicAdd into sx/sh.
__global__ __launch_bounds__(256) void gru_mm3_kernel(
    const float* __restrict__ Wih, const float* __restrict__ Whh,
    const float* __restrict__ xT, const float* __restrict__ hT,
    float* __restrict__ sx, float* __restrict__ sh)
{
    __shared__ float xs[8192];
    int t = threadIdx.x;
    int tj = t & 63, tq = t >> 6;
    int j = blockIdx.x * 64 + tj;
    int cg = blockIdx.y;
    float acc[8];
    #pragma unroll
    for (int bq = 0; bq < 8; ++bq) acc[bq] = 0.f;
    for (int c = cg * 2; c < cg * 2 + 2; ++c) {
        for (int idx = t; idx < 8192; idx += 256) xs[idx] = xT[c * 8192 + idx];
        __syncthreads();
        #pragma unroll 8
        for (int ii = 0; ii < 256; ++ii) {
            float w = Wih[(long)(c * 256 + ii) * H3 + j];
            #pragma unroll
            for (int bq = 0; bq < 8; ++bq) acc[bq] += xs[ii * 32 + tq * 8 + bq] * w;
        }
        __syncthreads();
    }
    #pragma unroll
    for (int bq = 0; bq < 8; ++bq)
        atomicAdd(&sx[(long)(tq * 8 + bq) * H3 + j], acc[bq]);
    #pragma unroll
    for (int bq = 0; bq < 8; ++bq) acc[bq] = 0.f;
    {
        int c = cg;
        for (int idx = t; idx < 8192; idx += 256) xs[idx] = hT[c * 8192 + idx];
        __syncthreads();
        #pragma unroll 8
        for (int ii = 0; ii < 256; ++ii) {
            float w = Whh[(long)(c * 256 + ii) * H3 + j];
            #pragma unroll
            for (int bq = 0; bq < 8; ++bq) acc[bq] += xs[ii * 32 + tq * 8 + bq] * w;
        }
    }
    #pragma unroll
    for (int bq = 0; bq < 8; ++bq)
        atomicAdd(&sh[(long)(tq * 8 + bq) * H3 + j], acc[bq]);
}

__global__ void gate_kernel(const float* __restrict__ sx, const float* __restrict__ sh,
                            const float* __restrict__ bih, const float* __restrict__ bhh,
                            float* __restrict__ hT, float* __restrict__ q_f32,
                            float* __restrict__ out_h, int hop)
{
    int gid = blockIdx.x * 256 + threadIdx.x;
    int b = gid / NH, j = gid % NH;
    float xr = bih[j]        + sx[b*H3 + j];
    float xz = bih[NH + j]   + sx[b*H3 + NH + j];
    float xn = bih[1536 + j] + sx[b*H3 + 1536 + j];
    float hr = bhh[j]        + sh[b*H3 + j];
    float hz = bhh[NH + j]   + sh[b*H3 + NH + j];
    float hn = bhh[1536 + j] + sh[b*H3 + 1536 + j];
    float r = 1.f / (1.f + expf(-(xr + hr)));
    float z = 1.f / (1.f + expf(-(xz + hz)));
    float n = tanhf(xn + r * hn);
    float hp = hT[j * NB + b];
    float hnew = (1.f - z) * n + z * hp;
    hT[j * NB + b] = hnew;
    q_f32[gid] = hnew;
    out_h[(long)(b * 3 + hop) * NH + j] = hnew;
}

// ---------------------------------------------------------------------------
extern "C" void kernel_launch(void* const* d_in, const int* in_sizes, int n_in,
                              void* d_out, int out_size, void* d_ws, size_t ws_size,
                              hipStream_t stream)
{
    const float* question = (const float*)d_in[0];
    const float* text     = (const float*)d_in[1];
    const float* pw_W     = (const float*)d_in[2];
    const float* pw_b     = (const float*)d_in[3];
    const float* Ws_W     = (const float*)d_in[4];
    const float* Ws_b     = (const float*)d_in[5];
    const float* Wt_W     = (const float*)d_in[6];
    const float* Wt_b     = (const float*)d_in[7];
    const float* We_W     = (const float*)d_in[8];
    const float* We_b     = (const float*)d_in[9];
    const float* headw_W  = (const float*)d_in[10];
    const float* headw_b  = (const float*)d_in[11];
    const float* Wih      = (const float*)d_in[12];
    const float* Whh      = (const float*)d_in[13];
    const float* bih      = (const float*)d_in[14];
    const float* bhh      = (const float*)d_in[15];

    char* ws = (char*)d_ws;
    float* comb   = (float*)(ws + 0);
    float* combB  = (float*)(ws + 9437184);
    float* W_ht   = (float*)(ws + 9449472);
    float* scores = (float*)(ws + 9842688);
    float* q_f32  = (float*)(ws + 10104832);
    float* hT     = (float*)(ws + 10203136);
    float* xT     = (float*)(ws + 10301440);
    float* sx     = (float*)(ws + 10498048);
    float* sh     = (float*)(ws + 10792960);
    u16*   combTH = (u16*)  (ws + 11087872);
    u16*   combTL = (u16*)  (ws + 15806464);
    float* TP     = (float*)(ws + 20525056);
    // prep scratch overlaid on TP region (dead before tp_gemm runs):
    u16*   WsTH   = (u16*)  (ws + 20525056);
    u16*   WsTL   = (u16*)  (ws + 25243648);
    u16*   pwH    = (u16*)  (ws + 29962240);
    u16*   pwL    = (u16*)  (ws + 34680832);

    // NSTORE heads of TP fit in (ws - 20,525,056); prep scratch needs
    // 18.9 MB of that region (>= 1 head's 50.3 MB, so always covered).
    int nstore = 0;
    if (ws_size >= (size_t)70856704) {
        long avail = (long)ws_size - 20525056L;
        nstore = (int)(avail / 50331648L);
        if (nstore > NK) nstore = NK;
    }
    const int tier = (nstore >= 1) ? 3
                   : (ws_size >= (size_t)20525056) ? 1 : 0;

    float* out_prob = (float*)d_out;
    float* out_h    = (float*)d_out + NB * NS;

    prep_kernel<<<4848, 256, 0, stream>>>(Ws_W, pw_b, Ws_b, combB, question, q_f32, hT,
                                          pw_W, WsTH, WsTL, pwH, pwL, tier >= 3 ? 2 : tier);
    if (tier == 3) {
        comb_mfma_kernel<<<dim3(6, 6, 4), 256, 0, stream>>>(WsTH, WsTL, pwH, pwL,
                                                            combTH, combTL);
        // scratch dead from here; TP overwrites it.
        tp_gemm_kernel<<<dim3(128, 6, nstore), 256, 0, stream>>>(text, combTH, combTL, TP);
    } else {
        comb_valu_kernel<<<dim3(12, 6, 4), 256, 0, stream>>>(pw_W, Ws_W, comb);
        if (tier == 1)
            split_combT_kernel<<<2304, 256, 0, stream>>>(comb, combTH, combTL);
    }

    for (int hop = 0; hop < 3; ++hop) {
        init_hop_kernel<<<1216, 256, 0, stream>>>(We_b, scores, Wt_b, W_ht, sx, sh);
        wht2_kernel<<<1536, 256, 0, stream>>>(q_f32, Wt_W, W_ht);
        if (tier == 3) {
            score_pass_kernel<<<dim3(16, 32, nstore), 256, 0, stream>>>(
                TP, combB, W_ht, We_W, We_b, scores);
            if (nstore < NK)
                fused_scores_mfma<0><<<dim3(128, 6, NK - nstore), 256, 0, stream>>>(
                    text, nullptr, nullptr, combTH, combTL, combB, W_ht, We_W,
                    scores, nstore);
        } else if (tier == 1) {
            fused_scores_mfma<0><<<dim3(128, 6, 4), 256, 0, stream>>>(
                text, nullptr, nullptr, combTH, combTL, combB, W_ht, We_W, scores, 0);
        } else {
            fused_scores_valu<<<dim3(256, 6, 4), 256, 0, stream>>>(
                text, comb, combB, W_ht, We_W, scores);
        }
        softmax_kernel<<<32, 256, 0, stream>>>(scores, headw_W, headw_b, text,
                                               q_f32, xT, out_prob, hop);
        gru_mm3_kernel<<<dim3(36, 3), 256, 0, stream>>>(Wih, Whh, xT, hT, sx, sh);
        gate_kernel<<<96, 256, 0, stream>>>(sx, sh, bih, bhh, hT, q_f32, out_h, hop);
    }
}

// Round 4
// 733.669 us; speedup vs baseline: 1.6804x; 1.1258x over previous
//
#include <hip/hip_runtime.h>

typedef unsigned short u16;
typedef __bf16 bf16x8 __attribute__((ext_vector_type(8)));
typedef float f32x4 __attribute__((ext_vector_type(4)));

#define NB 32          // batch
#define NS 512         // seq
#define NH 768         // hidden
#define NK 4           // heads
#define NBS 16384      // B*S
#define H3 2304        // 3H
#define HH 589824      // 768*768

__device__ inline float bf2f(u16 u) {
    unsigned x = ((unsigned)u) << 16;
    return __builtin_bit_cast(float, x);
}
__device__ inline u16 f2bf(float f) {
    unsigned u = __builtin_bit_cast(unsigned, f);
    u += 0x7fffu + ((u >> 16) & 1u);
    return (u16)(u >> 16);
}
// async global->LDS, 16B/lane; LDS dst = wave-uniform base + lane*16 (m97 recipe).
__device__ inline void gld16(const u16* g, u16* l) {
    __builtin_amdgcn_global_load_lds(
        (const __attribute__((address_space(1))) unsigned int*)g,
        (__attribute__((address_space(3))) unsigned int*)l, 16, 0, 0);
}

// ---------------------------------------------------------------------------
// Workspace layout (bytes):
//  comb    @ 0           9,437,184  f32 [4][768(h)][768(j)]  (tier 0/1 only)
//  combB   @ 9,437,184      12,288  f32 [4][768]
//  W_ht    @ 9,449,472     393,216  f32 [4][32][768]
//  scores  @ 9,842,688     262,144  f32 [4][32][512]
//  q_f32   @ 10,104,832     98,304  f32 [32][768]
//  hT      @ 10,203,136     98,304  f32 [768][32]
//  xT      @ 10,301,440    196,608  f32 [1536][32]
//  sx      @ 10,498,048    294,912  f32 [32][2304]
//  sh      @ 10,792,960    294,912  f32 [32][2304]  -> 11,087,872
//  combTH  @ 11,087,872   4,718,592 bf16 [4][j][h] hi
//  combTL  @ 15,806,464   4,718,592 bf16 [4][j][h] lo   -> 20,525,056  TIER1
//  TP      @ 20,525,056   NSTORE x 25,165,824 bf16 [k][bs][j]  (TIER3)
//  TIER3 prep scratch overlaid on TP region (consumed by comb_mfma BEFORE
//  tp_gemm writes TP):
//   WsTH @ 20,525,056  WsTL @ 25,243,648  pwH @ 29,962,240  pwL @ 34,680,832
//
// TIER3 (adaptive): scores GEMM operand text@comb is hop-INVARIANT (only the
// W_ht bias inside tanh changes per hop). Cache TP = text@comb as bf16 for
// NSTORE = (ws_size - 20,525,056)/25,165,824 heads (>=2 whenever
// ws >= 70,856,704; measured R3 ran f32 NSTORE=4 => ws >= 221.9 MB => 4 here).
// bf16 TP adds ~6e-4 abs to the tanh argument (TP ~0.3 magnitude) -> scores
// shift ~2e-4 -> argmax-stable, predict_prob shift ~1e-5. Given that budget,
// tp_gemm also drops the textL(A-lo) split term (same error order) => 2 MFMA
// per tile instead of 3 and half the A-conversion VALU.
// ---------------------------------------------------------------------------

// P: one-time prep (all tiers; scratch sections gated by tier>=2).
__global__ void prep_kernel(const float* __restrict__ WsW, const float* __restrict__ pwb,
                            const float* __restrict__ Wsb, float* __restrict__ combB,
                            const float* __restrict__ question,
                            float* __restrict__ q_f32, float* __restrict__ hT,
                            const float* __restrict__ pwW,
                            u16* __restrict__ WsTH, u16* __restrict__ WsTL,
                            u16* __restrict__ pwH, u16* __restrict__ pwL, int tier)
{
    int bid = blockIdx.x, t = threadIdx.x;
    if (bid < 48) {
        int idx = bid * 64 + (t >> 2);      // 0..3071
        int ph = t & 3;
        int k = idx / NH, j = idx % NH;
        const float* W = WsW + (long)k * HH + j;
        const float* pb = pwb + k * NH;
        float acc = 0.f;
        #pragma unroll 8
        for (int m = ph * 192; m < ph * 192 + 192; ++m)
            acc += pb[m] * W[(long)m * NH];
        acc += __shfl_xor(acc, 1);
        acc += __shfl_xor(acc, 2);
        if (ph == 0) combB[idx] = acc + Wsb[idx];
    } else if (bid < 144) {
        int idx = (bid - 48) * 256 + t;
        q_f32[idx] = question[idx];
    } else if (bid < 240) {
        int idx = (bid - 144) * 256 + t;
        hT[idx] = 0.f;
    } else if (bid < 2544) {
        if (tier < 2) return;
        __shared__ float tile[32][33];
        int bid2 = bid - 240;
        int k = bid2 / 576, rem = bid2 % 576, tr = rem / 24, tc = rem % 24;
        const float* src = WsW + (long)k * HH;
        long dbase = (long)k * HH;
        int tx = t & 31, ty = t >> 5;
        #pragma unroll
        for (int i = 0; i < 4; ++i)
            tile[tx][ty + i*8] = src[(long)(tr*32 + ty + i*8) * NH + tc*32 + tx];
        __syncthreads();
        #pragma unroll
        for (int i = 0; i < 4; ++i) {
            float v = tile[ty + i*8][tx];
            u16 hv = f2bf(v);
            u16 lv = f2bf(v - bf2f(hv));
            long o = dbase + (long)(tc*32 + ty + i*8) * NH + tr*32 + tx;
            WsTH[o] = hv; WsTL[o] = lv;
        }
    } else {
        if (tier < 2) return;
        long base = (long)(bid - 2544) * 1024 + t * 4;
        float4 v = *(const float4*)(pwW + base);
        ushort4 hv, lv;
        hv.x = f2bf(v.x); lv.x = f2bf(v.x - bf2f(hv.x));
        hv.y = f2bf(v.y); lv.y = f2bf(v.y - bf2f(hv.y));
        hv.z = f2bf(v.z); lv.z = f2bf(v.z - bf2f(hv.z));
        hv.w = f2bf(v.w); lv.w = f2bf(v.w - bf2f(hv.w));
        *(ushort4*)(pwH + base) = hv;
        *(ushort4*)(pwL + base) = lv;
    }
}

// combT[k][j][h] = sum_m WsT[k][j][m] * pw[k][h][m], split-bf16 3-MFMA.
__global__ __launch_bounds__(256) void comb_mfma_kernel(
    const u16* __restrict__ WsTH, const u16* __restrict__ WsTL,
    const u16* __restrict__ pwH, const u16* __restrict__ pwL,
    u16* __restrict__ combTH, u16* __restrict__ combTL)
{
    __shared__ __align__(16) u16 AsH[128 * 32];
    __shared__ __align__(16) u16 AsL[128 * 32];
    __shared__ __align__(16) u16 BsH[128 * 32];
    __shared__ __align__(16) u16 BsL[128 * 32];
    const int t = threadIdx.x;
    const int wave = t >> 6, lane = t & 63;
    const int k = blockIdx.z;
    const long m0 = (long)blockIdx.x * 128;   // j-rows
    const int n0 = blockIdx.y * 128;          // h-cols
    const u16* AH = WsTH + (long)k * HH;
    const u16* AL = WsTL + (long)k * HH;
    const u16* BH = pwH + (long)k * HH;
    const u16* BL = pwL + (long)k * HH;

    const int r = t >> 2, ch = t & 3;
    const int wm = (wave & 1) * 64, wn = (wave >> 1) * 64;
    const int fr = lane & 15, fq = lane >> 4;

    f32x4 acc[4][4];
    #pragma unroll
    for (int i = 0; i < 4; ++i)
        #pragma unroll
        for (int j = 0; j < 4; ++j) acc[i][j] = (f32x4){0.f, 0.f, 0.f, 0.f};

    for (int k0 = 0; k0 < NH; k0 += 32) {
        gld16(AH + (m0 + r)      * NH + k0 + ch*8, AsH + t*8);
        gld16(AH + (m0 + 64 + r) * NH + k0 + ch*8, AsH + 2048 + t*8);
        gld16(AL + (m0 + r)      * NH + k0 + ch*8, AsL + t*8);
        gld16(AL + (m0 + 64 + r) * NH + k0 + ch*8, AsL + 2048 + t*8);
        gld16(BH + (long)(n0 + r)      * NH + k0 + ch*8, BsH + t*8);
        gld16(BH + (long)(n0 + 64 + r) * NH + k0 + ch*8, BsH + 2048 + t*8);
        gld16(BL + (long)(n0 + r)      * NH + k0 + ch*8, BsL + t*8);
        gld16(BL + (long)(n0 + 64 + r) * NH + k0 + ch*8, BsL + 2048 + t*8);
        __syncthreads();
        bf16x8 afH[4], afL[4], bfH[4], bfL[4];
        #pragma unroll
        for (int i = 0; i < 4; ++i) {
            afH[i] = *(const bf16x8*)(AsH + (wm + i*16 + fr)*32 + fq*8);
            afL[i] = *(const bf16x8*)(AsL + (wm + i*16 + fr)*32 + fq*8);
            bfH[i] = *(const bf16x8*)(BsH + (wn + i*16 + fr)*32 + fq*8);
            bfL[i] = *(const bf16x8*)(BsL + (wn + i*16 + fr)*32 + fq*8);
        }
        #pragma unroll
        for (int i = 0; i < 4; ++i)
            #pragma unroll
            for (int j = 0; j < 4; ++j) {
                acc[i][j] = __builtin_amdgcn_mfma_f32_16x16x32_bf16(afH[i], bfH[j], acc[i][j], 0, 0, 0);
                acc[i][j] = __builtin_amdgcn_mfma_f32_16x16x32_bf16(afH[i], bfL[j], acc[i][j], 0, 0, 0);
                acc[i][j] = __builtin_amdgcn_mfma_f32_16x16x32_bf16(afL[i], bfH[j], acc[i][j], 0, 0, 0);
            }
        __syncthreads();
    }
    long kb = (long)k * HH;
    #pragma unroll
    for (int i = 0; i < 4; ++i) {
        long m = m0 + wm + i*16 + fq*4;       // j-row
        #pragma unroll
        for (int j = 0; j < 4; ++j) {
            long n = n0 + wn + j*16 + fr;     // h-col
            #pragma unroll
            for (int rr = 0; rr < 4; ++rr) {
                float v = acc[i][j][rr];
                u16 hv = f2bf(v);
                u16 lv = f2bf(v - bf2f(hv));
                combTH[kb + (m + rr) * NH + n] = hv;
                combTL[kb + (m + rr) * NH + n] = lv;
            }
        }
    }
}

// tier 0/1: comb[k][h][j] f32 VALU GEMM (proven R8 kernel).
__global__ __launch_bounds__(256) void comb_valu_kernel(
    const float* __restrict__ pwW, const float* __restrict__ WsW,
    float* __restrict__ comb)
{
    __shared__ float AtT[32][68];
    __shared__ float Bt[32][132];
    const int t = threadIdx.x;
    const int m0 = blockIdx.x * 64, j0 = blockIdx.y * 128, k = blockIdx.z;
    const float* A = pwW + (long)k * HH;
    const float* B = WsW + (long)k * HH;
    const int r4 = (t >> 4) * 4, c8 = (t & 15) * 8;
    float acc[4][8];
    #pragma unroll
    for (int rr = 0; rr < 4; ++rr)
        #pragma unroll
        for (int cc = 0; cc < 8; ++cc) acc[rr][cc] = 0.f;
    for (int h0 = 0; h0 < NH; h0 += 32) {
        #pragma unroll
        for (int p = 0; p < 8; ++p) {
            int idx = p * 256 + t;
            int r = idx >> 5, hh = idx & 31;
            AtT[hh][r] = A[(long)(m0 + r) * NH + h0 + hh];
        }
        #pragma unroll
        for (int p = 0; p < 16; ++p) {
            int idx = p * 256 + t;
            int hh = idx >> 7, c = idx & 127;
            Bt[hh][c] = B[(long)(h0 + hh) * NH + j0 + c];
        }
        __syncthreads();
        for (int hh = 0; hh < 32; ++hh) {
            float4 av  = *(const float4*)&AtT[hh][r4];
            float4 bv0 = *(const float4*)&Bt[hh][c8];
            float4 bv1 = *(const float4*)&Bt[hh][c8 + 4];
            float a[4] = {av.x, av.y, av.z, av.w};
            float bb[8] = {bv0.x, bv0.y, bv0.z, bv0.w, bv1.x, bv1.y, bv1.z, bv1.w};
            #pragma unroll
            for (int rr = 0; rr < 4; ++rr)
                #pragma unroll
                for (int cc = 0; cc < 8; ++cc) acc[rr][cc] += a[rr] * bb[cc];
        }
        __syncthreads();
    }
    float* C = comb + (long)k * HH;
    #pragma unroll
    for (int rr = 0; rr < 4; ++rr)
        #pragma unroll
        for (int cc = 0; cc < 8; ++cc)
            C[(long)(m0 + r4 + rr) * NH + j0 + c8 + cc] = acc[rr][cc];
}

// tier1: transpose+split comb f32 -> combTH/combTL. grid 2304.
__global__ void split_combT_kernel(const float* __restrict__ comb,
                                   u16* __restrict__ combTH, u16* __restrict__ combTL)
{
    __shared__ float tile[32][33];
    int bid = blockIdx.x, t = threadIdx.x;
    int k = bid / 576, rem = bid % 576, tr = rem / 24, tc = rem % 24;
    const float* src = comb + (long)k * HH;
    long dbase = (long)k * HH;
    int tx = t & 31, ty = t >> 5;
    #pragma unroll
    for (int i = 0; i < 4; ++i)
        tile[tx][ty + i*8] = src[(long)(tr*32 + ty + i*8) * NH + tc*32 + tx];
    __syncthreads();
    #pragma unroll
    for (int i = 0; i < 4; ++i) {
        float v = tile[ty + i*8][tx];
        u16 hv = f2bf(v);
        u16 lv = f2bf(v - bf2f(hv));
        long o = dbase + (long)(tc*32 + ty + i*8) * NH + tr*32 + tx;
        combTH[o] = hv; combTL[o] = lv;
    }
}

// TIER3: TP[k][bs][j] = bf16((text @ comb[k])[bs][j]), computed ONCE for heads
// [0, NSTORE). A = bf16(text) on the fly (hi only; lo term below bf16-TP
// quantization); B split hi/lo (2 MFMA). grid (128, 6, NSTORE).
__global__ __launch_bounds__(256) void tp_gemm_kernel(
    const float* __restrict__ textf,
    const u16* __restrict__ combTH, const u16* __restrict__ combTL,
    u16* __restrict__ TP)
{
    __shared__ __align__(16) u16 AsH[128 * 32];
    __shared__ __align__(16) u16 BsH[128 * 32];
    __shared__ __align__(16) u16 BsL[128 * 32];
    const int t = threadIdx.x;
    const int wave = t >> 6, lane = t & 63;
    const int k = blockIdx.z;
    const long m0 = (long)blockIdx.x * 128;   // bs-rows
    const int n0 = blockIdx.y * 128;          // j-cols
    const u16* BH = combTH + (long)k * HH;
    const u16* BL = combTL + (long)k * HH;

    const int r = t >> 2, ch = t & 3;
    const int wm = (wave & 1) * 64, wn = (wave >> 1) * 64;
    const int fr = lane & 15, fq = lane >> 4;

    f32x4 acc[4][4];
    #pragma unroll
    for (int i = 0; i < 4; ++i)
        #pragma unroll
        for (int j = 0; j < 4; ++j) acc[i][j] = (f32x4){0.f, 0.f, 0.f, 0.f};

    for (int h0 = 0; h0 < NH; h0 += 32) {
        #pragma unroll
        for (int p = 0; p < 4; ++p) {
            int task = p * 256 + t;
            int row = task >> 3, g = task & 7;
            float4 v = *(const float4*)(textf + (m0 + row) * NH + h0 + g*4);
            ushort4 hv;
            hv.x = f2bf(v.x);
            hv.y = f2bf(v.y);
            hv.z = f2bf(v.z);
            hv.w = f2bf(v.w);
            *(ushort4*)(AsH + row * 32 + g*4) = hv;
        }
        gld16(BH + (long)(n0 + r)      * NH + h0 + ch*8, BsH + t*8);
        gld16(BH + (long)(n0 + 64 + r) * NH + h0 + ch*8, BsH + 2048 + t*8);
        gld16(BL + (long)(n0 + r)      * NH + h0 + ch*8, BsL + t*8);
        gld16(BL + (long)(n0 + 64 + r) * NH + h0 + ch*8, BsL + 2048 + t*8);
        __syncthreads();
        bf16x8 afH[4], bfH[4], bfL[4];
        #pragma unroll
        for (int i = 0; i < 4; ++i) {
            afH[i] = *(const bf16x8*)(AsH + (wm + i*16 + fr)*32 + fq*8);
            bfH[i] = *(const bf16x8*)(BsH + (wn + i*16 + fr)*32 + fq*8);
            bfL[i] = *(const bf16x8*)(BsL + (wn + i*16 + fr)*32 + fq*8);
        }
        #pragma unroll
        for (int i = 0; i < 4; ++i)
            #pragma unroll
            for (int j = 0; j < 4; ++j) {
                acc[i][j] = __builtin_amdgcn_mfma_f32_16x16x32_bf16(afH[i], bfH[j], acc[i][j], 0, 0, 0);
                acc[i][j] = __builtin_amdgcn_mfma_f32_16x16x32_bf16(afH[i], bfL[j], acc[i][j], 0, 0, 0);
            }
        __syncthreads();
    }
    u16* out = TP + ((long)k * NBS + m0) * NH + n0;
    #pragma unroll
    for (int i = 0; i < 4; ++i) {
        #pragma unroll
        for (int rr = 0; rr < 4; ++rr) {
            int m = wm + i*16 + fq*4 + rr;
            #pragma unroll
            for (int j = 0; j < 4; ++j) {
                int n = wn + j*16 + fr;
                out[(long)m * NH + n] = f2bf(acc[i][j][rr]);
            }
        }
    }
}

// TIER3 per-hop: scores[k][b][s] = We_b[k] + sum_j tanh(TP + combB + W_ht)*We
// for stored heads k < NSTORE. Memory-bound bf16 pass. grid (16, 32, NSTORE).
__global__ __launch_bounds__(256) void score_pass_kernel(
    const u16* __restrict__ TP, const float* __restrict__ combB,
    const float* __restrict__ W_ht, const float* __restrict__ WeW,
    const float* __restrict__ Web, float* __restrict__ scores)
{
    __shared__ __align__(16) float bias_s[NH];
    __shared__ __align__(16) float we_s[NH];
    const int t = threadIdx.x;
    const int k = blockIdx.z, b = blockIdx.y;
    const int s0 = blockIdx.x * 32;
    for (int i = t; i < NH; i += 256) {
        bias_s[i] = combB[k * NH + i] + W_ht[((k << 5) + b) * NH + i];
        we_s[i]   = WeW[k * NH + i];
    }
    __syncthreads();
    const int wave = t >> 6, lane = t & 63;
    const u16* tpb = TP + ((long)k * NBS + (b << 9) + s0) * NH;
    const float web = Web[k];
    for (int sr = wave; sr < 32; sr += 4) {
        const u16* row = tpb + (long)sr * NH;
        float part = 0.f;
        #pragma unroll
        for (int p = 0; p < 3; ++p) {
            const int j = p * 256 + lane * 4;   // 8B/lane bf16 loads, coalesced 512B
            ushort4 v = *(const ushort4*)(row + j);
            float4 bb = *(const float4*)(bias_s + j);
            float4 ww = *(const float4*)(we_s + j);
            part += tanhf(bf2f(v.x) + bb.x) * ww.x;
            part += tanhf(bf2f(v.y) + bb.y) * ww.y;
            part += tanhf(bf2f(v.z) + bb.z) * ww.z;
            part += tanhf(bf2f(v.w) + bb.w) * ww.w;
        }
        part += __shfl_xor(part, 1);
        part += __shfl_xor(part, 2);
        part += __shfl_xor(part, 4);
        part += __shfl_xor(part, 8);
        part += __shfl_xor(part, 16);
        part += __shfl_xor(part, 32);
        if (lane == 0) scores[(((k << 5) + b) << 9) + s0 + sr] = part + web;
    }
}

// Per-hop init: scores=We_b (65,536 f), W_ht=Wt_b (98,304 f), sx/sh=0 (147,456 f).
// grid 1216 = 256 + 384 + 576.
__global__ void init_hop_kernel(const float* __restrict__ Web, float* __restrict__ scores,
                                const float* __restrict__ Wtb, float* __restrict__ W_ht,
                                float* __restrict__ sx, float* __restrict__ sh)
{
    int bid = blockIdx.x, t = threadIdx.x;
    if (bid < 256) {
        int idx = bid * 256 + t;              // 65,536
        scores[idx] = Web[idx >> 14];
    } else if (bid < 640) {
        int idx = (bid - 256) * 256 + t;      // 98,304
        int k = idx / 24576, j = idx % NH;
        W_ht[idx] = Wtb[k * NH + j];
    } else {
        int idx = (bid - 640) * 256 + t;      // 147,456 floats total (NOT bytes!)
        if (idx < 73728) sx[idx] = 0.f;
        else sh[idx - 73728] = 0.f;
    }
}

// W_ht partials: grid 1536 = 4k x 32b x 3jt x 4hg; atomicAdd into W_ht.
__global__ void wht2_kernel(const float* __restrict__ q, const float* __restrict__ WtW,
                            float* __restrict__ W_ht)
{
    int bid = blockIdx.x;
    int k = bid / 384, rem = bid % 384, b = rem / 12, rem2 = rem % 12;
    int jt = rem2 / 4, hg = rem2 % 4;
    int j = jt * 256 + threadIdx.x;
    const float* W = WtW + (long)k * HH + j;
    const float* qb = q + b * NH;
    float acc = 0.f;
    #pragma unroll 8
    for (int h = hg * 192; h < hg * 192 + 192; ++h) acc += qb[h] * W[(long)h * NH];
    atomicAdd(&W_ht[(k*NB + b) * NH + j], acc);
}

// ---------------------------------------------------------------------------
// MFMA split-bf16 fused scores (proven R9), head-offset koff.
// grid (128, 6, nheads); processes heads [koff, koff+nheads).
// ---------------------------------------------------------------------------
template <int AM>
__global__ __launch_bounds__(256) void fused_scores_mfma(
    const float* __restrict__ textf,
    const u16* __restrict__ textH, const u16* __restrict__ textL,
    const u16* __restrict__ combTH, const u16* __restrict__ combTL,
    const float* __restrict__ combB, const float* __restrict__ W_ht,
    const float* __restrict__ WeW, float* __restrict__ scores, int koff)
{
    __shared__ __align__(16) u16 AsH[128 * 32];
    __shared__ __align__(16) u16 AsL[128 * 32];
    __shared__ __align__(16) u16 BsH[128 * 32];
    __shared__ __align__(16) u16 BsL[128 * 32];
    __shared__ float wht_s[128];
    __shared__ float we_s[128];
    __shared__ float sred[128];
    const int t = threadIdx.x;
    const int wave = t >> 6, lane = t & 63;
    const int k = koff + blockIdx.z;
    const long m0 = (long)blockIdx.x * 128;
    const int n0 = blockIdx.y * 128;
    const int b = (int)(m0 >> 9), srow = (int)(m0 & 511);
    const u16* BH = combTH + (long)k * HH;
    const u16* BL = combTL + (long)k * HH;

    if (t < 128) {
        wht_s[t] = W_ht[((k << 5) + b) * NH + n0 + t] + combB[k * NH + n0 + t];
        we_s[t]  = WeW[k * NH + n0 + t];
        sred[t]  = 0.f;
    }

    const int r = t >> 2, ch = t & 3;
    const int wm = (wave & 1) * 64, wn = (wave >> 1) * 64;
    const int fr = lane & 15, fq = lane >> 4;

    f32x4 acc[4][4];
    #pragma unroll
    for (int i = 0; i < 4; ++i)
        #pragma unroll
        for (int j = 0; j < 4; ++j) acc[i][j] = (f32x4){0.f, 0.f, 0.f, 0.f};

    for (int h0 = 0; h0 < NH; h0 += 32) {
        if (AM) {
            gld16(textH + (m0 + r)      * NH + h0 + ch*8, AsH + t*8);
            gld16(textH + (m0 + 64 + r) * NH + h0 + ch*8, AsH + 2048 + t*8);
            gld16(textL + (m0 + r)      * NH + h0 + ch*8, AsL + t*8);
            gld16(textL + (m0 + 64 + r) * NH + h0 + ch*8, AsL + 2048 + t*8);
        } else {
            #pragma unroll
            for (int p = 0; p < 4; ++p) {
                int task = p * 256 + t;
                int row = task >> 3, g = task & 7;
                float4 v = *(const float4*)(textf + (m0 + row) * NH + h0 + g*4);
                ushort4 hv, lv;
                hv.x = f2bf(v.x); lv.x = f2bf(v.x - bf2f(hv.x));
                hv.y = f2bf(v.y); lv.y = f2bf(v.y - bf2f(hv.y));
                hv.z = f2bf(v.z); lv.z = f2bf(v.z - bf2f(hv.z));
                hv.w = f2bf(v.w); lv.w = f2bf(v.w - bf2f(hv.w));
                *(ushort4*)(AsH + row * 32 + g*4) = hv;
                *(ushort4*)(AsL + row * 32 + g*4) = lv;
            }
        }
        gld16(BH + (long)(n0 + r)      * NH + h0 + ch*8, BsH + t*8);
        gld16(BH + (long)(n0 + 64 + r) * NH + h0 + ch*8, BsH + 2048 + t*8);
        gld16(BL + (long)(n0 + r)      * NH + h0 + ch*8, BsL + t*8);
        gld16(BL + (long)(n0 + 64 + r) * NH + h0 + ch*8, BsL + 2048 + t*8);
        __syncthreads();
        bf16x8 afH[4], afL[4], bfH[4], bfL[4];
        #pragma unroll
        for (int i = 0; i < 4; ++i) {
            afH[i] = *(const bf16x8*)(AsH + (wm + i*16 + fr)*32 + fq*8);
            afL[i] = *(const bf16x8*)(AsL + (wm + i*16 + fr)*32 + fq*8);
            bfH[i] = *(const bf16x8*)(BsH + (wn + i*16 + fr)*32 + fq*8);
            bfL[i] = *(const bf16x8*)(BsL + (wn + i*16 + fr)*32 + fq*8);
        }
        #pragma unroll
        for (int i = 0; i < 4; ++i)
            #pragma unroll
            for (int j = 0; j < 4; ++j) {
                acc[i][j] = __builtin_amdgcn_mfma_f32_16x16x32_bf16(afH[i], bfH[j], acc[i][j], 0, 0, 0);
                acc[i][j] = __builtin_amdgcn_mfma_f32_16x16x32_bf16(afH[i], bfL[j], acc[i][j], 0, 0, 0);
                acc[i][j] = __builtin_amdgcn_mfma_f32_16x16x32_bf16(afL[i], bfH[j], acc[i][j], 0, 0, 0);
            }
        __syncthreads();
    }
    #pragma unroll
    for (int i = 0; i < 4; ++i) {
        #pragma unroll
        for (int rr = 0; rr < 4; ++rr) {
            int m = wm + i*16 + fq*4 + rr;
            float part = 0.f;
            #pragma unroll
            for (int j = 0; j < 4; ++j) {
                int n = wn + j*16 + fr;
                part += tanhf(acc[i][j][rr] + wht_s[n]) * we_s[n];
            }
            part += __shfl_xor(part, 1);
            part += __shfl_xor(part, 2);
            part += __shfl_xor(part, 4);
            part += __shfl_xor(part, 8);
            if (fr == 0) atomicAdd(&sred[m], part);
        }
    }
    __syncthreads();
    if (t < 128)
        atomicAdd(&scores[(((k << 5) + b) << 9) + srow + t], sred[t]);
}

// tier0 fallback (proven R8). grid (256, 6, 4).
__global__ __launch_bounds__(256) void fused_scores_valu(
    const float* __restrict__ text, const float* __restrict__ comb,
    const float* __restrict__ combB, const float* __restrict__ W_ht,
    const float* __restrict__ WeW, float* __restrict__ scores)
{
    __shared__ float AtT[32][68];
    __shared__ float Bt[32][132];
    __shared__ float wht_s[128];
    __shared__ float we_s[128];
    __shared__ float sred[64];
    const int t = threadIdx.x;
    const int row0 = blockIdx.x * 64;
    const int j0 = blockIdx.y * 128, k = blockIdx.z;
    const int b = row0 >> 9, s0 = row0 & 511;
    const float* B = comb + (long)k * HH;
    const int r4 = (t >> 4) * 4, c8 = (t & 15) * 8;
    if (t < 128) {
        wht_s[t] = W_ht[((k << 5) + b) * NH + j0 + t] + combB[k * NH + j0 + t];
        we_s[t]  = WeW[k * NH + j0 + t];
    }
    if (t < 64) sred[t] = 0.f;
    float acc[4][8];
    #pragma unroll
    for (int rr = 0; rr < 4; ++rr)
        #pragma unroll
        for (int cc = 0; cc < 8; ++cc) acc[rr][cc] = 0.f;
    for (int h0 = 0; h0 < NH; h0 += 32) {
        #pragma unroll
        for (int p = 0; p < 8; ++p) {
            int idx = p * 256 + t;
            int r = idx >> 5, hh = idx & 31;
            AtT[hh][r] = text[(long)(row0 + r) * NH + h0 + hh];
        }
        #pragma unroll
        for (int p = 0; p < 16; ++p) {
            int idx = p * 256 + t;
            int hh = idx >> 7, c = idx & 127;
            Bt[hh][c] = B[(long)(h0 + hh) * NH + j0 + c];
        }
        __syncthreads();
        for (int hh = 0; hh < 32; ++hh) {
            float4 av  = *(const float4*)&AtT[hh][r4];
            float4 bv0 = *(const float4*)&Bt[hh][c8];
            float4 bv1 = *(const float4*)&Bt[hh][c8 + 4];
            float a[4] = {av.x, av.y, av.z, av.w};
            float bb[8] = {bv0.x, bv0.y, bv0.z, bv0.w, bv1.x, bv1.y, bv1.z, bv1.w};
            #pragma unroll
            for (int rr = 0; rr < 4; ++rr)
                #pragma unroll
                for (int cc = 0; cc < 8; ++cc) acc[rr][cc] += a[rr] * bb[cc];
        }
        __syncthreads();
    }
    float part[4] = {0.f, 0.f, 0.f, 0.f};
    #pragma unroll
    for (int rr = 0; rr < 4; ++rr)
        #pragma unroll
        for (int cc = 0; cc < 8; ++cc)
            part[rr] += tanhf(acc[rr][cc] + wht_s[c8 + cc]) * we_s[c8 + cc];
    #pragma unroll
    for (int rr = 0; rr < 4; ++rr)
        atomicAdd(&sred[r4 + rr], part[rr]);
    __syncthreads();
    if (t < 64)
        atomicAdd(&scores[(((k << 5) + b) << 9) + s0 + t], sred[t]);
}

__global__ void softmax_kernel(const float* __restrict__ scores,
                               const float* __restrict__ headw_W, const float* __restrict__ headw_b,
                               const float* __restrict__ text,
                               const float* __restrict__ q_f32,
                               float* __restrict__ xT, float* __restrict__ out_prob, int hop)
{
    __shared__ float sc[NK][NS];
    __shared__ float red[256];
    __shared__ float rv[256];
    __shared__ int   ri[256];
    int b = blockIdx.x, t = threadIdx.x;
    for (int i = t; i < NK * NS; i += 256) {
        int k = i >> 9, s = i & 511;
        sc[k][s] = scores[((k*NB + b) << 9) + s];
    }
    __syncthreads();
    float fac[NK];
    for (int k = 0; k < NK; ++k) {
        float v0 = sc[k][t], v1 = sc[k][t + 256];
        red[t] = fmaxf(v0, v1);
        __syncthreads();
        for (int o = 128; o > 0; o >>= 1) { if (t < o) red[t] = fmaxf(red[t], red[t + o]); __syncthreads(); }
        float mx = red[0];
        __syncthreads();
        float e0 = expf(v0 - mx), e1 = expf(v1 - mx);
        sc[k][t] = e0; sc[k][t + 256] = e1;
        red[t] = e0 + e1;
        __syncthreads();
        for (int o = 128; o > 0; o >>= 1) { if (t < o) red[t] += red[t + o]; __syncthreads(); }
        fac[k] = headw_W[k] / red[0];
        __syncthreads();
    }
    float hwb = headw_b[0];
    float a0 = hwb, a1 = hwb;
    for (int k = 0; k < NK; ++k) { a0 += sc[k][t] * fac[k]; a1 += sc[k][t + 256] * fac[k]; }
    red[t] = a0*a0 + a1*a1;
    float bv; int bi;
    if (a0 >= a1) { bv = a0; bi = t; } else { bv = a1; bi = t + 256; }
    rv[t] = bv; ri[t] = bi;
    __syncthreads();
    for (int o = 128; o > 0; o >>= 1) {
        if (t < o) {
            red[t] += red[t + o];
            if (rv[t + o] > rv[t] || (rv[t + o] == rv[t] && ri[t + o] < ri[t])) { rv[t] = rv[t + o]; ri[t] = ri[t + o]; }
        }
        __syncthreads();
    }
    float scale = sqrtf(red[0]);
    int idx = ri[0];
    if (hop == 0) {
        out_prob[(b << 9) + t]       = a0 / scale;
        out_prob[(b << 9) + t + 256] = a1 / scale;
    }
    const float* trow = text + (long)(b * NS + idx) * NH;
    for (int i = t; i < NH; i += 256) {
        xT[i * NB + b]        = q_f32[b*NH + i];
        xT[(NH + i) * NB + b] = trow[i];
    }
}

// GRU matvec partials: grid (36 j-tiles, 3 c-groups); atomicAdd into sx/sh.
__global__ __launch_bounds__(256) void gru_mm3_kernel(
    const float* __restrict__ Wih, const float* __restrict__ Whh,
    const float* __restrict__ xT, const float* __restrict__ hT,
    float* __restrict__ sx, float* __restrict__ sh)
{
    __shared__ float xs[8192];
    int t = threadIdx.x;
    int tj = t & 63, tq = t >> 6;
    int j = blockIdx.x * 64 + tj;
    int cg = blockIdx.y;
    float acc[8];
    #pragma unroll
    for (int bq = 0; bq < 8; ++bq) acc[bq] = 0.f;
    for (int c = cg * 2; c < cg * 2 + 2; ++c) {
        for (int idx = t; idx < 8192; idx += 256) xs[idx] = xT[c * 8192 + idx];
        __syncthreads();
        #pragma unroll 8
        for (int ii = 0; ii < 256; ++ii) {
            float w = Wih[(long)(c * 256 + ii) * H3 + j];
            #pragma unroll
            for (int bq = 0; bq < 8; ++bq) acc[bq] += xs[ii * 32 + tq * 8 + bq] * w;
        }
        __syncthreads();
    }
    #pragma unroll
    for (int bq = 0; bq < 8; ++bq)
        atomicAdd(&sx[(long)(tq * 8 + bq) * H3 + j], acc[bq]);
    #pragma unroll
    for (int bq = 0; bq < 8; ++bq) acc[bq] = 0.f;
    {
        int c = cg;
        for (int idx = t; idx < 8192; idx += 256) xs[idx] = hT[c * 8192 + idx];
        __syncthreads();
        #pragma unroll 8
        for (int ii = 0; ii < 256; ++ii) {
            float w = Whh[(long)(c * 256 + ii) * H3 + j];
            #pragma unroll
            for (int bq = 0; bq < 8; ++bq) acc[bq] += xs[ii * 32 + tq * 8 + bq] * w;
        }
    }
    #pragma unroll
    for (int bq = 0; bq < 8; ++bq)
        atomicAdd(&sh[(long)(tq * 8 + bq) * H3 + j], acc[bq]);
}

__global__ void gate_kernel(const float* __restrict__ sx, const float* __restrict__ sh,
                            const float* __restrict__ bih, const float* __restrict__ bhh,
                            float* __restrict__ hT, float* __restrict__ q_f32,
                            float* __restrict__ out_h, int hop)
{
    int gid = blockIdx.x * 256 + threadIdx.x;
    int b = gid / NH, j = gid % NH;
    float xr = bih[j]        + sx[b*H3 + j];
    float xz = bih[NH + j]   + sx[b*H3 + NH + j];
    float xn = bih[1536 + j] + sx[b*H3 + 1536 + j];
    float hr = bhh[j]        + sh[b*H3 + j];
    float hz = bhh[NH + j]   + sh[b*H3 + NH + j];
    float hn = bhh[1536 + j] + sh[b*H3 + 1536 + j];
    float r = 1.f / (1.f + expf(-(xr + hr)));
    float z = 1.f / (1.f + expf(-(xz + hz)));
    float n = tanhf(xn + r * hn);
    float hp = hT[j * NB + b];
    float hnew = (1.f - z) * n + z * hp;
    hT[j * NB + b] = hnew;
    q_f32[gid] = hnew;
    out_h[(long)(b * 3 + hop) * NH + j] = hnew;
}

// ---------------------------------------------------------------------------
extern "C" void kernel_launch(void* const* d_in, const int* in_sizes, int n_in,
                              void* d_out, int out_size, void* d_ws, size_t ws_size,
                              hipStream_t stream)
{
    const float* question = (const float*)d_in[0];
    const float* text     = (const float*)d_in[1];
    const float* pw_W     = (const float*)d_in[2];
    const float* pw_b     = (const float*)d_in[3];
    const float* Ws_W     = (const float*)d_in[4];
    const float* Ws_b     = (const float*)d_in[5];
    const float* Wt_W     = (const float*)d_in[6];
    const float* Wt_b     = (const float*)d_in[7];
    const float* We_W     = (const float*)d_in[8];
    const float* We_b     = (const float*)d_in[9];
    const float* headw_W  = (const float*)d_in[10];
    const float* headw_b  = (const float*)d_in[11];
    const float* Wih      = (const float*)d_in[12];
    const float* Whh      = (const float*)d_in[13];
    const float* bih      = (const float*)d_in[14];
    const float* bhh      = (const float*)d_in[15];

    char* ws = (char*)d_ws;
    float* comb   = (float*)(ws + 0);
    float* combB  = (float*)(ws + 9437184);
    float* W_ht   = (float*)(ws + 9449472);
    float* scores = (float*)(ws + 9842688);
    float* q_f32  = (float*)(ws + 10104832);
    float* hT     = (float*)(ws + 10203136);
    float* xT     = (float*)(ws + 10301440);
    float* sx     = (float*)(ws + 10498048);
    float* sh     = (float*)(ws + 10792960);
    u16*   combTH = (u16*)  (ws + 11087872);
    u16*   combTL = (u16*)  (ws + 15806464);
    u16*   TP     = (u16*)  (ws + 20525056);
    // prep scratch overlaid on TP region (dead before tp_gemm runs):
    u16*   WsTH   = (u16*)  (ws + 20525056);
    u16*   WsTL   = (u16*)  (ws + 25243648);
    u16*   pwH    = (u16*)  (ws + 29962240);
    u16*   pwL    = (u16*)  (ws + 34680832);

    // NSTORE heads of bf16 TP fit in (ws - 20,525,056); prep scratch needs
    // 23.6 MB of that region (< 1 head's 25.2 MB, so always covered).
    int nstore = 0;
    if (ws_size >= (size_t)70856704) {
        long avail = (long)ws_size - 20525056L;
        nstore = (int)(avail / 25165824L);
        if (nstore > NK) nstore = NK;
    }
    const int tier = (nstore >= 1) ? 3
                   : (ws_size >= (size_t)20525056) ? 1 : 0;

    float* out_prob = (float*)d_out;
    float* out_h    = (float*)d_out + NB * NS;

    prep_kernel<<<4848, 256, 0, stream>>>(Ws_W, pw_b, Ws_b, combB, question, q_f32, hT,
                                          pw_W, WsTH, WsTL, pwH, pwL, tier >= 3 ? 2 : tier);
    if (tier == 3) {
        comb_mfma_kernel<<<dim3(6, 6, 4), 256, 0, stream>>>(WsTH, WsTL, pwH, pwL,
                                                            combTH, combTL);
        // scratch dead from here; TP overwrites it.
        tp_gemm_kernel<<<dim3(128, 6, nstore), 256, 0, stream>>>(text, combTH, combTL, TP);
    } else {
        comb_valu_kernel<<<dim3(12, 6, 4), 256, 0, stream>>>(pw_W, Ws_W, comb);
        if (tier == 1)
            split_combT_kernel<<<2304, 256, 0, stream>>>(comb, combTH, combTL);
    }

    for (int hop = 0; hop < 3; ++hop) {
        init_hop_kernel<<<1216, 256, 0, stream>>>(We_b, scores, Wt_b, W_ht, sx, sh);
        wht2_kernel<<<1536, 256, 0, stream>>>(q_f32, Wt_W, W_ht);
        if (tier == 3) {
            score_pass_kernel<<<dim3(16, 32, nstore), 256, 0, stream>>>(
                TP, combB, W_ht, We_W, We_b, scores);
            if (nstore < NK)
                fused_scores_mfma<0><<<dim3(128, 6, NK - nstore), 256, 0, stream>>>(
                    text, nullptr, nullptr, combTH, combTL, combB, W_ht, We_W,
                    scores, nstore);
        } else if (tier == 1) {
            fused_scores_mfma<0><<<dim3(128, 6, 4), 256, 0, stream>>>(
                text, nullptr, nullptr, combTH, combTL, combB, W_ht, We_W, scores, 0);
        } else {
            fused_scores_valu<<<dim3(256, 6, 4), 256, 0, stream>>>(
                text, comb, combB, W_ht, We_W, scores);
        }
        softmax_kernel<<<32, 256, 0, stream>>>(scores, headw_W, headw_b, text,
                                               q_f32, xT, out_prob, hop);
        gru_mm3_kernel<<<dim3(36, 3), 256, 0, stream>>>(Wih, Whh, xT, hT, sx, sh);
        gate_kernel<<<96, 256, 0, stream>>>(sx, sh, bih, bhh, hT, q_f32, out_h, hop);
    }
}

// Round 5
// 696.433 us; speedup vs baseline: 1.7703x; 1.0535x over previous
//
#include <hip/hip_runtime.h>

typedef unsigned short u16;
typedef __bf16 bf16x8 __attribute__((ext_vector_type(8)));
typedef float f32x4 __attribute__((ext_vector_type(4)));

#define NB 32          // batch
#define NS 512         // seq
#define NH 768         // hidden
#define NK 4           // heads
#define NBS 16384      // B*S
#define H3 2304        // 3H
#define HH 589824      // 768*768

__device__ inline float bf2f(u16 u) {
    unsigned x = ((unsigned)u) << 16;
    return __builtin_bit_cast(float, x);
}
__device__ inline u16 f2bf(float f) {
    unsigned u = __builtin_bit_cast(unsigned, f);
    u += 0x7fffu + ((u >> 16) & 1u);
    return (u16)(u >> 16);
}
// async global->LDS, 16B/lane; LDS dst = wave-uniform base + lane*16 (m97 recipe).
__device__ inline void gld16(const u16* g, u16* l) {
    __builtin_amdgcn_global_load_lds(
        (const __attribute__((address_space(1))) unsigned int*)g,
        (__attribute__((address_space(3))) unsigned int*)l, 16, 0, 0);
}

// ---------------------------------------------------------------------------
// Workspace layout (bytes):
//  comb    @ 0           9,437,184  f32 [4][768(h)][768(j)]  (tier 0/1 only)
//  combB   @ 9,437,184      12,288  f32 [4][768]
//  W_ht    @ 9,449,472     393,216  f32 [4][32][768]   (= Wtb + combB + q.Wt)
//  scores  @ 9,842,688     262,144  f32 [4][32][512]
//  q_f32   @ 10,104,832     98,304  f32 [32][768]
//  hT      @ 10,203,136     98,304  f32 [768][32]
//  xT      @ 10,301,440    196,608  f32 [1536][32]
//  sx      @ 10,498,048    294,912  f32 [32][2304]
//  sh      @ 10,792,960    294,912  f32 [32][2304]  -> 11,087,872
//  combTH  @ 11,087,872   4,718,592 bf16 [4][j][h] hi
//  combTL  @ 15,806,464   4,718,592 bf16 [4][j][h] lo   -> 20,525,056  TIER1
//  TP      @ 20,525,056   NSTORE x 25,165,824 bf16 [k][bs][j]  (TIER3)
//  textH   @ 121,188,352 25,165,824 bf16 [bs][h] hi  (only when NSTORE=4 and
//                                    ws >= 146,354,176)
//  TIER3 prep scratch overlaid on TP region (consumed by comb_mfma BEFORE
//  tp_gemm writes TP):
//   WsTH @ 20,525,056  WsTL @ 25,243,648  pwH @ 29,962,240  pwL @ 34,680,832
//
// R5 changes: combB folded into W_ht (wht2 full-dot, no atomics/init);
// init_hop eliminated (score_pass writes '='; sx/sh zeroed by prep once and
// re-zeroed by gate after reading); shuffle softmax; gru grid (36,9);
// tp_gemm A staged via bf16 textH + global_load_lds.
// ---------------------------------------------------------------------------

// P: one-time prep. grid 5424.
__global__ void prep_kernel(const float* __restrict__ WsW, const float* __restrict__ pwb,
                            const float* __restrict__ Wsb, float* __restrict__ combB,
                            const float* __restrict__ question,
                            float* __restrict__ q_f32, float* __restrict__ hT,
                            float* __restrict__ sx, float* __restrict__ sh,
                            const float* __restrict__ pwW,
                            u16* __restrict__ WsTH, u16* __restrict__ WsTL,
                            u16* __restrict__ pwH, u16* __restrict__ pwL, int tier)
{
    int bid = blockIdx.x, t = threadIdx.x;
    if (bid < 48) {
        int idx = bid * 64 + (t >> 2);      // 0..3071
        int ph = t & 3;
        int k = idx / NH, j = idx % NH;
        const float* W = WsW + (long)k * HH + j;
        const float* pb = pwb + k * NH;
        float acc = 0.f;
        #pragma unroll 8
        for (int m = ph * 192; m < ph * 192 + 192; ++m)
            acc += pb[m] * W[(long)m * NH];
        acc += __shfl_xor(acc, 1);
        acc += __shfl_xor(acc, 2);
        if (ph == 0) combB[idx] = acc + Wsb[idx];
    } else if (bid < 144) {
        int idx = (bid - 48) * 256 + t;
        q_f32[idx] = question[idx];
    } else if (bid < 240) {
        int idx = (bid - 144) * 256 + t;
        hT[idx] = 0.f;
    } else if (bid < 816) {
        int idx = (bid - 240) * 256 + t;    // 147,456 floats
        if (idx < 73728) sx[idx] = 0.f;
        else sh[idx - 73728] = 0.f;
    } else if (bid < 3120) {
        if (tier < 2) return;
        __shared__ float tile[32][33];
        int bid2 = bid - 816;
        int k = bid2 / 576, rem = bid2 % 576, tr = rem / 24, tc = rem % 24;
        const float* src = WsW + (long)k * HH;
        long dbase = (long)k * HH;
        int tx = t & 31, ty = t >> 5;
        #pragma unroll
        for (int i = 0; i < 4; ++i)
            tile[tx][ty + i*8] = src[(long)(tr*32 + ty + i*8) * NH + tc*32 + tx];
        __syncthreads();
        #pragma unroll
        for (int i = 0; i < 4; ++i) {
            float v = tile[ty + i*8][tx];
            u16 hv = f2bf(v);
            u16 lv = f2bf(v - bf2f(hv));
            long o = dbase + (long)(tc*32 + ty + i*8) * NH + tr*32 + tx;
            WsTH[o] = hv; WsTL[o] = lv;
        }
    } else {
        if (tier < 2) return;
        long base = (long)(bid - 3120) * 1024 + t * 4;
        float4 v = *(const float4*)(pwW + base);
        ushort4 hv, lv;
        hv.x = f2bf(v.x); lv.x = f2bf(v.x - bf2f(hv.x));
        hv.y = f2bf(v.y); lv.y = f2bf(v.y - bf2f(hv.y));
        hv.z = f2bf(v.z); lv.z = f2bf(v.z - bf2f(hv.z));
        hv.w = f2bf(v.w); lv.w = f2bf(v.w - bf2f(hv.w));
        *(ushort4*)(pwH + base) = hv;
        *(ushort4*)(pwL + base) = lv;
    }
}

// combT[k][j][h] = sum_m WsT[k][j][m] * pw[k][h][m], split-bf16 3-MFMA.
__global__ __launch_bounds__(256) void comb_mfma_kernel(
    const u16* __restrict__ WsTH, const u16* __restrict__ WsTL,
    const u16* __restrict__ pwH, const u16* __restrict__ pwL,
    u16* __restrict__ combTH, u16* __restrict__ combTL)
{
    __shared__ __align__(16) u16 AsH[128 * 32];
    __shared__ __align__(16) u16 AsL[128 * 32];
    __shared__ __align__(16) u16 BsH[128 * 32];
    __shared__ __align__(16) u16 BsL[128 * 32];
    const int t = threadIdx.x;
    const int wave = t >> 6, lane = t & 63;
    const int k = blockIdx.z;
    const long m0 = (long)blockIdx.x * 128;   // j-rows
    const int n0 = blockIdx.y * 128;          // h-cols
    const u16* AH = WsTH + (long)k * HH;
    const u16* AL = WsTL + (long)k * HH;
    const u16* BH = pwH + (long)k * HH;
    const u16* BL = pwL + (long)k * HH;

    const int r = t >> 2, ch = t & 3;
    const int wm = (wave & 1) * 64, wn = (wave >> 1) * 64;
    const int fr = lane & 15, fq = lane >> 4;

    f32x4 acc[4][4];
    #pragma unroll
    for (int i = 0; i < 4; ++i)
        #pragma unroll
        for (int j = 0; j < 4; ++j) acc[i][j] = (f32x4){0.f, 0.f, 0.f, 0.f};

    for (int k0 = 0; k0 < NH; k0 += 32) {
        gld16(AH + (m0 + r)      * NH + k0 + ch*8, AsH + t*8);
        gld16(AH + (m0 + 64 + r) * NH + k0 + ch*8, AsH + 2048 + t*8);
        gld16(AL + (m0 + r)      * NH + k0 + ch*8, AsL + t*8);
        gld16(AL + (m0 + 64 + r) * NH + k0 + ch*8, AsL + 2048 + t*8);
        gld16(BH + (long)(n0 + r)      * NH + k0 + ch*8, BsH + t*8);
        gld16(BH + (long)(n0 + 64 + r) * NH + k0 + ch*8, BsH + 2048 + t*8);
        gld16(BL + (long)(n0 + r)      * NH + k0 + ch*8, BsL + t*8);
        gld16(BL + (long)(n0 + 64 + r) * NH + k0 + ch*8, BsL + 2048 + t*8);
        __syncthreads();
        bf16x8 afH[4], afL[4], bfH[4], bfL[4];
        #pragma unroll
        for (int i = 0; i < 4; ++i) {
            afH[i] = *(const bf16x8*)(AsH + (wm + i*16 + fr)*32 + fq*8);
            afL[i] = *(const bf16x8*)(AsL + (wm + i*16 + fr)*32 + fq*8);
            bfH[i] = *(const bf16x8*)(BsH + (wn + i*16 + fr)*32 + fq*8);
            bfL[i] = *(const bf16x8*)(BsL + (wn + i*16 + fr)*32 + fq*8);
        }
        #pragma unroll
        for (int i = 0; i < 4; ++i)
            #pragma unroll
            for (int j = 0; j < 4; ++j) {
                acc[i][j] = __builtin_amdgcn_mfma_f32_16x16x32_bf16(afH[i], bfH[j], acc[i][j], 0, 0, 0);
                acc[i][j] = __builtin_amdgcn_mfma_f32_16x16x32_bf16(afH[i], bfL[j], acc[i][j], 0, 0, 0);
                acc[i][j] = __builtin_amdgcn_mfma_f32_16x16x32_bf16(afL[i], bfH[j], acc[i][j], 0, 0, 0);
            }
        __syncthreads();
    }
    long kb = (long)k * HH;
    #pragma unroll
    for (int i = 0; i < 4; ++i) {
        long m = m0 + wm + i*16 + fq*4;       // j-row
        #pragma unroll
        for (int j = 0; j < 4; ++j) {
            long n = n0 + wn + j*16 + fr;     // h-col
            #pragma unroll
            for (int rr = 0; rr < 4; ++rr) {
                float v = acc[i][j][rr];
                u16 hv = f2bf(v);
                u16 lv = f2bf(v - bf2f(hv));
                combTH[kb + (m + rr) * NH + n] = hv;
                combTL[kb + (m + rr) * NH + n] = lv;
            }
        }
    }
}

// tier 0/1: comb[k][h][j] f32 VALU GEMM (proven R8 kernel).
__global__ __launch_bounds__(256) void comb_valu_kernel(
    const float* __restrict__ pwW, const float* __restrict__ WsW,
    float* __restrict__ comb)
{
    __shared__ float AtT[32][68];
    __shared__ float Bt[32][132];
    const int t = threadIdx.x;
    const int m0 = blockIdx.x * 64, j0 = blockIdx.y * 128, k = blockIdx.z;
    const float* A = pwW + (long)k * HH;
    const float* B = WsW + (long)k * HH;
    const int r4 = (t >> 4) * 4, c8 = (t & 15) * 8;
    float acc[4][8];
    #pragma unroll
    for (int rr = 0; rr < 4; ++rr)
        #pragma unroll
        for (int cc = 0; cc < 8; ++cc) acc[rr][cc] = 0.f;
    for (int h0 = 0; h0 < NH; h0 += 32) {
        #pragma unroll
        for (int p = 0; p < 8; ++p) {
            int idx = p * 256 + t;
            int r = idx >> 5, hh = idx & 31;
            AtT[hh][r] = A[(long)(m0 + r) * NH + h0 + hh];
        }
        #pragma unroll
        for (int p = 0; p < 16; ++p) {
            int idx = p * 256 + t;
            int hh = idx >> 7, c = idx & 127;
            Bt[hh][c] = B[(long)(h0 + hh) * NH + j0 + c];
        }
        __syncthreads();
        for (int hh = 0; hh < 32; ++hh) {
            float4 av  = *(const float4*)&AtT[hh][r4];
            float4 bv0 = *(const float4*)&Bt[hh][c8];
            float4 bv1 = *(const float4*)&Bt[hh][c8 + 4];
            float a[4] = {av.x, av.y, av.z, av.w};
            float bb[8] = {bv0.x, bv0.y, bv0.z, bv0.w, bv1.x, bv1.y, bv1.z, bv1.w};
            #pragma unroll
            for (int rr = 0; rr < 4; ++rr)
                #pragma unroll
                for (int cc = 0; cc < 8; ++cc) acc[rr][cc] += a[rr] * bb[cc];
        }
        __syncthreads();
    }
    float* C = comb + (long)k * HH;
    #pragma unroll
    for (int rr = 0; rr < 4; ++rr)
        #pragma unroll
        for (int cc = 0; cc < 8; ++cc)
            C[(long)(m0 + r4 + rr) * NH + j0 + c8 + cc] = acc[rr][cc];
}

// tier1: transpose+split comb f32 -> combTH/combTL. grid 2304.
__global__ void split_combT_kernel(const float* __restrict__ comb,
                                   u16* __restrict__ combTH, u16* __restrict__ combTL)
{
    __shared__ float tile[32][33];
    int bid = blockIdx.x, t = threadIdx.x;
    int k = bid / 576, rem = bid % 576, tr = rem / 24, tc = rem % 24;
    const float* src = comb + (long)k * HH;
    long dbase = (long)k * HH;
    int tx = t & 31, ty = t >> 5;
    #pragma unroll
    for (int i = 0; i < 4; ++i)
        tile[tx][ty + i*8] = src[(long)(tr*32 + ty + i*8) * NH + tc*32 + tx];
    __syncthreads();
    #pragma unroll
    for (int i = 0; i < 4; ++i) {
        float v = tile[ty + i*8][tx];
        u16 hv = f2bf(v);
        u16 lv = f2bf(v - bf2f(hv));
        long o = dbase + (long)(tc*32 + ty + i*8) * NH + tr*32 + tx;
        combTH[o] = hv; combTL[o] = lv;
    }
}

// split text f32 -> textH (hi only). grid 12288.
__global__ void split_text_kernel(const float* __restrict__ text,
                                  u16* __restrict__ textH)
{
    long base = (long)blockIdx.x * 1024 + threadIdx.x * 4;
    float4 v = *(const float4*)(text + base);
    ushort4 hv;
    hv.x = f2bf(v.x);
    hv.y = f2bf(v.y);
    hv.z = f2bf(v.z);
    hv.w = f2bf(v.w);
    *(ushort4*)(textH + base) = hv;
}

// TIER3: TP[k][bs][j] = bf16((text @ comb[k])[bs][j]), once per launch, heads
// [0, NSTORE). AM=1: A hi via gld16 from textH. AM=0: on-the-fly f32->bf16.
// B split hi/lo (2 MFMA). grid (128, 6, NSTORE).
template <int AM>
__global__ __launch_bounds__(256) void tp_gemm_kernel(
    const float* __restrict__ textf, const u16* __restrict__ textH,
    const u16* __restrict__ combTH, const u16* __restrict__ combTL,
    u16* __restrict__ TP)
{
    __shared__ __align__(16) u16 AsH[128 * 32];
    __shared__ __align__(16) u16 BsH[128 * 32];
    __shared__ __align__(16) u16 BsL[128 * 32];
    const int t = threadIdx.x;
    const int wave = t >> 6, lane = t & 63;
    const int k = blockIdx.z;
    const long m0 = (long)blockIdx.x * 128;   // bs-rows
    const int n0 = blockIdx.y * 128;          // j-cols
    const u16* BH = combTH + (long)k * HH;
    const u16* BL = combTL + (long)k * HH;

    const int r = t >> 2, ch = t & 3;
    const int wm = (wave & 1) * 64, wn = (wave >> 1) * 64;
    const int fr = lane & 15, fq = lane >> 4;

    f32x4 acc[4][4];
    #pragma unroll
    for (int i = 0; i < 4; ++i)
        #pragma unroll
        for (int j = 0; j < 4; ++j) acc[i][j] = (f32x4){0.f, 0.f, 0.f, 0.f};

    for (int h0 = 0; h0 < NH; h0 += 32) {
        if (AM) {
            gld16(textH + (m0 + r)      * NH + h0 + ch*8, AsH + t*8);
            gld16(textH + (m0 + 64 + r) * NH + h0 + ch*8, AsH + 2048 + t*8);
        } else {
            #pragma unroll
            for (int p = 0; p < 4; ++p) {
                int task = p * 256 + t;
                int row = task >> 3, g = task & 7;
                float4 v = *(const float4*)(textf + (m0 + row) * NH + h0 + g*4);
                ushort4 hv;
                hv.x = f2bf(v.x);
                hv.y = f2bf(v.y);
                hv.z = f2bf(v.z);
                hv.w = f2bf(v.w);
                *(ushort4*)(AsH + row * 32 + g*4) = hv;
            }
        }
        gld16(BH + (long)(n0 + r)      * NH + h0 + ch*8, BsH + t*8);
        gld16(BH + (long)(n0 + 64 + r) * NH + h0 + ch*8, BsH + 2048 + t*8);
        gld16(BL + (long)(n0 + r)      * NH + h0 + ch*8, BsL + t*8);
        gld16(BL + (long)(n0 + 64 + r) * NH + h0 + ch*8, BsL + 2048 + t*8);
        __syncthreads();
        bf16x8 afH[4], bfH[4], bfL[4];
        #pragma unroll
        for (int i = 0; i < 4; ++i) {
            afH[i] = *(const bf16x8*)(AsH + (wm + i*16 + fr)*32 + fq*8);
            bfH[i] = *(const bf16x8*)(BsH + (wn + i*16 + fr)*32 + fq*8);
            bfL[i] = *(const bf16x8*)(BsL + (wn + i*16 + fr)*32 + fq*8);
        }
        #pragma unroll
        for (int i = 0; i < 4; ++i)
            #pragma unroll
            for (int j = 0; j < 4; ++j) {
                acc[i][j] = __builtin_amdgcn_mfma_f32_16x16x32_bf16(afH[i], bfH[j], acc[i][j], 0, 0, 0);
                acc[i][j] = __builtin_amdgcn_mfma_f32_16x16x32_bf16(afH[i], bfL[j], acc[i][j], 0, 0, 0);
            }
        __syncthreads();
    }
    u16* out = TP + ((long)k * NBS + m0) * NH + n0;
    #pragma unroll
    for (int i = 0; i < 4; ++i) {
        #pragma unroll
        for (int rr = 0; rr < 4; ++rr) {
            int m = wm + i*16 + fq*4 + rr;
            #pragma unroll
            for (int j = 0; j < 4; ++j) {
                int n = wn + j*16 + fr;
                out[(long)m * NH + n] = f2bf(acc[i][j][rr]);
            }
        }
    }
}

// TIER3 per-hop: scores[k][b][s] = We_b[k] + sum_j tanh(TP + W_ht)*We for
// stored heads (W_ht already includes combB). grid (16, 32, NSTORE).
__global__ __launch_bounds__(256) void score_pass_kernel(
    const u16* __restrict__ TP, const float* __restrict__ W_ht,
    const float* __restrict__ WeW, const float* __restrict__ Web,
    float* __restrict__ scores)
{
    __shared__ __align__(16) float bias_s[NH];
    __shared__ __align__(16) float we_s[NH];
    const int t = threadIdx.x;
    const int k = blockIdx.z, b = blockIdx.y;
    const int s0 = blockIdx.x * 32;
    for (int i = t; i < NH; i += 256) {
        bias_s[i] = W_ht[((k << 5) + b) * NH + i];
        we_s[i]   = WeW[k * NH + i];
    }
    __syncthreads();
    const int wave = t >> 6, lane = t & 63;
    const u16* tpb = TP + ((long)k * NBS + (b << 9) + s0) * NH;
    const float web = Web[k];
    for (int sr = wave; sr < 32; sr += 4) {
        const u16* row = tpb + (long)sr * NH;
        float part = 0.f;
        #pragma unroll
        for (int p = 0; p < 3; ++p) {
            const int j = p * 256 + lane * 4;   // 8B/lane bf16 loads, coalesced 512B
            ushort4 v = *(const ushort4*)(row + j);
            float4 bb = *(const float4*)(bias_s + j);
            float4 ww = *(const float4*)(we_s + j);
            part += tanhf(bf2f(v.x) + bb.x) * ww.x;
            part += tanhf(bf2f(v.y) + bb.y) * ww.y;
            part += tanhf(bf2f(v.z) + bb.z) * ww.z;
            part += tanhf(bf2f(v.w) + bb.w) * ww.w;
        }
        part += __shfl_xor(part, 1);
        part += __shfl_xor(part, 2);
        part += __shfl_xor(part, 4);
        part += __shfl_xor(part, 8);
        part += __shfl_xor(part, 16);
        part += __shfl_xor(part, 32);
        if (lane == 0) scores[(((k << 5) + b) << 9) + s0 + sr] = part + web;
    }
}

// scores = We_b for heads [koff, NK) (only needed ahead of atomicAdd fused path).
// grid (NK-koff)*64.
__global__ void init_scores_kernel(const float* __restrict__ Web,
                                   float* __restrict__ scores, int koff)
{
    int idx = (koff << 14) + blockIdx.x * 256 + threadIdx.x;
    scores[idx] = Web[idx >> 14];
}

// W_ht[k][b][j] = Wtb + combB + q.Wt  (full dot, no atomics). grid 384.
__global__ __launch_bounds__(256) void wht2_kernel(
    const float* __restrict__ q, const float* __restrict__ WtW,
    const float* __restrict__ combB, const float* __restrict__ Wtb,
    float* __restrict__ W_ht)
{
    int bid = blockIdx.x;                 // 4k x 32b x 3jt
    int k = bid / 96, rem = bid % 96, b = rem / 3, jt = rem % 3;
    int j = jt * 256 + threadIdx.x;
    const float* W = WtW + (long)k * HH + j;
    const float* qb = q + b * NH;
    float acc = 0.f;
    #pragma unroll 8
    for (int h = 0; h < NH; ++h) acc += qb[h] * W[(long)h * NH];
    W_ht[(k*NB + b) * NH + j] = acc + Wtb[k * NH + j] + combB[k * NH + j];
}

// ---------------------------------------------------------------------------
// MFMA split-bf16 fused scores (W_ht includes combB), head-offset koff.
// grid (128, 6, nheads).
// ---------------------------------------------------------------------------
template <int AM>
__global__ __launch_bounds__(256) void fused_scores_mfma(
    const float* __restrict__ textf,
    const u16* __restrict__ textH, const u16* __restrict__ textL,
    const u16* __restrict__ combTH, const u16* __restrict__ combTL,
    const float* __restrict__ W_ht,
    const float* __restrict__ WeW, float* __restrict__ scores, int koff)
{
    __shared__ __align__(16) u16 AsH[128 * 32];
    __shared__ __align__(16) u16 AsL[128 * 32];
    __shared__ __align__(16) u16 BsH[128 * 32];
    __shared__ __align__(16) u16 BsL[128 * 32];
    __shared__ float wht_s[128];
    __shared__ float we_s[128];
    __shared__ float sred[128];
    const int t = threadIdx.x;
    const int wave = t >> 6, lane = t & 63;
    const int k = koff + blockIdx.z;
    const long m0 = (long)blockIdx.x * 128;
    const int n0 = blockIdx.y * 128;
    const int b = (int)(m0 >> 9), srow = (int)(m0 & 511);
    const u16* BH = combTH + (long)k * HH;
    const u16* BL = combTL + (long)k * HH;

    if (t < 128) {
        wht_s[t] = W_ht[((k << 5) + b) * NH + n0 + t];
        we_s[t]  = WeW[k * NH + n0 + t];
        sred[t]  = 0.f;
    }

    const int r = t >> 2, ch = t & 3;
    const int wm = (wave & 1) * 64, wn = (wave >> 1) * 64;
    const int fr = lane & 15, fq = lane >> 4;

    f32x4 acc[4][4];
    #pragma unroll
    for (int i = 0; i < 4; ++i)
        #pragma unroll
        for (int j = 0; j < 4; ++j) acc[i][j] = (f32x4){0.f, 0.f, 0.f, 0.f};

    for (int h0 = 0; h0 < NH; h0 += 32) {
        if (AM) {
            gld16(textH + (m0 + r)      * NH + h0 + ch*8, AsH + t*8);
            gld16(textH + (m0 + 64 + r) * NH + h0 + ch*8, AsH + 2048 + t*8);
            gld16(textL + (m0 + r)      * NH + h0 + ch*8, AsL + t*8);
            gld16(textL + (m0 + 64 + r) * NH + h0 + ch*8, AsL + 2048 + t*8);
        } else {
            #pragma unroll
            for (int p = 0; p < 4; ++p) {
                int task = p * 256 + t;
                int row = task >> 3, g = task & 7;
                float4 v = *(const float4*)(textf + (m0 + row) * NH + h0 + g*4);
                ushort4 hv, lv;
                hv.x = f2bf(v.x); lv.x = f2bf(v.x - bf2f(hv.x));
                hv.y = f2bf(v.y); lv.y = f2bf(v.y - bf2f(hv.y));
                hv.z = f2bf(v.z); lv.z = f2bf(v.z - bf2f(hv.z));
                hv.w = f2bf(v.w); lv.w = f2bf(v.w - bf2f(hv.w));
                *(ushort4*)(AsH + row * 32 + g*4) = hv;
                *(ushort4*)(AsL + row * 32 + g*4) = lv;
            }
        }
        gld16(BH + (long)(n0 + r)      * NH + h0 + ch*8, BsH + t*8);
        gld16(BH + (long)(n0 + 64 + r) * NH + h0 + ch*8, BsH + 2048 + t*8);
        gld16(BL + (long)(n0 + r)      * NH + h0 + ch*8, BsL + t*8);
        gld16(BL + (long)(n0 + 64 + r) * NH + h0 + ch*8, BsL + 2048 + t*8);
        __syncthreads();
        bf16x8 afH[4], afL[4], bfH[4], bfL[4];
        #pragma unroll
        for (int i = 0; i < 4; ++i) {
            afH[i] = *(const bf16x8*)(AsH + (wm + i*16 + fr)*32 + fq*8);
            afL[i] = *(const bf16x8*)(AsL + (wm + i*16 + fr)*32 + fq*8);
            bfH[i] = *(const bf16x8*)(BsH + (wn + i*16 + fr)*32 + fq*8);
            bfL[i] = *(const bf16x8*)(BsL + (wn + i*16 + fr)*32 + fq*8);
        }
        #pragma unroll
        for (int i = 0; i < 4; ++i)
            #pragma unroll
            for (int j = 0; j < 4; ++j) {
                acc[i][j] = __builtin_amdgcn_mfma_f32_16x16x32_bf16(afH[i], bfH[j], acc[i][j], 0, 0, 0);
                acc[i][j] = __builtin_amdgcn_mfma_f32_16x16x32_bf16(afH[i], bfL[j], acc[i][j], 0, 0, 0);
                acc[i][j] = __builtin_amdgcn_mfma_f32_16x16x32_bf16(afL[i], bfH[j], acc[i][j], 0, 0, 0);
            }
        __syncthreads();
    }
    #pragma unroll
    for (int i = 0; i < 4; ++i) {
        #pragma unroll
        for (int rr = 0; rr < 4; ++rr) {
            int m = wm + i*16 + fq*4 + rr;
            float part = 0.f;
            #pragma unroll
            for (int j = 0; j < 4; ++j) {
                int n = wn + j*16 + fr;
                part += tanhf(acc[i][j][rr] + wht_s[n]) * we_s[n];
            }
            part += __shfl_xor(part, 1);
            part += __shfl_xor(part, 2);
            part += __shfl_xor(part, 4);
            part += __shfl_xor(part, 8);
            if (fr == 0) atomicAdd(&sred[m], part);
        }
    }
    __syncthreads();
    if (t < 128)
        atomicAdd(&scores[(((k << 5) + b) << 9) + srow + t], sred[t]);
}

// tier0 fallback (W_ht includes combB). grid (256, 6, 4).
__global__ __launch_bounds__(256) void fused_scores_valu(
    const float* __restrict__ text, const float* __restrict__ comb,
    const float* __restrict__ W_ht,
    const float* __restrict__ WeW, float* __restrict__ scores)
{
    __shared__ float AtT[32][68];
    __shared__ float Bt[32][132];
    __shared__ float wht_s[128];
    __shared__ float we_s[128];
    __shared__ float sred[64];
    const int t = threadIdx.x;
    const int row0 = blockIdx.x * 64;
    const int j0 = blockIdx.y * 128, k = blockIdx.z;
    const int b = row0 >> 9, s0 = row0 & 511;
    const float* B = comb + (long)k * HH;
    const int r4 = (t >> 4) * 4, c8 = (t & 15) * 8;
    if (t < 128) {
        wht_s[t] = W_ht[((k << 5) + b) * NH + j0 + t];
        we_s[t]  = WeW[k * NH + j0 + t];
    }
    if (t < 64) sred[t] = 0.f;
    float acc[4][8];
    #pragma unroll
    for (int rr = 0; rr < 4; ++rr)
        #pragma unroll
        for (int cc = 0; cc < 8; ++cc) acc[rr][cc] = 0.f;
    for (int h0 = 0; h0 < NH; h0 += 32) {
        #pragma unroll
        for (int p = 0; p < 8; ++p) {
            int idx = p * 256 + t;
            int r = idx >> 5, hh = idx & 31;
            AtT[hh][r] = text[(long)(row0 + r) * NH + h0 + hh];
        }
        #pragma unroll
        for (int p = 0; p < 16; ++p) {
            int idx = p * 256 + t;
            int hh = idx >> 7, c = idx & 127;
            Bt[hh][c] = B[(long)(h0 + hh) * NH + j0 + c];
        }
        __syncthreads();
        for (int hh = 0; hh < 32; ++hh) {
            float4 av  = *(const float4*)&AtT[hh][r4];
            float4 bv0 = *(const float4*)&Bt[hh][c8];
            float4 bv1 = *(const float4*)&Bt[hh][c8 + 4];
            float a[4] = {av.x, av.y, av.z, av.w};
            float bb[8] = {bv0.x, bv0.y, bv0.z, bv0.w, bv1.x, bv1.y, bv1.z, bv1.w};
            #pragma unroll
            for (int rr = 0; rr < 4; ++rr)
                #pragma unroll
                for (int cc = 0; cc < 8; ++cc) acc[rr][cc] += a[rr] * bb[cc];
        }
        __syncthreads();
    }
    float part[4] = {0.f, 0.f, 0.f, 0.f};
    #pragma unroll
    for (int rr = 0; rr < 4; ++rr)
        #pragma unroll
        for (int cc = 0; cc < 8; ++cc)
            part[rr] += tanhf(acc[rr][cc] + wht_s[c8 + cc]) * we_s[c8 + cc];
    #pragma unroll
    for (int rr = 0; rr < 4; ++rr)
        atomicAdd(&sred[r4 + rr], part[rr]);
    __syncthreads();
    if (t < 64)
        atomicAdd(&scores[(((k << 5) + b) << 9) + s0 + t], sred[t]);
}

// Shuffle-based softmax + head-combine + argmax + xT build. grid 32.
__global__ void softmax_kernel(const float* __restrict__ scores,
                               const float* __restrict__ headw_W, const float* __restrict__ headw_b,
                               const float* __restrict__ text,
                               const float* __restrict__ q_f32,
                               float* __restrict__ xT, float* __restrict__ out_prob, int hop)
{
    __shared__ float sc[NK][NS];
    __shared__ float cred[4];
    __shared__ float cval[4];
    __shared__ int   cidx[4];
    int b = blockIdx.x, t = threadIdx.x;
    int wave = t >> 6, lane = t & 63;
    for (int i = t; i < NK * NS; i += 256) {
        int k = i >> 9, s = i & 511;
        sc[k][s] = scores[((k*NB + b) << 9) + s];
    }
    __syncthreads();
    float fac[NK];
    for (int k = 0; k < NK; ++k) {
        float v0 = sc[k][t], v1 = sc[k][t + 256];
        float m = fmaxf(v0, v1);
        #pragma unroll
        for (int o = 32; o > 0; o >>= 1) m = fmaxf(m, __shfl_xor(m, o));
        if (lane == 0) cred[wave] = m;
        __syncthreads();
        float mx = fmaxf(fmaxf(cred[0], cred[1]), fmaxf(cred[2], cred[3]));
        __syncthreads();
        float e0 = expf(v0 - mx), e1 = expf(v1 - mx);
        sc[k][t] = e0; sc[k][t + 256] = e1;
        float sm = e0 + e1;
        #pragma unroll
        for (int o = 32; o > 0; o >>= 1) sm += __shfl_xor(sm, o);
        if (lane == 0) cred[wave] = sm;
        __syncthreads();
        fac[k] = headw_W[k] / (cred[0] + cred[1] + cred[2] + cred[3]);
        __syncthreads();
    }
    float hwb = headw_b[0];
    float a0 = hwb, a1 = hwb;
    for (int k = 0; k < NK; ++k) { a0 += sc[k][t] * fac[k]; a1 += sc[k][t + 256] * fac[k]; }
    float ss = a0*a0 + a1*a1;
    #pragma unroll
    for (int o = 32; o > 0; o >>= 1) ss += __shfl_xor(ss, o);
    float bv; int bi;
    if (a0 >= a1) { bv = a0; bi = t; } else { bv = a1; bi = t + 256; }
    #pragma unroll
    for (int o = 1; o < 64; o <<= 1) {
        float ov = __shfl_xor(bv, o);
        int   oi = __shfl_xor(bi, o);
        if (ov > bv || (ov == bv && oi < bi)) { bv = ov; bi = oi; }
    }
    if (lane == 0) { cred[wave] = ss; cval[wave] = bv; cidx[wave] = bi; }
    __syncthreads();
    float scale = sqrtf(cred[0] + cred[1] + cred[2] + cred[3]);
    float mbv = cval[0]; int mbi = cidx[0];
    #pragma unroll
    for (int w = 1; w < 4; ++w)
        if (cval[w] > mbv || (cval[w] == mbv && cidx[w] < mbi)) { mbv = cval[w]; mbi = cidx[w]; }
    int idx = mbi;
    if (hop == 0) {
        out_prob[(b << 9) + t]       = a0 / scale;
        out_prob[(b << 9) + t + 256] = a1 / scale;
    }
    const float* trow = text + (long)(b * NS + idx) * NH;
    for (int i = t; i < NH; i += 256) {
        xT[i * NB + b]        = q_f32[b*NH + i];
        xT[(NH + i) * NB + b] = trow[i];
    }
}

// GRU matvec partials: grid (36 j-tiles, 9 chunks: 6 sx + 3 sh); atomicAdd.
__global__ __launch_bounds__(256) void gru_mm3_kernel(
    const float* __restrict__ Wih, const float* __restrict__ Whh,
    const float* __restrict__ xT, const float* __restrict__ hT,
    float* __restrict__ sx, float* __restrict__ sh)
{
    __shared__ float xs[8192];
    int t = threadIdx.x;
    int tj = t & 63, tq = t >> 6;
    int j = blockIdx.x * 64 + tj;
    int cg = blockIdx.y;
    const float* W; const float* src; float* dst; int c;
    if (cg < 6) { W = Wih; src = xT; dst = sx; c = cg; }
    else        { W = Whh; src = hT; dst = sh; c = cg - 6; }
    for (int idx = t; idx < 8192; idx += 256) xs[idx] = src[c * 8192 + idx];
    __syncthreads();
    float acc[8];
    #pragma unroll
    for (int bq = 0; bq < 8; ++bq) acc[bq] = 0.f;
    #pragma unroll 8
    for (int ii = 0; ii < 256; ++ii) {
        float w = W[(long)(c * 256 + ii) * H3 + j];
        #pragma unroll
        for (int bq = 0; bq < 8; ++bq) acc[bq] += xs[ii * 32 + tq * 8 + bq] * w;
    }
    #pragma unroll
    for (int bq = 0; bq < 8; ++bq)
        atomicAdd(&dst[(long)(tq * 8 + bq) * H3 + j], acc[bq]);
}

// Gate + h/q update; re-zeroes sx/sh for the next hop after reading.
__global__ void gate_kernel(const float* __restrict__ bih, const float* __restrict__ bhh,
                            float* __restrict__ sx, float* __restrict__ sh,
                            float* __restrict__ hT, float* __restrict__ q_f32,
                            float* __restrict__ out_h, int hop)
{
    int gid = blockIdx.x * 256 + threadIdx.x;
    int b = gid / NH, j = gid % NH;
    float xr = bih[j]        + sx[b*H3 + j];
    float xz = bih[NH + j]   + sx[b*H3 + NH + j];
    float xn = bih[1536 + j] + sx[b*H3 + 1536 + j];
    float hr = bhh[j]        + sh[b*H3 + j];
    float hz = bhh[NH + j]   + sh[b*H3 + NH + j];
    float hn = bhh[1536 + j] + sh[b*H3 + 1536 + j];
    sx[b*H3 + j] = 0.f; sx[b*H3 + NH + j] = 0.f; sx[b*H3 + 1536 + j] = 0.f;
    sh[b*H3 + j] = 0.f; sh[b*H3 + NH + j] = 0.f; sh[b*H3 + 1536 + j] = 0.f;
    float r = 1.f / (1.f + expf(-(xr + hr)));
    float z = 1.f / (1.f + expf(-(xz + hz)));
    float n = tanhf(xn + r * hn);
    float hp = hT[j * NB + b];
    float hnew = (1.f - z) * n + z * hp;
    hT[j * NB + b] = hnew;
    q_f32[gid] = hnew;
    out_h[(long)(b * 3 + hop) * NH + j] = hnew;
}

// ---------------------------------------------------------------------------
extern "C" void kernel_launch(void* const* d_in, const int* in_sizes, int n_in,
                              void* d_out, int out_size, void* d_ws, size_t ws_size,
                              hipStream_t stream)
{
    const float* question = (const float*)d_in[0];
    const float* text     = (const float*)d_in[1];
    const float* pw_W     = (const float*)d_in[2];
    const float* pw_b     = (const float*)d_in[3];
    const float* Ws_W     = (const float*)d_in[4];
    const float* Ws_b     = (const float*)d_in[5];
    const float* Wt_W     = (const float*)d_in[6];
    const float* Wt_b     = (const float*)d_in[7];
    const float* We_W     = (const float*)d_in[8];
    const float* We_b     = (const float*)d_in[9];
    const float* headw_W  = (const float*)d_in[10];
    const float* headw_b  = (const float*)d_in[11];
    const float* Wih      = (const float*)d_in[12];
    const float* Whh      = (const float*)d_in[13];
    const float* bih      = (const float*)d_in[14];
    const float* bhh      = (const float*)d_in[15];

    char* ws = (char*)d_ws;
    float* comb   = (float*)(ws + 0);
    float* combB  = (float*)(ws + 9437184);
    float* W_ht   = (float*)(ws + 9449472);
    float* scores = (float*)(ws + 9842688);
    float* q_f32  = (float*)(ws + 10104832);
    float* hT     = (float*)(ws + 10203136);
    float* xT     = (float*)(ws + 10301440);
    float* sx     = (float*)(ws + 10498048);
    float* sh     = (float*)(ws + 10792960);
    u16*   combTH = (u16*)  (ws + 11087872);
    u16*   combTL = (u16*)  (ws + 15806464);
    u16*   TP     = (u16*)  (ws + 20525056);
    u16*   textH  = (u16*)  (ws + 121188352);
    // prep scratch overlaid on TP region (dead before tp_gemm runs):
    u16*   WsTH   = (u16*)  (ws + 20525056);
    u16*   WsTL   = (u16*)  (ws + 25243648);
    u16*   pwH    = (u16*)  (ws + 29962240);
    u16*   pwL    = (u16*)  (ws + 34680832);

    int nstore = 0;
    if (ws_size >= (size_t)70856704) {
        long avail = (long)ws_size - 20525056L;
        nstore = (int)(avail / 25165824L);
        if (nstore > NK) nstore = NK;
    }
    const int tier = (nstore >= 1) ? 3
                   : (ws_size >= (size_t)20525056) ? 1 : 0;
    const bool haveTextH = (tier == 3) && (nstore == NK)
                        && (ws_size >= (size_t)146354176);

    float* out_prob = (float*)d_out;
    float* out_h    = (float*)d_out + NB * NS;

    prep_kernel<<<5424, 256, 0, stream>>>(Ws_W, pw_b, Ws_b, combB, question, q_f32, hT,
                                          sx, sh, pw_W, WsTH, WsTL, pwH, pwL,
                                          tier >= 3 ? 2 : tier);
    if (tier == 3) {
        comb_mfma_kernel<<<dim3(6, 6, 4), 256, 0, stream>>>(WsTH, WsTL, pwH, pwL,
                                                            combTH, combTL);
        // scratch dead from here; TP overwrites it.
        if (haveTextH) {
            split_text_kernel<<<12288, 256, 0, stream>>>(text, textH);
            tp_gemm_kernel<1><<<dim3(128, 6, nstore), 256, 0, stream>>>(
                text, textH, combTH, combTL, TP);
        } else {
            tp_gemm_kernel<0><<<dim3(128, 6, nstore), 256, 0, stream>>>(
                text, nullptr, combTH, combTL, TP);
        }
    } else {
        comb_valu_kernel<<<dim3(12, 6, 4), 256, 0, stream>>>(pw_W, Ws_W, comb);
        if (tier == 1)
            split_combT_kernel<<<2304, 256, 0, stream>>>(comb, combTH, combTL);
    }

    for (int hop = 0; hop < 3; ++hop) {
        wht2_kernel<<<384, 256, 0, stream>>>(q_f32, Wt_W, combB, Wt_b, W_ht);
        if (tier == 3) {
            if (nstore < NK)
                init_scores_kernel<<<(NK - nstore) * 64, 256, 0, stream>>>(
                    We_b, scores, nstore);
            score_pass_kernel<<<dim3(16, 32, nstore), 256, 0, stream>>>(
                TP, W_ht, We_W, We_b, scores);
            if (nstore < NK)
                fused_scores_mfma<0><<<dim3(128, 6, NK - nstore), 256, 0, stream>>>(
                    text, nullptr, nullptr, combTH, combTL, W_ht, We_W,
                    scores, nstore);
        } else if (tier == 1) {
            init_scores_kernel<<<256, 256, 0, stream>>>(We_b, scores, 0);
            fused_scores_mfma<0><<<dim3(128, 6, 4), 256, 0, stream>>>(
                text, nullptr, nullptr, combTH, combTL, W_ht, We_W, scores, 0);
        } else {
            init_scores_kernel<<<256, 256, 0, stream>>>(We_b, scores, 0);
            fused_scores_valu<<<dim3(256, 6, 4), 256, 0, stream>>>(
                text, comb, W_ht, We_W, scores);
        }
        softmax_kernel<<<32, 256, 0, stream>>>(scores, headw_W, headw_b, text,
                                               q_f32, xT, out_prob, hop);
        gru_mm3_kernel<<<dim3(36, 9), 256, 0, stream>>>(Wih, Whh, xT, hT, sx, sh);
        gate_kernel<<<96, 256, 0, stream>>>(bih, bhh, sx, sh, hT, q_f32, out_h, hop);
    }
}

// Round 7
// 632.917 us; speedup vs baseline: 1.9479x; 1.1004x over previous
//
#include <hip/hip_runtime.h>

typedef unsigned short u16;
typedef __bf16 bf16x8 __attribute__((ext_vector_type(8)));
typedef float f32x4 __attribute__((ext_vector_type(4)));

#define NB 32          // batch
#define NS 512         // seq
#define NH 768         // hidden
#define NK 4           // heads
#define NBS 16384      // B*S
#define H3 2304        // 3H
#define HH 589824      // 768*768

__device__ inline float bf2f(u16 u) {
    unsigned x = ((unsigned)u) << 16;
    return __builtin_bit_cast(float, x);
}
__device__ inline u16 f2bf(float f) {
    unsigned u = __builtin_bit_cast(unsigned, f);
    u += 0x7fffu + ((u >> 16) & 1u);
    return (u16)(u >> 16);
}
// fast tanh: 1 - 2*rcp(exp(2x)+1). ~5 VALU vs ~20+ for libm tanhf (no
// fast-math). err ~1e-6, far below the 2e-3 absmax budget. Saturates
// correctly: x>>0 -> exp=inf -> 1; x<<0 -> exp=0 -> -1.
__device__ inline float tanh_fast(float x) {
    float e = __expf(2.f * x);
    return 1.f - 2.f * __builtin_amdgcn_rcpf(e + 1.f);
}
__device__ inline float sig_fast(float x) {
    return __builtin_amdgcn_rcpf(1.f + __expf(-x));
}
// async global->LDS, 16B/lane; LDS dst = wave-uniform base + lane*16 (m97 recipe).
__device__ inline void gld16(const u16* g, u16* l) {
    __builtin_amdgcn_global_load_lds(
        (const __attribute__((address_space(1))) unsigned int*)g,
        (__attribute__((address_space(3))) unsigned int*)l, 16, 0, 0);
}

// ---------------------------------------------------------------------------
// Workspace layout (bytes):
//  comb    @ 0           9,437,184  f32 [4][768(h)][768(j)]  (tier 0/1 only)
//  combB   @ 9,437,184      12,288  f32 [4][768]
//  W_ht    @ 9,449,472     393,216  f32 [4][32][768]   (= Wtb + combB + q.Wt)
//  scores  @ 9,842,688     262,144  f32 [4][32][512]
//  q_f32   @ 10,104,832     98,304  f32 [32][768]
//  hT      @ 10,203,136     98,304  f32 [768][32]
//  xT      @ 10,301,440    196,608  f32 [1536][32]
//  sx      @ 10,498,048    294,912  f32 [32][2304]
//  sh      @ 10,792,960    294,912  f32 [32][2304]  -> 11,087,872
//  combTH  @ 11,087,872   4,718,592 bf16 [4][j][h] hi
//  combTL  @ 15,806,464   4,718,592 bf16 [4][j][h] lo   -> 20,525,056  TIER1
//  TP      @ 20,525,056   NSTORE x 25,165,824 bf16 [k][bs][j]  (TIER3)
//  textH   @ 121,188,352 25,165,824 bf16 [bs][h] hi  (NSTORE=4 &&
//                                    ws >= 146,354,176)
//  TIER3 prep scratch overlaid on TP region (consumed by comb_mfma BEFORE
//  tp_gemm writes TP):
//   WsTH @ 20,525,056  WsTL @ 25,243,648  pwH @ 29,962,240  pwL @ 34,680,832
//
// R6: hop-0 scores fused into tp_gemm epilogue (acc IS final TP; wht2 hoisted
// before tp_gemm; hop-0 score_pass eliminated); fast tanh/sigmoid via
// v_exp+v_rcp; split_text + scores=Web init folded into prep.
// ---------------------------------------------------------------------------

// P: one-time prep. grid up to 17968 (sections gated).
__global__ void prep_kernel(const float* __restrict__ WsW, const float* __restrict__ pwb,
                            const float* __restrict__ Wsb, float* __restrict__ combB,
                            const float* __restrict__ question,
                            float* __restrict__ q_f32, float* __restrict__ hT,
                            float* __restrict__ sx, float* __restrict__ sh,
                            const float* __restrict__ Web, float* __restrict__ scores,
                            const float* __restrict__ pwW,
                            u16* __restrict__ WsTH, u16* __restrict__ WsTL,
                            u16* __restrict__ pwH, u16* __restrict__ pwL,
                            const float* __restrict__ text, u16* __restrict__ textH,
                            int tier, int splitText)
{
    int bid = blockIdx.x, t = threadIdx.x;
    if (bid < 48) {
        int idx = bid * 64 + (t >> 2);      // 0..3071
        int ph = t & 3;
        int k = idx / NH, j = idx % NH;
        const float* W = WsW + (long)k * HH + j;
        const float* pb = pwb + k * NH;
        float acc = 0.f;
        #pragma unroll 8
        for (int m = ph * 192; m < ph * 192 + 192; ++m)
            acc += pb[m] * W[(long)m * NH];
        acc += __shfl_xor(acc, 1);
        acc += __shfl_xor(acc, 2);
        if (ph == 0) combB[idx] = acc + Wsb[idx];
    } else if (bid < 144) {
        int idx = (bid - 48) * 256 + t;
        q_f32[idx] = question[idx];
    } else if (bid < 240) {
        int idx = (bid - 144) * 256 + t;
        hT[idx] = 0.f;
    } else if (bid < 816) {
        int idx = (bid - 240) * 256 + t;    // 147,456 floats
        if (idx < 73728) sx[idx] = 0.f;
        else sh[idx - 73728] = 0.f;
    } else if (bid < 1072) {
        int idx = (bid - 816) * 256 + t;    // 65,536: scores = We_b (hop 0)
        scores[idx] = Web[idx >> 14];
    } else if (bid < 3376) {
        if (tier < 2) return;
        __shared__ float tile[32][33];
        int bid2 = bid - 1072;
        int k = bid2 / 576, rem = bid2 % 576, tr = rem / 24, tc = rem % 24;
        const float* src = WsW + (long)k * HH;
        long dbase = (long)k * HH;
        int tx = t & 31, ty = t >> 5;
        #pragma unroll
        for (int i = 0; i < 4; ++i)
            tile[tx][ty + i*8] = src[(long)(tr*32 + ty + i*8) * NH + tc*32 + tx];
        __syncthreads();
        #pragma unroll
        for (int i = 0; i < 4; ++i) {
            float v = tile[ty + i*8][tx];
            u16 hv = f2bf(v);
            u16 lv = f2bf(v - bf2f(hv));
            long o = dbase + (long)(tc*32 + ty + i*8) * NH + tr*32 + tx;
            WsTH[o] = hv; WsTL[o] = lv;
        }
    } else if (bid < 5680) {
        if (tier < 2) return;
        long base = (long)(bid - 3376) * 1024 + t * 4;
        float4 v = *(const float4*)(pwW + base);
        ushort4 hv, lv;
        hv.x = f2bf(v.x); lv.x = f2bf(v.x - bf2f(hv.x));
        hv.y = f2bf(v.y); lv.y = f2bf(v.y - bf2f(hv.y));
        hv.z = f2bf(v.z); lv.z = f2bf(v.z - bf2f(hv.z));
        hv.w = f2bf(v.w); lv.w = f2bf(v.w - bf2f(hv.w));
        *(ushort4*)(pwH + base) = hv;
        *(ushort4*)(pwL + base) = lv;
    } else {
        if (!splitText) return;
        long base = (long)(bid - 5680) * 1024 + t * 4;
        float4 v = *(const float4*)(text + base);
        ushort4 hv;
        hv.x = f2bf(v.x);
        hv.y = f2bf(v.y);
        hv.z = f2bf(v.z);
        hv.w = f2bf(v.w);
        *(ushort4*)(textH + base) = hv;
    }
}

// combT[k][j][h] = sum_m WsT[k][j][m] * pw[k][h][m], split-bf16 3-MFMA.
__global__ __launch_bounds__(256) void comb_mfma_kernel(
    const u16* __restrict__ WsTH, const u16* __restrict__ WsTL,
    const u16* __restrict__ pwH, const u16* __restrict__ pwL,
    u16* __restrict__ combTH, u16* __restrict__ combTL)
{
    __shared__ __align__(16) u16 AsH[128 * 32];
    __shared__ __align__(16) u16 AsL[128 * 32];
    __shared__ __align__(16) u16 BsH[128 * 32];
    __shared__ __align__(16) u16 BsL[128 * 32];
    const int t = threadIdx.x;
    const int wave = t >> 6, lane = t & 63;
    const int k = blockIdx.z;
    const long m0 = (long)blockIdx.x * 128;   // j-rows
    const int n0 = blockIdx.y * 128;          // h-cols
    const u16* AH = WsTH + (long)k * HH;
    const u16* AL = WsTL + (long)k * HH;
    const u16* BH = pwH + (long)k * HH;
    const u16* BL = pwL + (long)k * HH;

    const int r = t >> 2, ch = t & 3;
    const int wm = (wave & 1) * 64, wn = (wave >> 1) * 64;
    const int fr = lane & 15, fq = lane >> 4;

    f32x4 acc[4][4];
    #pragma unroll
    for (int i = 0; i < 4; ++i)
        #pragma unroll
        for (int j = 0; j < 4; ++j) acc[i][j] = (f32x4){0.f, 0.f, 0.f, 0.f};

    for (int k0 = 0; k0 < NH; k0 += 32) {
        gld16(AH + (m0 + r)      * NH + k0 + ch*8, AsH + t*8);
        gld16(AH + (m0 + 64 + r) * NH + k0 + ch*8, AsH + 2048 + t*8);
        gld16(AL + (m0 + r)      * NH + k0 + ch*8, AsL + t*8);
        gld16(AL + (m0 + 64 + r) * NH + k0 + ch*8, AsL + 2048 + t*8);
        gld16(BH + (long)(n0 + r)      * NH + k0 + ch*8, BsH + t*8);
        gld16(BH + (long)(n0 + 64 + r) * NH + k0 + ch*8, BsH + 2048 + t*8);
        gld16(BL + (long)(n0 + r)      * NH + k0 + ch*8, BsL + t*8);
        gld16(BL + (long)(n0 + 64 + r) * NH + k0 + ch*8, BsL + 2048 + t*8);
        __syncthreads();
        bf16x8 afH[4], afL[4], bfH[4], bfL[4];
        #pragma unroll
        for (int i = 0; i < 4; ++i) {
            afH[i] = *(const bf16x8*)(AsH + (wm + i*16 + fr)*32 + fq*8);
            afL[i] = *(const bf16x8*)(AsL + (wm + i*16 + fr)*32 + fq*8);
            bfH[i] = *(const bf16x8*)(BsH + (wn + i*16 + fr)*32 + fq*8);
            bfL[i] = *(const bf16x8*)(BsL + (wn + i*16 + fr)*32 + fq*8);
        }
        #pragma unroll
        for (int i = 0; i < 4; ++i)
            #pragma unroll
            for (int j = 0; j < 4; ++j) {
                acc[i][j] = __builtin_amdgcn_mfma_f32_16x16x32_bf16(afH[i], bfH[j], acc[i][j], 0, 0, 0);
                acc[i][j] = __builtin_amdgcn_mfma_f32_16x16x32_bf16(afH[i], bfL[j], acc[i][j], 0, 0, 0);
                acc[i][j] = __builtin_amdgcn_mfma_f32_16x16x32_bf16(afL[i], bfH[j], acc[i][j], 0, 0, 0);
            }
        __syncthreads();
    }
    long kb = (long)k * HH;
    #pragma unroll
    for (int i = 0; i < 4; ++i) {
        long m = m0 + wm + i*16 + fq*4;       // j-row
        #pragma unroll
        for (int j = 0; j < 4; ++j) {
            long n = n0 + wn + j*16 + fr;     // h-col
            #pragma unroll
            for (int rr = 0; rr < 4; ++rr) {
                float v = acc[i][j][rr];
                u16 hv = f2bf(v);
                u16 lv = f2bf(v - bf2f(hv));
                combTH[kb + (m + rr) * NH + n] = hv;
                combTL[kb + (m + rr) * NH + n] = lv;
            }
        }
    }
}

// tier 0/1: comb[k][h][j] f32 VALU GEMM (proven R8 kernel).
__global__ __launch_bounds__(256) void comb_valu_kernel(
    const float* __restrict__ pwW, const float* __restrict__ WsW,
    float* __restrict__ comb)
{
    __shared__ float AtT[32][68];
    __shared__ float Bt[32][132];
    const int t = threadIdx.x;
    const int m0 = blockIdx.x * 64, j0 = blockIdx.y * 128, k = blockIdx.z;
    const float* A = pwW + (long)k * HH;
    const float* B = WsW + (long)k * HH;
    const int r4 = (t >> 4) * 4, c8 = (t & 15) * 8;
    float acc[4][8];
    #pragma unroll
    for (int rr = 0; rr < 4; ++rr)
        #pragma unroll
        for (int cc = 0; cc < 8; ++cc) acc[rr][cc] = 0.f;
    for (int h0 = 0; h0 < NH; h0 += 32) {
        #pragma unroll
        for (int p = 0; p < 8; ++p) {
            int idx = p * 256 + t;
            int r = idx >> 5, hh = idx & 31;
            AtT[hh][r] = A[(long)(m0 + r) * NH + h0 + hh];
        }
        #pragma unroll
        for (int p = 0; p < 16; ++p) {
            int idx = p * 256 + t;
            int hh = idx >> 7, c = idx & 127;
            Bt[hh][c] = B[(long)(h0 + hh) * NH + j0 + c];
        }
        __syncthreads();
        for (int hh = 0; hh < 32; ++hh) {
            float4 av  = *(const float4*)&AtT[hh][r4];
            float4 bv0 = *(const float4*)&Bt[hh][c8];
            float4 bv1 = *(const float4*)&Bt[hh][c8 + 4];
            float a[4] = {av.x, av.y, av.z, av.w};
            float bb[8] = {bv0.x, bv0.y, bv0.z, bv0.w, bv1.x, bv1.y, bv1.z, bv1.w};
            #pragma unroll
            for (int rr = 0; rr < 4; ++rr)
                #pragma unroll
                for (int cc = 0; cc < 8; ++cc) acc[rr][cc] += a[rr] * bb[cc];
        }
        __syncthreads();
    }
    float* C = comb + (long)k * HH;
    #pragma unroll
    for (int rr = 0; rr < 4; ++rr)
        #pragma unroll
        for (int cc = 0; cc < 8; ++cc)
            C[(long)(m0 + r4 + rr) * NH + j0 + c8 + cc] = acc[rr][cc];
}

// tier1: transpose+split comb f32 -> combTH/combTL. grid 2304.
__global__ void split_combT_kernel(const float* __restrict__ comb,
                                   u16* __restrict__ combTH, u16* __restrict__ combTL)
{
    __shared__ float tile[32][33];
    int bid = blockIdx.x, t = threadIdx.x;
    int k = bid / 576, rem = bid % 576, tr = rem / 24, tc = rem % 24;
    const float* src = comb + (long)k * HH;
    long dbase = (long)k * HH;
    int tx = t & 31, ty = t >> 5;
    #pragma unroll
    for (int i = 0; i < 4; ++i)
        tile[tx][ty + i*8] = src[(long)(tr*32 + ty + i*8) * NH + tc*32 + tx];
    __syncthreads();
    #pragma unroll
    for (int i = 0; i < 4; ++i) {
        float v = tile[ty + i*8][tx];
        u16 hv = f2bf(v);
        u16 lv = f2bf(v - bf2f(hv));
        long o = dbase + (long)(tc*32 + ty + i*8) * NH + tr*32 + tx;
        combTH[o] = hv; combTL[o] = lv;
    }
}

// TIER3: TP[k][bs][j] = bf16((text @ comb[k])[bs][j]) for heads [0, NSTORE),
// PLUS hop-0 scores fused in the epilogue (acc is the final TP value; W_ht
// for hop 0 is computed by wht2 before this launch). grid (128, 6, NSTORE).
template <int AM>
__global__ __launch_bounds__(256) void tp_gemm_kernel(
    const float* __restrict__ textf, const u16* __restrict__ textH,
    const u16* __restrict__ combTH, const u16* __restrict__ combTL,
    const float* __restrict__ W_ht, const float* __restrict__ WeW,
    u16* __restrict__ TP, float* __restrict__ scores)
{
    __shared__ __align__(16) u16 AsH[128 * 32];
    __shared__ __align__(16) u16 BsH[128 * 32];
    __shared__ __align__(16) u16 BsL[128 * 32];
    __shared__ float wht_s[128];
    __shared__ float we_s[128];
    __shared__ float sred[128];
    const int t = threadIdx.x;
    const int wave = t >> 6, lane = t & 63;
    const int k = blockIdx.z;
    const long m0 = (long)blockIdx.x * 128;   // bs-rows
    const int n0 = blockIdx.y * 128;          // j-cols
    const int b = (int)(m0 >> 9), srow = (int)(m0 & 511);
    const u16* BH = combTH + (long)k * HH;
    const u16* BL = combTL + (long)k * HH;

    if (t < 128) {
        wht_s[t] = W_ht[((k << 5) + b) * NH + n0 + t];
        we_s[t]  = WeW[k * NH + n0 + t];
        sred[t]  = 0.f;
    }

    const int r = t >> 2, ch = t & 3;
    const int wm = (wave & 1) * 64, wn = (wave >> 1) * 64;
    const int fr = lane & 15, fq = lane >> 4;

    f32x4 acc[4][4];
    #pragma unroll
    for (int i = 0; i < 4; ++i)
        #pragma unroll
        for (int j = 0; j < 4; ++j) acc[i][j] = (f32x4){0.f, 0.f, 0.f, 0.f};

    for (int h0 = 0; h0 < NH; h0 += 32) {
        if (AM) {
            gld16(textH + (m0 + r)      * NH + h0 + ch*8, AsH + t*8);
            gld16(textH + (m0 + 64 + r) * NH + h0 + ch*8, AsH + 2048 + t*8);
        } else {
            #pragma unroll
            for (int p = 0; p < 4; ++p) {
                int task = p * 256 + t;
                int row = task >> 3, g = task & 7;
                float4 v = *(const float4*)(textf + (m0 + row) * NH + h0 + g*4);
                ushort4 hv;
                hv.x = f2bf(v.x);
                hv.y = f2bf(v.y);
                hv.z = f2bf(v.z);
                hv.w = f2bf(v.w);
                *(ushort4*)(AsH + row * 32 + g*4) = hv;
            }
        }
        gld16(BH + (long)(n0 + r)      * NH + h0 + ch*8, BsH + t*8);
        gld16(BH + (long)(n0 + 64 + r) * NH + h0 + ch*8, BsH + 2048 + t*8);
        gld16(BL + (long)(n0 + r)      * NH + h0 + ch*8, BsL + t*8);
        gld16(BL + (long)(n0 + 64 + r) * NH + h0 + ch*8, BsL + 2048 + t*8);
        __syncthreads();
        bf16x8 afH[4], bfH[4], bfL[4];
        #pragma unroll
        for (int i = 0; i < 4; ++i) {
            afH[i] = *(const bf16x8*)(AsH + (wm + i*16 + fr)*32 + fq*8);
            bfH[i] = *(const bf16x8*)(BsH + (wn + i*16 + fr)*32 + fq*8);
            bfL[i] = *(const bf16x8*)(BsL + (wn + i*16 + fr)*32 + fq*8);
        }
        #pragma unroll
        for (int i = 0; i < 4; ++i)
            #pragma unroll
            for (int j = 0; j < 4; ++j) {
                acc[i][j] = __builtin_amdgcn_mfma_f32_16x16x32_bf16(afH[i], bfH[j], acc[i][j], 0, 0, 0);
                acc[i][j] = __builtin_amdgcn_mfma_f32_16x16x32_bf16(afH[i], bfL[j], acc[i][j], 0, 0, 0);
            }
        __syncthreads();
    }
    u16* out = TP + ((long)k * NBS + m0) * NH + n0;
    #pragma unroll
    for (int i = 0; i < 4; ++i) {
        #pragma unroll
        for (int rr = 0; rr < 4; ++rr) {
            int m = wm + i*16 + fq*4 + rr;
            #pragma unroll
            for (int j = 0; j < 4; ++j) {
                int n = wn + j*16 + fr;
                out[(long)m * NH + n] = f2bf(acc[i][j][rr]);
            }
        }
    }
    // hop-0 scores: partial over this block's 128 j-cols, atomicAdd combine
    // across the 6 y-blocks (proven fused_scores_mfma epilogue).
    #pragma unroll
    for (int i = 0; i < 4; ++i) {
        #pragma unroll
        for (int rr = 0; rr < 4; ++rr) {
            int m = wm + i*16 + fq*4 + rr;
            float part = 0.f;
            #pragma unroll
            for (int j = 0; j < 4; ++j) {
                int n = wn + j*16 + fr;
                part += tanh_fast(acc[i][j][rr] + wht_s[n]) * we_s[n];
            }
            part += __shfl_xor(part, 1);
            part += __shfl_xor(part, 2);
            part += __shfl_xor(part, 4);
            part += __shfl_xor(part, 8);
            if (fr == 0) atomicAdd(&sred[m], part);
        }
    }
    __syncthreads();
    if (t < 128)
        atomicAdd(&scores[(((k << 5) + b) << 9) + srow + t], sred[t]);
}

// hops 1,2: scores[k][b][s] = We_b[k] + sum_j tanh(TP + W_ht)*We for stored
// heads. grid (16, 32, NSTORE).
__global__ __launch_bounds__(256) void score_pass_kernel(
    const u16* __restrict__ TP, const float* __restrict__ W_ht,
    const float* __restrict__ WeW, const float* __restrict__ Web,
    float* __restrict__ scores)
{
    __shared__ __align__(16) float bias_s[NH];
    __shared__ __align__(16) float we_s[NH];
    const int t = threadIdx.x;
    const int k = blockIdx.z, b = blockIdx.y;
    const int s0 = blockIdx.x * 32;
    for (int i = t; i < NH; i += 256) {
        bias_s[i] = W_ht[((k << 5) + b) * NH + i];
        we_s[i]   = WeW[k * NH + i];
    }
    __syncthreads();
    const int wave = t >> 6, lane = t & 63;
    const u16* tpb = TP + ((long)k * NBS + (b << 9) + s0) * NH;
    const float web = Web[k];
    for (int sr = wave; sr < 32; sr += 4) {
        const u16* row = tpb + (long)sr * NH;
        float part = 0.f;
        #pragma unroll
        for (int p = 0; p < 3; ++p) {
            const int j = p * 256 + lane * 4;   // 8B/lane bf16 loads, coalesced 512B
            ushort4 v = *(const ushort4*)(row + j);
            float4 bb = *(const float4*)(bias_s + j);
            float4 ww = *(const float4*)(we_s + j);
            part += tanh_fast(bf2f(v.x) + bb.x) * ww.x;
            part += tanh_fast(bf2f(v.y) + bb.y) * ww.y;
            part += tanh_fast(bf2f(v.z) + bb.z) * ww.z;
            part += tanh_fast(bf2f(v.w) + bb.w) * ww.w;
        }
        part += __shfl_xor(part, 1);
        part += __shfl_xor(part, 2);
        part += __shfl_xor(part, 4);
        part += __shfl_xor(part, 8);
        part += __shfl_xor(part, 16);
        part += __shfl_xor(part, 32);
        if (lane == 0) scores[(((k << 5) + b) << 9) + s0 + sr] = part + web;
    }
}

// scores = We_b for heads [koff, NK) (ahead of atomicAdd fused path).
__global__ void init_scores_kernel(const float* __restrict__ Web,
                                   float* __restrict__ scores, int koff)
{
    int idx = (koff << 14) + blockIdx.x * 256 + threadIdx.x;
    scores[idx] = Web[idx >> 14];
}

// W_ht[k][b][j] = Wtb + combB + q.Wt  (full dot, no atomics). grid 384.
__global__ __launch_bounds__(256) void wht2_kernel(
    const float* __restrict__ q, const float* __restrict__ WtW,
    const float* __restrict__ combB, const float* __restrict__ Wtb,
    float* __restrict__ W_ht)
{
    int bid = blockIdx.x;                 // 4k x 32b x 3jt
    int k = bid / 96, rem = bid % 96, b = rem / 3, jt = rem % 3;
    int j = jt * 256 + threadIdx.x;
    const float* W = WtW + (long)k * HH + j;
    const float* qb = q + b * NH;
    float acc = 0.f;
    #pragma unroll 8
    for (int h = 0; h < NH; ++h) acc += qb[h] * W[(long)h * NH];
    W_ht[(k*NB + b) * NH + j] = acc + Wtb[k * NH + j] + combB[k * NH + j];
}

// ---------------------------------------------------------------------------
// MFMA split-bf16 fused scores (W_ht includes combB), head-offset koff.
// grid (128, 6, nheads).
// ---------------------------------------------------------------------------
template <int AM>
__global__ __launch_bounds__(256) void fused_scores_mfma(
    const float* __restrict__ textf,
    const u16* __restrict__ textH, const u16* __restrict__ textL,
    const u16* __restrict__ combTH, const u16* __restrict__ combTL,
    const float* __restrict__ W_ht,
    const float* __restrict__ WeW, float* __restrict__ scores, int koff)
{
    __shared__ __align__(16) u16 AsH[128 * 32];
    __shared__ __align__(16) u16 AsL[128 * 32];
    __shared__ __align__(16) u16 BsH[128 * 32];
    __shared__ __align__(16) u16 BsL[128 * 32];
    __shared__ float wht_s[128];
    __shared__ float we_s[128];
    __shared__ float sred[128];
    const int t = threadIdx.x;
    const int wave = t >> 6, lane = t & 63;
    const int k = koff + blockIdx.z;
    const long m0 = (long)blockIdx.x * 128;
    const int n0 = blockIdx.y * 128;
    const int b = (int)(m0 >> 9), srow = (int)(m0 & 511);
    const u16* BH = combTH + (long)k * HH;
    const u16* BL = combTL + (long)k * HH;

    if (t < 128) {
        wht_s[t] = W_ht[((k << 5) + b) * NH + n0 + t];
        we_s[t]  = WeW[k * NH + n0 + t];
        sred[t]  = 0.f;
    }

    const int r = t >> 2, ch = t & 3;
    const int wm = (wave & 1) * 64, wn = (wave >> 1) * 64;
    const int fr = lane & 15, fq = lane >> 4;

    f32x4 acc[4][4];
    #pragma unroll
    for (int i = 0; i < 4; ++i)
        #pragma unroll
        for (int j = 0; j < 4; ++j) acc[i][j] = (f32x4){0.f, 0.f, 0.f, 0.f};

    for (int h0 = 0; h0 < NH; h0 += 32) {
        if (AM) {
            gld16(textH + (m0 + r)      * NH + h0 + ch*8, AsH + t*8);
            gld16(textH + (m0 + 64 + r) * NH + h0 + ch*8, AsH + 2048 + t*8);
            gld16(textL + (m0 + r)      * NH + h0 + ch*8, AsL + t*8);
            gld16(textL + (m0 + 64 + r) * NH + h0 + ch*8, AsL + 2048 + t*8);
        } else {
            #pragma unroll
            for (int p = 0; p < 4; ++p) {
                int task = p * 256 + t;
                int row = task >> 3, g = task & 7;
                float4 v = *(const float4*)(textf + (m0 + row) * NH + h0 + g*4);
                ushort4 hv, lv;
                hv.x = f2bf(v.x); lv.x = f2bf(v.x - bf2f(hv.x));
                hv.y = f2bf(v.y); lv.y = f2bf(v.y - bf2f(hv.y));
                hv.z = f2bf(v.z); lv.z = f2bf(v.z - bf2f(hv.z));
                hv.w = f2bf(v.w); lv.w = f2bf(v.w - bf2f(hv.w));
                *(ushort4*)(AsH + row * 32 + g*4) = hv;
                *(ushort4*)(AsL + row * 32 + g*4) = lv;
            }
        }
        gld16(BH + (long)(n0 + r)      * NH + h0 + ch*8, BsH + t*8);
        gld16(BH + (long)(n0 + 64 + r) * NH + h0 + ch*8, BsH + 2048 + t*8);
        gld16(BL + (long)(n0 + r)      * NH + h0 + ch*8, BsL + t*8);
        gld16(BL + (long)(n0 + 64 + r) * NH + h0 + ch*8, BsL + 2048 + t*8);
        __syncthreads();
        bf16x8 afH[4], afL[4], bfH[4], bfL[4];
        #pragma unroll
        for (int i = 0; i < 4; ++i) {
            afH[i] = *(const bf16x8*)(AsH + (wm + i*16 + fr)*32 + fq*8);
            afL[i] = *(const bf16x8*)(AsL + (wm + i*16 + fr)*32 + fq*8);
            bfH[i] = *(const bf16x8*)(BsH + (wn + i*16 + fr)*32 + fq*8);
            bfL[i] = *(const bf16x8*)(BsL + (wn + i*16 + fr)*32 + fq*8);
        }
        #pragma unroll
        for (int i = 0; i < 4; ++i)
            #pragma unroll
            for (int j = 0; j < 4; ++j) {
                acc[i][j] = __builtin_amdgcn_mfma_f32_16x16x32_bf16(afH[i], bfH[j], acc[i][j], 0, 0, 0);
                acc[i][j] = __builtin_amdgcn_mfma_f32_16x16x32_bf16(afH[i], bfL[j], acc[i][j], 0, 0, 0);
                acc[i][j] = __builtin_amdgcn_mfma_f32_16x16x32_bf16(afL[i], bfH[j], acc[i][j], 0, 0, 0);
            }
        __syncthreads();
    }
    #pragma unroll
    for (int i = 0; i < 4; ++i) {
        #pragma unroll
        for (int rr = 0; rr < 4; ++rr) {
            int m = wm + i*16 + fq*4 + rr;
            float part = 0.f;
            #pragma unroll
            for (int j = 0; j < 4; ++j) {
                int n = wn + j*16 + fr;
                part += tanh_fast(acc[i][j][rr] + wht_s[n]) * we_s[n];
            }
            part += __shfl_xor(part, 1);
            part += __shfl_xor(part, 2);
            part += __shfl_xor(part, 4);
            part += __shfl_xor(part, 8);
            if (fr == 0) atomicAdd(&sred[m], part);
        }
    }
    __syncthreads();
    if (t < 128)
        atomicAdd(&scores[(((k << 5) + b) << 9) + srow + t], sred[t]);
}

// tier0 fallback (W_ht includes combB). grid (256, 6, 4).
__global__ __launch_bounds__(256) void fused_scores_valu(
    const float* __restrict__ text, const float* __restrict__ comb,
    const float* __restrict__ W_ht,
    const float* __restrict__ WeW, float* __restrict__ scores)
{
    __shared__ float AtT[32][68];
    __shared__ float Bt[32][132];
    __shared__ float wht_s[128];
    __shared__ float we_s[128];
    __shared__ float sred[64];
    const int t = threadIdx.x;
    const int row0 = blockIdx.x * 64;
    const int j0 = blockIdx.y * 128, k = blockIdx.z;
    const int b = row0 >> 9, s0 = row0 & 511;
    const float* B = comb + (long)k * HH;
    const int r4 = (t >> 4) * 4, c8 = (t & 15) * 8;
    if (t < 128) {
        wht_s[t] = W_ht[((k << 5) + b) * NH + j0 + t];
        we_s[t]  = WeW[k * NH + j0 + t];
    }
    if (t < 64) sred[t] = 0.f;
    float acc[4][8];
    #pragma unroll
    for (int rr = 0; rr < 4; ++rr)
        #pragma unroll
        for (int cc = 0; cc < 8; ++cc) acc[rr][cc] = 0.f;
    for (int h0 = 0; h0 < NH; h0 += 32) {
        #pragma unroll
        for (int p = 0; p < 8; ++p) {
            int idx = p * 256 + t;
            int r = idx >> 5, hh = idx & 31;
            AtT[hh][r] = text[(long)(row0 + r) * NH + h0 + hh];
        }
        #pragma unroll
        for (int p = 0; p < 16; ++p) {
            int idx = p * 256 + t;
            int hh = idx >> 7, c = idx & 127;
            Bt[hh][c] = B[(long)(h0 + hh) * NH + j0 + c];
        }
        __syncthreads();
        for (int hh = 0; hh < 32; ++hh) {
            float4 av  = *(const float4*)&AtT[hh][r4];
            float4 bv0 = *(const float4*)&Bt[hh][c8];
            float4 bv1 = *(const float4*)&Bt[hh][c8 + 4];
            float a[4] = {av.x, av.y, av.z, av.w};
            float bb[8] = {bv0.x, bv0.y, bv0.z, bv0.w, bv1.x, bv1.y, bv1.z, bv1.w};
            #pragma unroll
            for (int rr = 0; rr < 4; ++rr)
                #pragma unroll
                for (int cc = 0; cc < 8; ++cc) acc[rr][cc] += a[rr] * bb[cc];
        }
        __syncthreads();
    }
    float part[4] = {0.f, 0.f, 0.f, 0.f};
    #pragma unroll
    for (int rr = 0; rr < 4; ++rr)
        #pragma unroll
        for (int cc = 0; cc < 8; ++cc)
            part[rr] += tanh_fast(acc[rr][cc] + wht_s[c8 + cc]) * we_s[c8 + cc];
    #pragma unroll
    for (int rr = 0; rr < 4; ++rr)
        atomicAdd(&sred[r4 + rr], part[rr]);
    __syncthreads();
    if (t < 64)
        atomicAdd(&scores[(((k << 5) + b) << 9) + s0 + t], sred[t]);
}

// Shuffle-based softmax + head-combine + argmax + xT build. grid 32.
__global__ void softmax_kernel(const float* __restrict__ scores,
                               const float* __restrict__ headw_W, const float* __restrict__ headw_b,
                               const float* __restrict__ text,
                               const float* __restrict__ q_f32,
                               float* __restrict__ xT, float* __restrict__ out_prob, int hop)
{
    __shared__ float sc[NK][NS];
    __shared__ float cred[4];
    __shared__ float cval[4];
    __shared__ int   cidx[4];
    int b = blockIdx.x, t = threadIdx.x;
    int wave = t >> 6, lane = t & 63;
    for (int i = t; i < NK * NS; i += 256) {
        int k = i >> 9, s = i & 511;
        sc[k][s] = scores[((k*NB + b) << 9) + s];
    }
    __syncthreads();
    float fac[NK];
    for (int k = 0; k < NK; ++k) {
        float v0 = sc[k][t], v1 = sc[k][t + 256];
        float m = fmaxf(v0, v1);
        #pragma unroll
        for (int o = 32; o > 0; o >>= 1) m = fmaxf(m, __shfl_xor(m, o));
        if (lane == 0) cred[wave] = m;
        __syncthreads();
        float mx = fmaxf(fmaxf(cred[0], cred[1]), fmaxf(cred[2], cred[3]));
        __syncthreads();
        float e0 = __expf(v0 - mx), e1 = __expf(v1 - mx);
        sc[k][t] = e0; sc[k][t + 256] = e1;
        float sm = e0 + e1;
        #pragma unroll
        for (int o = 32; o > 0; o >>= 1) sm += __shfl_xor(sm, o);
        if (lane == 0) cred[wave] = sm;
        __syncthreads();
        fac[k] = headw_W[k] / (cred[0] + cred[1] + cred[2] + cred[3]);
        __syncthreads();
    }
    float hwb = headw_b[0];
    float a0 = hwb, a1 = hwb;
    for (int k = 0; k < NK; ++k) { a0 += sc[k][t] * fac[k]; a1 += sc[k][t + 256] * fac[k]; }
    float ss = a0*a0 + a1*a1;
    #pragma unroll
    for (int o = 32; o > 0; o >>= 1) ss += __shfl_xor(ss, o);
    float bv; int bi;
    if (a0 >= a1) { bv = a0; bi = t; } else { bv = a1; bi = t + 256; }
    #pragma unroll
    for (int o = 1; o < 64; o <<= 1) {
        float ov = __shfl_xor(bv, o);
        int   oi = __shfl_xor(bi, o);
        if (ov > bv || (ov == bv && oi < bi)) { bv = ov; bi = oi; }
    }
    if (lane == 0) { cred[wave] = ss; cval[wave] = bv; cidx[wave] = bi; }
    __syncthreads();
    float scale = sqrtf(cred[0] + cred[1] + cred[2] + cred[3]);
    float mbv = cval[0]; int mbi = cidx[0];
    #pragma unroll
    for (int w = 1; w < 4; ++w)
        if (cval[w] > mbv || (cval[w] == mbv && cidx[w] < mbi)) { mbv = cval[w]; mbi = cidx[w]; }
    int idx = mbi;
    if (hop == 0) {
        out_prob[(b << 9) + t]       = a0 / scale;
        out_prob[(b << 9) + t + 256] = a1 / scale;
    }
    const float* trow = text + (long)(b * NS + idx) * NH;
    for (int i = t; i < NH; i += 256) {
        xT[i * NB + b]        = q_f32[b*NH + i];
        xT[(NH + i) * NB + b] = trow[i];
    }
}

// GRU matvec partials: grid (36 j-tiles, 9 chunks: 6 sx + 3 sh); atomicAdd.
__global__ __launch_bounds__(256) void gru_mm3_kernel(
    const float* __restrict__ Wih, const float* __restrict__ Whh,
    const float* __restrict__ xT, const float* __restrict__ hT,
    float* __restrict__ sx, float* __restrict__ sh)
{
    __shared__ float xs[8192];
    int t = threadIdx.x;
    int tj = t & 63, tq = t >> 6;
    int j = blockIdx.x * 64 + tj;
    int cg = blockIdx.y;
    const float* W; const float* src; float* dst; int c;
    if (cg < 6) { W = Wih; src = xT; dst = sx; c = cg; }
    else        { W = Whh; src = hT; dst = sh; c = cg - 6; }
    for (int idx = t; idx < 8192; idx += 256) xs[idx] = src[c * 8192 + idx];
    __syncthreads();
    float acc[8];
    #pragma unroll
    for (int bq = 0; bq < 8; ++bq) acc[bq] = 0.f;
    #pragma unroll 8
    for (int ii = 0; ii < 256; ++ii) {
        float w = W[(long)(c * 256 + ii) * H3 + j];
        #pragma unroll
        for (int bq = 0; bq < 8; ++bq) acc[bq] += xs[ii * 32 + tq * 8 + bq] * w;
    }
    #pragma unroll
    for (int bq = 0; bq < 8; ++bq)
        atomicAdd(&dst[(long)(tq * 8 + bq) * H3 + j], acc[bq]);
}

// Gate + h/q update; re-zeroes sx/sh for the next hop after reading.
__global__ void gate_kernel(const float* __restrict__ bih, const float* __restrict__ bhh,
                            float* __restrict__ sx, float* __restrict__ sh,
                            float* __restrict__ hT, float* __restrict__ q_f32,
                            float* __restrict__ out_h, int hop)
{
    int gid = blockIdx.x * 256 + threadIdx.x;
    int b = gid / NH, j = gid % NH;
    float xr = bih[j]        + sx[b*H3 + j];
    float xz = bih[NH + j]   + sx[b*H3 + NH + j];
    float xn = bih[1536 + j] + sx[b*H3 + 1536 + j];
    float hr = bhh[j]        + sh[b*H3 + j];
    float hz = bhh[NH + j]   + sh[b*H3 + NH + j];
    float hn = bhh[1536 + j] + sh[b*H3 + 1536 + j];
    sx[b*H3 + j] = 0.f; sx[b*H3 + NH + j] = 0.f; sx[b*H3 + 1536 + j] = 0.f;
    sh[b*H3 + j] = 0.f; sh[b*H3 + NH + j] = 0.f; sh[b*H3 + 1536 + j] = 0.f;
    float r = sig_fast(xr + hr);
    float z = sig_fast(xz + hz);
    float n = tanh_fast(xn + r * hn);
    float hp = hT[j * NB + b];
    float hnew = (1.f - z) * n + z * hp;
    hT[j * NB + b] = hnew;
    q_f32[gid] = hnew;
    out_h[(long)(b * 3 + hop) * NH + j] = hnew;
}

// ---------------------------------------------------------------------------
extern "C" void kernel_launch(void* const* d_in, const int* in_sizes, int n_in,
                              void* d_out, int out_size, void* d_ws, size_t ws_size,
                              hipStream_t stream)
{
    const float* question = (const float*)d_in[0];
    const float* text     = (const float*)d_in[1];
    const float* pw_W     = (const float*)d_in[2];
    const float* pw_b     = (const float*)d_in[3];
    const float* Ws_W     = (const float*)d_in[4];
    const float* Ws_b     = (const float*)d_in[5];
    const float* Wt_W     = (const float*)d_in[6];
    const float* Wt_b     = (const float*)d_in[7];
    const float* We_W     = (const float*)d_in[8];
    const float* We_b     = (const float*)d_in[9];
    const float* headw_W  = (const float*)d_in[10];
    const float* headw_b  = (const float*)d_in[11];
    const float* Wih      = (const float*)d_in[12];
    const float* Whh      = (const float*)d_in[13];
    const float* bih      = (const float*)d_in[14];
    const float* bhh      = (const float*)d_in[15];

    char* ws = (char*)d_ws;
    float* comb   = (float*)(ws + 0);
    float* combB  = (float*)(ws + 9437184);
    float* W_ht   = (float*)(ws + 9449472);
    float* scores = (float*)(ws + 9842688);
    float* q_f32  = (float*)(ws + 10104832);
    float* hT     = (float*)(ws + 10203136);
    float* xT     = (float*)(ws + 10301440);
    float* sx     = (float*)(ws + 10498048);
    float* sh     = (float*)(ws + 10792960);
    u16*   combTH = (u16*)  (ws + 11087872);
    u16*   combTL = (u16*)  (ws + 15806464);
    u16*   TP     = (u16*)  (ws + 20525056);
    u16*   textH  = (u16*)  (ws + 121188352);
    // prep scratch overlaid on TP region (dead before tp_gemm runs):
    u16*   WsTH   = (u16*)  (ws + 20525056);
    u16*   WsTL   = (u16*)  (ws + 25243648);
    u16*   pwH    = (u16*)  (ws + 29962240);
    u16*   pwL    = (u16*)  (ws + 34680832);

    int nstore = 0;
    if (ws_size >= (size_t)70856704) {
        long avail = (long)ws_size - 20525056L;
        nstore = (int)(avail / 25165824L);
        if (nstore > NK) nstore = NK;
    }
    const int tier = (nstore >= 1) ? 3
                   : (ws_size >= (size_t)20525056) ? 1 : 0;
    const bool haveTextH = (tier == 3) && (nstore == NK)
                        && (ws_size >= (size_t)146354176);

    float* out_prob = (float*)d_out;
    float* out_h    = (float*)d_out + NB * NS;

    const int prepGrid = haveTextH ? 17968 : (tier >= 2 ? 5680 : 1072);
    prep_kernel<<<prepGrid, 256, 0, stream>>>(
        Ws_W, pw_b, Ws_b, combB, question, q_f32, hT, sx, sh, We_b, scores,
        pw_W, WsTH, WsTL, pwH, pwL, text, textH,
        tier >= 3 ? 2 : tier, haveTextH ? 1 : 0);

    if (tier == 3) {
        comb_mfma_kernel<<<dim3(6, 6, 4), 256, 0, stream>>>(WsTH, WsTL, pwH, pwL,
                                                            combTH, combTL);
        wht2_kernel<<<384, 256, 0, stream>>>(q_f32, Wt_W, combB, Wt_b, W_ht);  // hop 0
        // scratch dead from here; TP overwrites it. tp_gemm also emits hop-0
        // scores (atomicAdd onto prep's We_b init) for heads [0, nstore).
        if (haveTextH) {
            tp_gemm_kernel<1><<<dim3(128, 6, nstore), 256, 0, stream>>>(
                text, textH, combTH, combTL, W_ht, We_W, TP, scores);
        } else {
            tp_gemm_kernel<0><<<dim3(128, 6, nstore), 256, 0, stream>>>(
                text, nullptr, combTH, combTL, W_ht, We_W, TP, scores);
        }
    } else {
        comb_valu_kernel<<<dim3(12, 6, 4), 256, 0, stream>>>(pw_W, Ws_W, comb);
        if (tier == 1)
            split_combT_kernel<<<2304, 256, 0, stream>>>(comb, combTH, combTL);
    }

    for (int hop = 0; hop < 3; ++hop) {
        if (tier == 3) {
            if (hop > 0) {
                wht2_kernel<<<384, 256, 0, stream>>>(q_f32, Wt_W, combB, Wt_b, W_ht);
                score_pass_kernel<<<dim3(16, 32, nstore), 256, 0, stream>>>(
                    TP, W_ht, We_W, We_b, scores);
                if (nstore < NK) {
                    init_scores_kernel<<<(NK - nstore) * 64, 256, 0, stream>>>(
                        We_b, scores, nstore);
                    fused_scores_mfma<0><<<dim3(128, 6, NK - nstore), 256, 0, stream>>>(
                        text, nullptr, nullptr, combTH, combTL, W_ht, We_W,
                        scores, nstore);
                }
            } else if (nstore < NK) {
                // hop 0 leftover heads: scores pre-init'd to We_b by prep.
                fused_scores_mfma<0><<<dim3(128, 6, NK - nstore), 256, 0, stream>>>(
                    text, nullptr, nullptr, combTH, combTL, W_ht, We_W,
                    scores, nstore);
            }
        } else {
            wht2_kernel<<<384, 256, 0, stream>>>(q_f32, Wt_W, combB, Wt_b, W_ht);
            init_scores_kernel<<<256, 256, 0, stream>>>(We_b, scores, 0);
            if (tier == 1)
                fused_scores_mfma<0><<<dim3(128, 6, 4), 256, 0, stream>>>(
                    text, nullptr, nullptr, combTH, combTL, W_ht, We_W, scores, 0);
            else
                fused_scores_valu<<<dim3(256, 6, 4), 256, 0, stream>>>(
                    text, comb, W_ht, We_W, scores);
        }
        softmax_kernel<<<32, 256, 0, stream>>>(scores, headw_W, headw_b, text,
                                               q_f32, xT, out_prob, hop);
        gru_mm3_kernel<<<dim3(36, 9), 256, 0, stream>>>(Wih, Whh, xT, hT, sx, sh);
        gate_kernel<<<96, 256, 0, stream>>>(bih, bhh, sx, sh, hT, q_f32, out_h, hop);
    }
}

// Round 9
// 630.657 us; speedup vs baseline: 1.9549x; 1.0036x over previous
//
#include <hip/hip_runtime.h>

typedef unsigned short u16;
typedef __bf16 bf16x8 __attribute__((ext_vector_type(8)));
typedef float f32x4 __attribute__((ext_vector_type(4)));

#define NB 32          // batch
#define NS 512         // seq
#define NH 768         // hidden
#define NK 4           // heads
#define NBS 16384      // B*S
#define H3 2304        // 3H
#define HH 589824      // 768*768

__device__ inline float bf2f(u16 u) {
    unsigned x = ((unsigned)u) << 16;
    return __builtin_bit_cast(float, x);
}
__device__ inline u16 f2bf(float f) {
    unsigned u = __builtin_bit_cast(unsigned, f);
    u += 0x7fffu + ((u >> 16) & 1u);
    return (u16)(u >> 16);
}
// fast tanh: 1 - 2*rcp(exp(2x)+1). ~5 VALU vs ~20+ for libm tanhf. err ~1e-6.
__device__ inline float tanh_fast(float x) {
    float e = __expf(2.f * x);
    return 1.f - 2.f * __builtin_amdgcn_rcpf(e + 1.f);
}
__device__ inline float sig_fast(float x) {
    return __builtin_amdgcn_rcpf(1.f + __expf(-x));
}
// async global->LDS, 16B/lane; LDS dst = wave-uniform base + lane*16 (m97 recipe).
__device__ inline void gld16(const u16* g, u16* l) {
    __builtin_amdgcn_global_load_lds(
        (const __attribute__((address_space(1))) unsigned int*)g,
        (__attribute__((address_space(3))) unsigned int*)l, 16, 0, 0);
}

// ---------------------------------------------------------------------------
// Workspace layout (bytes):
//  comb    @ 0           9,437,184  f32 [4][768(h)][768(j)]  (tier 0/1 only)
//  combB   @ 9,437,184      12,288  f32 [4][768]
//  W_ht    @ 9,449,472     393,216  f32 [4][32][768]   (= Wtb + combB + q.Wt)
//  scores  @ 9,842,688     262,144  f32 [4][32][512]
//  q_f32   @ 10,104,832     98,304  f32 [32][768]
//  hT      @ 10,203,136     98,304  f32 [768][32]
//  xT      @ 10,301,440    196,608  f32 [1536][32]
//  sx      @ 10,498,048    294,912  f32 [32][2304]
//  sh      @ 10,792,960    294,912  f32 [32][2304]  -> 11,087,872
//  combTH  @ 11,087,872   4,718,592 bf16 [4][j][h] hi
//  combTL  @ 15,806,464   4,718,592 bf16 [4][j][h] lo   -> 20,525,056  TIER1
//  TP      @ 20,525,056   NSTORE x 25,165,824 bf16 [k][bs][j]  (TIER3)
//  textH   @ 121,188,352 25,165,824 bf16 [bs][h] hi  (NSTORE=4 &&
//                                    ws >= 146,354,176)
//  TIER3 prep scratch overlaid on TP region (consumed by comb_mfma BEFORE
//  tp_gemm writes TP):
//   WsTH @ 20,525,056  WsTL @ 25,243,648  pwH @ 29,962,240  pwL @ 34,680,832
//
// R8: hop-0 epilogue UN-fused from tp_gemm (R7 measured fusion cost 39 us vs
// 18 us standalone score_pass — VGPR 88->116, MfmaUtil 37->30); tp_gemm
// BK=32->64 (halves barrier count; 48 KB LDS keeps 3 blocks/CU; m233: the
// 2-phase loop's cost is stage+drain+barrier, not LDS reads); all hops use
// score_pass; fast tanh/sigmoid kept.
// ---------------------------------------------------------------------------

// P: one-time prep. grid up to 17968 (sections gated).
__global__ void prep_kernel(const float* __restrict__ WsW, const float* __restrict__ pwb,
                            const float* __restrict__ Wsb, float* __restrict__ combB,
                            const float* __restrict__ question,
                            float* __restrict__ q_f32, float* __restrict__ hT,
                            float* __restrict__ sx, float* __restrict__ sh,
                            const float* __restrict__ Web, float* __restrict__ scores,
                            const float* __restrict__ pwW,
                            u16* __restrict__ WsTH, u16* __restrict__ WsTL,
                            u16* __restrict__ pwH, u16* __restrict__ pwL,
                            const float* __restrict__ text, u16* __restrict__ textH,
                            int tier, int splitText)
{
    int bid = blockIdx.x, t = threadIdx.x;
    if (bid < 48) {
        int idx = bid * 64 + (t >> 2);      // 0..3071
        int ph = t & 3;
        int k = idx / NH, j = idx % NH;
        const float* W = WsW + (long)k * HH + j;
        const float* pb = pwb + k * NH;
        float acc = 0.f;
        #pragma unroll 8
        for (int m = ph * 192; m < ph * 192 + 192; ++m)
            acc += pb[m] * W[(long)m * NH];
        acc += __shfl_xor(acc, 1);
        acc += __shfl_xor(acc, 2);
        if (ph == 0) combB[idx] = acc + Wsb[idx];
    } else if (bid < 144) {
        int idx = (bid - 48) * 256 + t;
        q_f32[idx] = question[idx];
    } else if (bid < 240) {
        int idx = (bid - 144) * 256 + t;
        hT[idx] = 0.f;
    } else if (bid < 816) {
        int idx = (bid - 240) * 256 + t;    // 147,456 floats
        if (idx < 73728) sx[idx] = 0.f;
        else sh[idx - 73728] = 0.f;
    } else if (bid < 1072) {
        int idx = (bid - 816) * 256 + t;    // 65,536: scores = We_b (hop 0,
        scores[idx] = Web[idx >> 14];       // needed for fused leftover heads)
    } else if (bid < 3376) {
        if (tier < 2) return;
        __shared__ float tile[32][33];
        int bid2 = bid - 1072;
        int k = bid2 / 576, rem = bid2 % 576, tr = rem / 24, tc = rem % 24;
        const float* src = WsW + (long)k * HH;
        long dbase = (long)k * HH;
        int tx = t & 31, ty = t >> 5;
        #pragma unroll
        for (int i = 0; i < 4; ++i)
            tile[tx][ty + i*8] = src[(long)(tr*32 + ty + i*8) * NH + tc*32 + tx];
        __syncthreads();
        #pragma unroll
        for (int i = 0; i < 4; ++i) {
            float v = tile[ty + i*8][tx];
            u16 hv = f2bf(v);
            u16 lv = f2bf(v - bf2f(hv));
            long o = dbase + (long)(tc*32 + ty + i*8) * NH + tr*32 + tx;
            WsTH[o] = hv; WsTL[o] = lv;
        }
    } else if (bid < 5680) {
        if (tier < 2) return;
        long base = (long)(bid - 3376) * 1024 + t * 4;
        float4 v = *(const float4*)(pwW + base);
        ushort4 hv, lv;
        hv.x = f2bf(v.x); lv.x = f2bf(v.x - bf2f(hv.x));
        hv.y = f2bf(v.y); lv.y = f2bf(v.y - bf2f(hv.y));
        hv.z = f2bf(v.z); lv.z = f2bf(v.z - bf2f(hv.z));
        hv.w = f2bf(v.w); lv.w = f2bf(v.w - bf2f(hv.w));
        *(ushort4*)(pwH + base) = hv;
        *(ushort4*)(pwL + base) = lv;
    } else {
        if (!splitText) return;
        long base = (long)(bid - 5680) * 1024 + t * 4;
        float4 v = *(const float4*)(text + base);
        ushort4 hv;
        hv.x = f2bf(v.x);
        hv.y = f2bf(v.y);
        hv.z = f2bf(v.z);
        hv.w = f2bf(v.w);
        *(ushort4*)(textH + base) = hv;
    }
}

// combT[k][j][h] = sum_m WsT[k][j][m] * pw[k][h][m], split-bf16 3-MFMA.
__global__ __launch_bounds__(256) void comb_mfma_kernel(
    const u16* __restrict__ WsTH, const u16* __restrict__ WsTL,
    const u16* __restrict__ pwH, const u16* __restrict__ pwL,
    u16* __restrict__ combTH, u16* __restrict__ combTL)
{
    __shared__ __align__(16) u16 AsH[128 * 32];
    __shared__ __align__(16) u16 AsL[128 * 32];
    __shared__ __align__(16) u16 BsH[128 * 32];
    __shared__ __align__(16) u16 BsL[128 * 32];
    const int t = threadIdx.x;
    const int wave = t >> 6, lane = t & 63;
    const int k = blockIdx.z;
    const long m0 = (long)blockIdx.x * 128;   // j-rows
    const int n0 = blockIdx.y * 128;          // h-cols
    const u16* AH = WsTH + (long)k * HH;
    const u16* AL = WsTL + (long)k * HH;
    const u16* BH = pwH + (long)k * HH;
    const u16* BL = pwL + (long)k * HH;

    const int r = t >> 2, ch = t & 3;
    const int wm = (wave & 1) * 64, wn = (wave >> 1) * 64;
    const int fr = lane & 15, fq = lane >> 4;

    f32x4 acc[4][4];
    #pragma unroll
    for (int i = 0; i < 4; ++i)
        #pragma unroll
        for (int j = 0; j < 4; ++j) acc[i][j] = (f32x4){0.f, 0.f, 0.f, 0.f};

    for (int k0 = 0; k0 < NH; k0 += 32) {
        gld16(AH + (m0 + r)      * NH + k0 + ch*8, AsH + t*8);
        gld16(AH + (m0 + 64 + r) * NH + k0 + ch*8, AsH + 2048 + t*8);
        gld16(AL + (m0 + r)      * NH + k0 + ch*8, AsL + t*8);
        gld16(AL + (m0 + 64 + r) * NH + k0 + ch*8, AsL + 2048 + t*8);
        gld16(BH + (long)(n0 + r)      * NH + k0 + ch*8, BsH + t*8);
        gld16(BH + (long)(n0 + 64 + r) * NH + k0 + ch*8, BsH + 2048 + t*8);
        gld16(BL + (long)(n0 + r)      * NH + k0 + ch*8, BsL + t*8);
        gld16(BL + (long)(n0 + 64 + r) * NH + k0 + ch*8, BsL + 2048 + t*8);
        __syncthreads();
        bf16x8 afH[4], afL[4], bfH[4], bfL[4];
        #pragma unroll
        for (int i = 0; i < 4; ++i) {
            afH[i] = *(const bf16x8*)(AsH + (wm + i*16 + fr)*32 + fq*8);
            afL[i] = *(const bf16x8*)(AsL + (wm + i*16 + fr)*32 + fq*8);
            bfH[i] = *(const bf16x8*)(BsH + (wn + i*16 + fr)*32 + fq*8);
            bfL[i] = *(const bf16x8*)(BsL + (wn + i*16 + fr)*32 + fq*8);
        }
        #pragma unroll
        for (int i = 0; i < 4; ++i)
            #pragma unroll
            for (int j = 0; j < 4; ++j) {
                acc[i][j] = __builtin_amdgcn_mfma_f32_16x16x32_bf16(afH[i], bfH[j], acc[i][j], 0, 0, 0);
                acc[i][j] = __builtin_amdgcn_mfma_f32_16x16x32_bf16(afH[i], bfL[j], acc[i][j], 0, 0, 0);
                acc[i][j] = __builtin_amdgcn_mfma_f32_16x16x32_bf16(afL[i], bfH[j], acc[i][j], 0, 0, 0);
            }
        __syncthreads();
    }
    long kb = (long)k * HH;
    #pragma unroll
    for (int i = 0; i < 4; ++i) {
        long m = m0 + wm + i*16 + fq*4;       // j-row
        #pragma unroll
        for (int j = 0; j < 4; ++j) {
            long n = n0 + wn + j*16 + fr;     // h-col
            #pragma unroll
            for (int rr = 0; rr < 4; ++rr) {
                float v = acc[i][j][rr];
                u16 hv = f2bf(v);
                u16 lv = f2bf(v - bf2f(hv));
                combTH[kb + (m + rr) * NH + n] = hv;
                combTL[kb + (m + rr) * NH + n] = lv;
            }
        }
    }
}

// tier 0/1: comb[k][h][j] f32 VALU GEMM (proven R8 kernel).
__global__ __launch_bounds__(256) void comb_valu_kernel(
    const float* __restrict__ pwW, const float* __restrict__ WsW,
    float* __restrict__ comb)
{
    __shared__ float AtT[32][68];
    __shared__ float Bt[32][132];
    const int t = threadIdx.x;
    const int m0 = blockIdx.x * 64, j0 = blockIdx.y * 128, k = blockIdx.z;
    const float* A = pwW + (long)k * HH;
    const float* B = WsW + (long)k * HH;
    const int r4 = (t >> 4) * 4, c8 = (t & 15) * 8;
    float acc[4][8];
    #pragma unroll
    for (int rr = 0; rr < 4; ++rr)
        #pragma unroll
        for (int cc = 0; cc < 8; ++cc) acc[rr][cc] = 0.f;
    for (int h0 = 0; h0 < NH; h0 += 32) {
        #pragma unroll
        for (int p = 0; p < 8; ++p) {
            int idx = p * 256 + t;
            int r = idx >> 5, hh = idx & 31;
            AtT[hh][r] = A[(long)(m0 + r) * NH + h0 + hh];
        }
        #pragma unroll
        for (int p = 0; p < 16; ++p) {
            int idx = p * 256 + t;
            int hh = idx >> 7, c = idx & 127;
            Bt[hh][c] = B[(long)(h0 + hh) * NH + j0 + c];
        }
        __syncthreads();
        for (int hh = 0; hh < 32; ++hh) {
            float4 av  = *(const float4*)&AtT[hh][r4];
            float4 bv0 = *(const float4*)&Bt[hh][c8];
            float4 bv1 = *(const float4*)&Bt[hh][c8 + 4];
            float a[4] = {av.x, av.y, av.z, av.w};
            float bb[8] = {bv0.x, bv0.y, bv0.z, bv0.w, bv1.x, bv1.y, bv1.z, bv1.w};
            #pragma unroll
            for (int rr = 0; rr < 4; ++rr)
                #pragma unroll
                for (int cc = 0; cc < 8; ++cc) acc[rr][cc] += a[rr] * bb[cc];
        }
        __syncthreads();
    }
    float* C = comb + (long)k * HH;
    #pragma unroll
    for (int rr = 0; rr < 4; ++rr)
        #pragma unroll
        for (int cc = 0; cc < 8; ++cc)
            C[(long)(m0 + r4 + rr) * NH + j0 + c8 + cc] = acc[rr][cc];
}

// tier1: transpose+split comb f32 -> combTH/combTL. grid 2304.
__global__ void split_combT_kernel(const float* __restrict__ comb,
                                   u16* __restrict__ combTH, u16* __restrict__ combTL)
{
    __shared__ float tile[32][33];
    int bid = blockIdx.x, t = threadIdx.x;
    int k = bid / 576, rem = bid % 576, tr = rem / 24, tc = rem % 24;
    const float* src = comb + (long)k * HH;
    long dbase = (long)k * HH;
    int tx = t & 31, ty = t >> 5;
    #pragma unroll
    for (int i = 0; i < 4; ++i)
        tile[tx][ty + i*8] = src[(long)(tr*32 + ty + i*8) * NH + tc*32 + tx];
    __syncthreads();
    #pragma unroll
    for (int i = 0; i < 4; ++i) {
        float v = tile[ty + i*8][tx];
        u16 hv = f2bf(v);
        u16 lv = f2bf(v - bf2f(hv));
        long o = dbase + (long)(tc*32 + ty + i*8) * NH + tr*32 + tx;
        combTH[o] = hv; combTL[o] = lv;
    }
}

// TIER3: TP[k][bs][j] = bf16((text @ comb[k])[bs][j]) for heads [0, NSTORE).
// BK=64 (12 barrier-pairs over K=768 instead of 24; 48 KB LDS keeps 3
// blocks/CU). AM=1: A hi via gld16 from textH. B split hi/lo (2 MFMA).
// grid (128, 6, NSTORE).
template <int AM>
__global__ __launch_bounds__(256) void tp_gemm_kernel(
    const float* __restrict__ textf, const u16* __restrict__ textH,
    const u16* __restrict__ combTH, const u16* __restrict__ combTL,
    u16* __restrict__ TP)
{
    __shared__ __align__(16) u16 AsH[128 * 64];
    __shared__ __align__(16) u16 BsH[128 * 64];
    __shared__ __align__(16) u16 BsL[128 * 64];
    const int t = threadIdx.x;
    const int wave = t >> 6, lane = t & 63;
    const int k = blockIdx.z;
    const long m0 = (long)blockIdx.x * 128;   // bs-rows
    const int n0 = blockIdx.y * 128;          // j-cols
    const u16* BH = combTH + (long)k * HH;
    const u16* BL = combTL + (long)k * HH;

    const int r = t >> 3, ch = t & 7;         // 32 rows x 8 chunks per gld16 call
    const int wm = (wave & 1) * 64, wn = (wave >> 1) * 64;
    const int fr = lane & 15, fq = lane >> 4;

    f32x4 acc[4][4];
    #pragma unroll
    for (int i = 0; i < 4; ++i)
        #pragma unroll
        for (int j = 0; j < 4; ++j) acc[i][j] = (f32x4){0.f, 0.f, 0.f, 0.f};

    for (int h0 = 0; h0 < NH; h0 += 64) {
        if (AM) {
            #pragma unroll
            for (int q = 0; q < 4; ++q)
                gld16(textH + (m0 + q*32 + r) * NH + h0 + ch*8, AsH + q*2048 + t*8);
        } else {
            // on-the-fly f32->bf16: 128 rows x 64 cols = 8192 elems, 8 passes
            #pragma unroll
            for (int p = 0; p < 8; ++p) {
                int task = p * 256 + t;
                int row = task >> 4, g = task & 15;   // 16 float4-groups per row
                float4 v = *(const float4*)(textf + (m0 + row) * NH + h0 + g*4);
                ushort4 hv;
                hv.x = f2bf(v.x);
                hv.y = f2bf(v.y);
                hv.z = f2bf(v.z);
                hv.w = f2bf(v.w);
                *(ushort4*)(AsH + row * 64 + g*4) = hv;
            }
        }
        #pragma unroll
        for (int q = 0; q < 4; ++q) {
            gld16(BH + (long)(n0 + q*32 + r) * NH + h0 + ch*8, BsH + q*2048 + t*8);
            gld16(BL + (long)(n0 + q*32 + r) * NH + h0 + ch*8, BsL + q*2048 + t*8);
        }
        __syncthreads();
        #pragma unroll
        for (int ks = 0; ks < 2; ++ks) {
            bf16x8 afH[4], bfH[4], bfL[4];
            #pragma unroll
            for (int i = 0; i < 4; ++i) {
                afH[i] = *(const bf16x8*)(AsH + (wm + i*16 + fr)*64 + ks*32 + fq*8);
                bfH[i] = *(const bf16x8*)(BsH + (wn + i*16 + fr)*64 + ks*32 + fq*8);
                bfL[i] = *(const bf16x8*)(BsL + (wn + i*16 + fr)*64 + ks*32 + fq*8);
            }
            #pragma unroll
            for (int i = 0; i < 4; ++i)
                #pragma unroll
                for (int j = 0; j < 4; ++j) {
                    acc[i][j] = __builtin_amdgcn_mfma_f32_16x16x32_bf16(afH[i], bfH[j], acc[i][j], 0, 0, 0);
                    acc[i][j] = __builtin_amdgcn_mfma_f32_16x16x32_bf16(afH[i], bfL[j], acc[i][j], 0, 0, 0);
                }
        }
        __syncthreads();
    }
    u16* out = TP + ((long)k * NBS + m0) * NH + n0;
    #pragma unroll
    for (int i = 0; i < 4; ++i) {
        #pragma unroll
        for (int rr = 0; rr < 4; ++rr) {
            int m = wm + i*16 + fq*4 + rr;
            #pragma unroll
            for (int j = 0; j < 4; ++j) {
                int n = wn + j*16 + fr;
                out[(long)m * NH + n] = f2bf(acc[i][j][rr]);
            }
        }
    }
}

// All hops: scores[k][b][s] = We_b[k] + sum_j tanh(TP + W_ht)*We for stored
// heads (writes '='). grid (16, 32, NSTORE).
__global__ __launch_bounds__(256) void score_pass_kernel(
    const u16* __restrict__ TP, const float* __restrict__ W_ht,
    const float* __restrict__ WeW, const float* __restrict__ Web,
    float* __restrict__ scores)
{
    __shared__ __align__(16) float bias_s[NH];
    __shared__ __align__(16) float we_s[NH];
    const int t = threadIdx.x;
    const int k = blockIdx.z, b = blockIdx.y;
    const int s0 = blockIdx.x * 32;
    for (int i = t; i < NH; i += 256) {
        bias_s[i] = W_ht[((k << 5) + b) * NH + i];
        we_s[i]   = WeW[k * NH + i];
    }
    __syncthreads();
    const int wave = t >> 6, lane = t & 63;
    const u16* tpb = TP + ((long)k * NBS + (b << 9) + s0) * NH;
    const float web = Web[k];
    for (int sr = wave; sr < 32; sr += 4) {
        const u16* row = tpb + (long)sr * NH;
        float part = 0.f;
        #pragma unroll
        for (int p = 0; p < 3; ++p) {
            const int j = p * 256 + lane * 4;   // 8B/lane bf16 loads, coalesced 512B
            ushort4 v = *(const ushort4*)(row + j);
            float4 bb = *(const float4*)(bias_s + j);
            float4 ww = *(const float4*)(we_s + j);
            part += tanh_fast(bf2f(v.x) + bb.x) * ww.x;
            part += tanh_fast(bf2f(v.y) + bb.y) * ww.y;
            part += tanh_fast(bf2f(v.z) + bb.z) * ww.z;
            part += tanh_fast(bf2f(v.w) + bb.w) * ww.w;
        }
        part += __shfl_xor(part, 1);
        part += __shfl_xor(part, 2);
        part += __shfl_xor(part, 4);
        part += __shfl_xor(part, 8);
        part += __shfl_xor(part, 16);
        part += __shfl_xor(part, 32);
        if (lane == 0) scores[(((k << 5) + b) << 9) + s0 + sr] = part + web;
    }
}

// scores = We_b for heads [koff, NK) (ahead of atomicAdd fused path).
__global__ void init_scores_kernel(const float* __restrict__ Web,
                                   float* __restrict__ scores, int koff)
{
    int idx = (koff << 14) + blockIdx.x * 256 + threadIdx.x;
    scores[idx] = Web[idx >> 14];
}

// W_ht[k][b][j] = Wtb + combB + q.Wt  (full dot, no atomics). grid 384.
__global__ __launch_bounds__(256) void wht2_kernel(
    const float* __restrict__ q, const float* __restrict__ WtW,
    const float* __restrict__ combB, const float* __restrict__ Wtb,
    float* __restrict__ W_ht)
{
    int bid = blockIdx.x;                 // 4k x 32b x 3jt
    int k = bid / 96, rem = bid % 96, b = rem / 3, jt = rem % 3;
    int j = jt * 256 + threadIdx.x;
    const float* W = WtW + (long)k * HH + j;
    const float* qb = q + b * NH;
    float acc = 0.f;
    #pragma unroll 8
    for (int h = 0; h < NH; ++h) acc += qb[h] * W[(long)h * NH];
    W_ht[(k*NB + b) * NH + j] = acc + Wtb[k * NH + j] + combB[k * NH + j];
}

// ---------------------------------------------------------------------------
// MFMA split-bf16 fused scores (W_ht includes combB), head-offset koff.
// grid (128, 6, nheads).
// ---------------------------------------------------------------------------
template <int AM>
__global__ __launch_bounds__(256) void fused_scores_mfma(
    const float* __restrict__ textf,
    const u16* __restrict__ textH, const u16* __restrict__ textL,
    const u16* __restrict__ combTH, const u16* __restrict__ combTL,
    const float* __restrict__ W_ht,
    const float* __restrict__ WeW, float* __restrict__ scores, int koff)
{
    __shared__ __align__(16) u16 AsH[128 * 32];
    __shared__ __align__(16) u16 AsL[128 * 32];
    __shared__ __align__(16) u16 BsH[128 * 32];
    __shared__ __align__(16) u16 BsL[128 * 32];
    __shared__ float wht_s[128];
    __shared__ float we_s[128];
    __shared__ float sred[128];
    const int t = threadIdx.x;
    const int wave = t >> 6, lane = t & 63;
    const int k = koff + blockIdx.z;
    const long m0 = (long)blockIdx.x * 128;
    const int n0 = blockIdx.y * 128;
    const int b = (int)(m0 >> 9), srow = (int)(m0 & 511);
    const u16* BH = combTH + (long)k * HH;
    const u16* BL = combTL + (long)k * HH;

    if (t < 128) {
        wht_s[t] = W_ht[((k << 5) + b) * NH + n0 + t];
        we_s[t]  = WeW[k * NH + n0 + t];
        sred[t]  = 0.f;
    }

    const int r = t >> 2, ch = t & 3;
    const int wm = (wave & 1) * 64, wn = (wave >> 1) * 64;
    const int fr = lane & 15, fq = lane >> 4;

    f32x4 acc[4][4];
    #pragma unroll
    for (int i = 0; i < 4; ++i)
        #pragma unroll
        for (int j = 0; j < 4; ++j) acc[i][j] = (f32x4){0.f, 0.f, 0.f, 0.f};

    for (int h0 = 0; h0 < NH; h0 += 32) {
        if (AM) {
            gld16(textH + (m0 + r)      * NH + h0 + ch*8, AsH + t*8);
            gld16(textH + (m0 + 64 + r) * NH + h0 + ch*8, AsH + 2048 + t*8);
            gld16(textL + (m0 + r)      * NH + h0 + ch*8, AsL + t*8);
            gld16(textL + (m0 + 64 + r) * NH + h0 + ch*8, AsL + 2048 + t*8);
        } else {
            #pragma unroll
            for (int p = 0; p < 4; ++p) {
                int task = p * 256 + t;
                int row = task >> 3, g = task & 7;
                float4 v = *(const float4*)(textf + (m0 + row) * NH + h0 + g*4);
                ushort4 hv, lv;
                hv.x = f2bf(v.x); lv.x = f2bf(v.x - bf2f(hv.x));
                hv.y = f2bf(v.y); lv.y = f2bf(v.y - bf2f(hv.y));
                hv.z = f2bf(v.z); lv.z = f2bf(v.z - bf2f(hv.z));
                hv.w = f2bf(v.w); lv.w = f2bf(v.w - bf2f(hv.w));
                *(ushort4*)(AsH + row * 32 + g*4) = hv;
                *(ushort4*)(AsL + row * 32 + g*4) = lv;
            }
        }
        gld16(BH + (long)(n0 + r)      * NH + h0 + ch*8, BsH + t*8);
        gld16(BH + (long)(n0 + 64 + r) * NH + h0 + ch*8, BsH + 2048 + t*8);
        gld16(BL + (long)(n0 + r)      * NH + h0 + ch*8, BsL + t*8);
        gld16(BL + (long)(n0 + 64 + r) * NH + h0 + ch*8, BsL + 2048 + t*8);
        __syncthreads();
        bf16x8 afH[4], afL[4], bfH[4], bfL[4];
        #pragma unroll
        for (int i = 0; i < 4; ++i) {
            afH[i] = *(const bf16x8*)(AsH + (wm + i*16 + fr)*32 + fq*8);
            afL[i] = *(const bf16x8*)(AsL + (wm + i*16 + fr)*32 + fq*8);
            bfH[i] = *(const bf16x8*)(BsH + (wn + i*16 + fr)*32 + fq*8);
            bfL[i] = *(const bf16x8*)(BsL + (wn + i*16 + fr)*32 + fq*8);
        }
        #pragma unroll
        for (int i = 0; i < 4; ++i)
            #pragma unroll
            for (int j = 0; j < 4; ++j) {
                acc[i][j] = __builtin_amdgcn_mfma_f32_16x16x32_bf16(afH[i], bfH[j], acc[i][j], 0, 0, 0);
                acc[i][j] = __builtin_amdgcn_mfma_f32_16x16x32_bf16(afH[i], bfL[j], acc[i][j], 0, 0, 0);
                acc[i][j] = __builtin_amdgcn_mfma_f32_16x16x32_bf16(afL[i], bfH[j], acc[i][j], 0, 0, 0);
            }
        __syncthreads();
    }
    #pragma unroll
    for (int i = 0; i < 4; ++i) {
        #pragma unroll
        for (int rr = 0; rr < 4; ++rr) {
            int m = wm + i*16 + fq*4 + rr;
            float part = 0.f;
            #pragma unroll
            for (int j = 0; j < 4; ++j) {
                int n = wn + j*16 + fr;
                part += tanh_fast(acc[i][j][rr] + wht_s[n]) * we_s[n];
            }
            part += __shfl_xor(part, 1);
            part += __shfl_xor(part, 2);
            part += __shfl_xor(part, 4);
            part += __shfl_xor(part, 8);
            if (fr == 0) atomicAdd(&sred[m], part);
        }
    }
    __syncthreads();
    if (t < 128)
        atomicAdd(&scores[(((k << 5) + b) << 9) + srow + t], sred[t]);
}

// tier0 fallback (W_ht includes combB). grid (256, 6, 4).
__global__ __launch_bounds__(256) void fused_scores_valu(
    const float* __restrict__ text, const float* __restrict__ comb,
    const float* __restrict__ W_ht,
    const float* __restrict__ WeW, float* __restrict__ scores)
{
    __shared__ float AtT[32][68];
    __shared__ float Bt[32][132];
    __shared__ float wht_s[128];
    __shared__ float we_s[128];
    __shared__ float sred[64];
    const int t = threadIdx.x;
    const int row0 = blockIdx.x * 64;
    const int j0 = blockIdx.y * 128, k = blockIdx.z;
    const int b = row0 >> 9, s0 = row0 & 511;
    const float* B = comb + (long)k * HH;
    const int r4 = (t >> 4) * 4, c8 = (t & 15) * 8;
    if (t < 128) {
        wht_s[t] = W_ht[((k << 5) + b) * NH + j0 + t];
        we_s[t]  = WeW[k * NH + j0 + t];
    }
    if (t < 64) sred[t] = 0.f;
    float acc[4][8];
    #pragma unroll
    for (int rr = 0; rr < 4; ++rr)
        #pragma unroll
        for (int cc = 0; cc < 8; ++cc) acc[rr][cc] = 0.f;
    for (int h0 = 0; h0 < NH; h0 += 32) {
        #pragma unroll
        for (int p = 0; p < 8; ++p) {
            int idx = p * 256 + t;
            int r = idx >> 5, hh = idx & 31;
            AtT[hh][r] = text[(long)(row0 + r) * NH + h0 + hh];
        }
        #pragma unroll
        for (int p = 0; p < 16; ++p) {
            int idx = p * 256 + t;
            int hh = idx >> 7, c = idx & 127;
            Bt[hh][c] = B[(long)(h0 + hh) * NH + j0 + c];
        }
        __syncthreads();
        for (int hh = 0; hh < 32; ++hh) {
            float4 av  = *(const float4*)&AtT[hh][r4];
            float4 bv0 = *(const float4*)&Bt[hh][c8];
            float4 bv1 = *(const float4*)&Bt[hh][c8 + 4];
            float a[4] = {av.x, av.y, av.z, av.w};
            float bb[8] = {bv0.x, bv0.y, bv0.z, bv0.w, bv1.x, bv1.y, bv1.z, bv1.w};
            #pragma unroll
            for (int rr = 0; rr < 4; ++rr)
                #pragma unroll
                for (int cc = 0; cc < 8; ++cc) acc[rr][cc] += a[rr] * bb[cc];
        }
        __syncthreads();
    }
    float part[4] = {0.f, 0.f, 0.f, 0.f};
    #pragma unroll
    for (int rr = 0; rr < 4; ++rr)
        #pragma unroll
        for (int cc = 0; cc < 8; ++cc)
            part[rr] += tanh_fast(acc[rr][cc] + wht_s[c8 + cc]) * we_s[c8 + cc];
    #pragma unroll
    for (int rr = 0; rr < 4; ++rr)
        atomicAdd(&sred[r4 + rr], part[rr]);
    __syncthreads();
    if (t < 64)
        atomicAdd(&scores[(((k << 5) + b) << 9) + s0 + t], sred[t]);
}

// Shuffle-based softmax + head-combine + argmax + xT build. grid 32.
__global__ void softmax_kernel(const float* __restrict__ scores,
                               const float* __restrict__ headw_W, const float* __restrict__ headw_b,
                               const float* __restrict__ text,
                               const float* __restrict__ q_f32,
                               float* __restrict__ xT, float* __restrict__ out_prob, int hop)
{
    __shared__ float sc[NK][NS];
    __shared__ float cred[4];
    __shared__ float cval[4];
    __shared__ int   cidx[4];
    int b = blockIdx.x, t = threadIdx.x;
    int wave = t >> 6, lane = t & 63;
    for (int i = t; i < NK * NS; i += 256) {
        int k = i >> 9, s = i & 511;
        sc[k][s] = scores[((k*NB + b) << 9) + s];
    }
    __syncthreads();
    float fac[NK];
    for (int k = 0; k < NK; ++k) {
        float v0 = sc[k][t], v1 = sc[k][t + 256];
        float m = fmaxf(v0, v1);
        #pragma unroll
        for (int o = 32; o > 0; o >>= 1) m = fmaxf(m, __shfl_xor(m, o));
        if (lane == 0) cred[wave] = m;
        __syncthreads();
        float mx = fmaxf(fmaxf(cred[0], cred[1]), fmaxf(cred[2], cred[3]));
        __syncthreads();
        float e0 = __expf(v0 - mx), e1 = __expf(v1 - mx);
        sc[k][t] = e0; sc[k][t + 256] = e1;
        float sm = e0 + e1;
        #pragma unroll
        for (int o = 32; o > 0; o >>= 1) sm += __shfl_xor(sm, o);
        if (lane == 0) cred[wave] = sm;
        __syncthreads();
        fac[k] = headw_W[k] / (cred[0] + cred[1] + cred[2] + cred[3]);
        __syncthreads();
    }
    float hwb = headw_b[0];
    float a0 = hwb, a1 = hwb;
    for (int k = 0; k < NK; ++k) { a0 += sc[k][t] * fac[k]; a1 += sc[k][t + 256] * fac[k]; }
    float ss = a0*a0 + a1*a1;
    #pragma unroll
    for (int o = 32; o > 0; o >>= 1) ss += __shfl_xor(ss, o);
    float bv; int bi;
    if (a0 >= a1) { bv = a0; bi = t; } else { bv = a1; bi = t + 256; }
    #pragma unroll
    for (int o = 1; o < 64; o <<= 1) {
        float ov = __shfl_xor(bv, o);
        int   oi = __shfl_xor(bi, o);
        if (ov > bv || (ov == bv && oi < bi)) { bv = ov; bi = oi; }
    }
    if (lane == 0) { cred[wave] = ss; cval[wave] = bv; cidx[wave] = bi; }
    __syncthreads();
    float scale = sqrtf(cred[0] + cred[1] + cred[2] + cred[3]);
    float mbv = cval[0]; int mbi = cidx[0];
    #pragma unroll
    for (int w = 1; w < 4; ++w)
        if (cval[w] > mbv || (cval[w] == mbv && cidx[w] < mbi)) { mbv = cval[w]; mbi = cidx[w]; }
    int idx = mbi;
    if (hop == 0) {
        out_prob[(b << 9) + t]       = a0 / scale;
        out_prob[(b << 9) + t + 256] = a1 / scale;
    }
    const float* trow = text + (long)(b * NS + idx) * NH;
    for (int i = t; i < NH; i += 256) {
        xT[i * NB + b]        = q_f32[b*NH + i];
        xT[(NH + i) * NB + b] = trow[i];
    }
}

// GRU matvec partials: grid (36 j-tiles, 9 chunks: 6 sx + 3 sh); atomicAdd.
__global__ __launch_bounds__(256) void gru_mm3_kernel(
    const float* __restrict__ Wih, const float* __restrict__ Whh,
    const float* __restrict__ xT, const float* __restrict__ hT,
    float* __restrict__ sx, float* __restrict__ sh)
{
    __shared__ float xs[8192];
    int t = threadIdx.x;
    int tj = t & 63, tq = t >> 6;
    int j = blockIdx.x * 64 + tj;
    int cg = blockIdx.y;
    const float* W; const float* src; float* dst; int c;
    if (cg < 6) { W = Wih; src = xT; dst = sx; c = cg; }
    else        { W = Whh; src = hT; dst = sh; c = cg - 6; }
    for (int idx = t; idx < 8192; idx += 256) xs[idx] = src[c * 8192 + idx];
    __syncthreads();
    float acc[8];
    #pragma unroll
    for (int bq = 0; bq < 8; ++bq) acc[bq] = 0.f;
    #pragma unroll 8
    for (int ii = 0; ii < 256; ++ii) {
        float w = W[(long)(c * 256 + ii) * H3 + j];
        #pragma unroll
        for (int bq = 0; bq < 8; ++bq) acc[bq] += xs[ii * 32 + tq * 8 + bq] * w;
    }
    #pragma unroll
    for (int bq = 0; bq < 8; ++bq)
        atomicAdd(&dst[(long)(tq * 8 + bq) * H3 + j], acc[bq]);
}

// Gate + h/q update; re-zeroes sx/sh for the next hop after reading.
__global__ void gate_kernel(const float* __restrict__ bih, const float* __restrict__ bhh,
                            float* __restrict__ sx, float* __restrict__ sh,
                            float* __restrict__ hT, float* __restrict__ q_f32,
                            float* __restrict__ out_h, int hop)
{
    int gid = blockIdx.x * 256 + threadIdx.x;
    int b = gid / NH, j = gid % NH;
    float xr = bih[j]        + sx[b*H3 + j];
    float xz = bih[NH + j]   + sx[b*H3 + NH + j];
    float xn = bih[1536 + j] + sx[b*H3 + 1536 + j];
    float hr = bhh[j]        + sh[b*H3 + j];
    float hz = bhh[NH + j]   + sh[b*H3 + NH + j];
    float hn = bhh[1536 + j] + sh[b*H3 + 1536 + j];
    sx[b*H3 + j] = 0.f; sx[b*H3 + NH + j] = 0.f; sx[b*H3 + 1536 + j] = 0.f;
    sh[b*H3 + j] = 0.f; sh[b*H3 + NH + j] = 0.f; sh[b*H3 + 1536 + j] = 0.f;
    float r = sig_fast(xr + hr);
    float z = sig_fast(xz + hz);
    float n = tanh_fast(xn + r * hn);
    float hp = hT[j * NB + b];
    float hnew = (1.f - z) * n + z * hp;
    hT[j * NB + b] = hnew;
    q_f32[gid] = hnew;
    out_h[(long)(b * 3 + hop) * NH + j] = hnew;
}

// ---------------------------------------------------------------------------
extern "C" void kernel_launch(void* const* d_in, const int* in_sizes, int n_in,
                              void* d_out, int out_size, void* d_ws, size_t ws_size,
                              hipStream_t stream)
{
    const float* question = (const float*)d_in[0];
    const float* text     = (const float*)d_in[1];
    const float* pw_W     = (const float*)d_in[2];
    const float* pw_b     = (const float*)d_in[3];
    const float* Ws_W     = (const float*)d_in[4];
    const float* Ws_b     = (const float*)d_in[5];
    const float* Wt_W     = (const float*)d_in[6];
    const float* Wt_b     = (const float*)d_in[7];
    const float* We_W     = (const float*)d_in[8];
    const float* We_b     = (const float*)d_in[9];
    const float* headw_W  = (const float*)d_in[10];
    const float* headw_b  = (const float*)d_in[11];
    const float* Wih      = (const float*)d_in[12];
    const float* Whh      = (const float*)d_in[13];
    const float* bih      = (const float*)d_in[14];
    const float* bhh      = (const float*)d_in[15];

    char* ws = (char*)d_ws;
    float* comb   = (float*)(ws + 0);
    float* combB  = (float*)(ws + 9437184);
    float* W_ht   = (float*)(ws + 9449472);
    float* scores = (float*)(ws + 9842688);
    float* q_f32  = (float*)(ws + 10104832);
    float* hT     = (float*)(ws + 10203136);
    float* xT     = (float*)(ws + 10301440);
    float* sx     = (float*)(ws + 10498048);
    float* sh     = (float*)(ws + 10792960);
    u16*   combTH = (u16*)  (ws + 11087872);
    u16*   combTL = (u16*)  (ws + 15806464);
    u16*   TP     = (u16*)  (ws + 20525056);
    u16*   textH  = (u16*)  (ws + 121188352);
    // prep scratch overlaid on TP region (dead before tp_gemm runs):
    u16*   WsTH   = (u16*)  (ws + 20525056);
    u16*   WsTL   = (u16*)  (ws + 25243648);
    u16*   pwH    = (u16*)  (ws + 29962240);
    u16*   pwL    = (u16*)  (ws + 34680832);

    int nstore = 0;
    if (ws_size >= (size_t)70856704) {
        long avail = (long)ws_size - 20525056L;
        nstore = (int)(avail / 25165824L);
        if (nstore > NK) nstore = NK;
    }
    const int tier = (nstore >= 1) ? 3
                   : (ws_size >= (size_t)20525056) ? 1 : 0;
    const bool haveTextH = (tier == 3) && (nstore == NK)
                        && (ws_size >= (size_t)146354176);

    float* out_prob = (float*)d_out;
    float* out_h    = (float*)d_out + NB * NS;

    const int prepGrid = haveTextH ? 17968 : (tier >= 2 ? 5680 : 1072);
    prep_kernel<<<prepGrid, 256, 0, stream>>>(
        Ws_W, pw_b, Ws_b, combB, question, q_f32, hT, sx, sh, We_b, scores,
        pw_W, WsTH, WsTL, pwH, pwL, text, textH,
        tier >= 3 ? 2 : tier, haveTextH ? 1 : 0);

    if (tier == 3) {
        comb_mfma_kernel<<<dim3(6, 6, 4), 256, 0, stream>>>(WsTH, WsTL, pwH, pwL,
                                                            combTH, combTL);
        // scratch dead from here; TP overwrites it.
        if (haveTextH) {
            tp_gemm_kernel<1><<<dim3(128, 6, nstore), 256, 0, stream>>>(
                text, textH, combTH, combTL, TP);
        } else {
            tp_gemm_kernel<0><<<dim3(128, 6, nstore), 256, 0, stream>>>(
                text, nullptr, combTH, combTL, TP);
        }
    } else {
        comb_valu_kernel<<<dim3(12, 6, 4), 256, 0, stream>>>(pw_W, Ws_W, comb);
        if (tier == 1)
            split_combT_kernel<<<2304, 256, 0, stream>>>(comb, combTH, combTL);
    }

    for (int hop = 0; hop < 3; ++hop) {
        wht2_kernel<<<384, 256, 0, stream>>>(q_f32, Wt_W, combB, Wt_b, W_ht);
        if (tier == 3) {
            score_pass_kernel<<<dim3(16, 32, nstore), 256, 0, stream>>>(
                TP, W_ht, We_W, We_b, scores);
            if (nstore < NK) {
                if (hop > 0)
                    init_scores_kernel<<<(NK - nstore) * 64, 256, 0, stream>>>(
                        We_b, scores, nstore);
                fused_scores_mfma<0><<<dim3(128, 6, NK - nstore), 256, 0, stream>>>(
                    text, nullptr, nullptr, combTH, combTL, W_ht, We_W,
                    scores, nstore);
            }
        } else if (tier == 1) {
            init_scores_kernel<<<256, 256, 0, stream>>>(We_b, scores, 0);
            fused_scores_mfma<0><<<dim3(128, 6, 4), 256, 0, stream>>>(
                text, nullptr, nullptr, combTH, combTL, W_ht, We_W, scores, 0);
        } else {
            init_scores_kernel<<<256, 256, 0, stream>>>(We_b, scores, 0);
            fused_scores_valu<<<dim3(256, 6, 4), 256, 0, stream>>>(
                text, comb, W_ht, We_W, scores);
        }
        softmax_kernel<<<32, 256, 0, stream>>>(scores, headw_W, headw_b, text,
                                               q_f32, xT, out_prob, hop);
        gru_mm3_kernel<<<dim3(36, 9), 256, 0, stream>>>(Wih, Whh, xT, hT, sx, sh);
        gate_kernel<<<96, 256, 0, stream>>>(bih, bhh, sx, sh, hT, q_f32, out_h, hop);
    }
}